// Round 2
// baseline (996.905 us; speedup 1.0000x reference)
//
#include <hip/hip_runtime.h>
#include <math.h>

#define T_ 8
#define N_ 3200
#define E_ 25600
#define ET_ 28800   // E_ + N_
#define B_ 8
#define NP_ 400
#define IND_ 128
#define G_ 64
#define HC_ 256
#define D_ 512
#define NEG_ 0.2f
#define EPS_ 1e-5f

__device__ __forceinline__ float wred_sum(float v){
#pragma unroll
  for (int o = 32; o; o >>= 1) v += __shfl_xor(v, o, 64);
  return v;
}

// ---------------- CSR build ----------------
__global__ void k_zero_i(int* p, int n){
  int i = blockIdx.x*256 + threadIdx.x;
  if (i < n) p[i] = 0;
}

__global__ void k_count(const int* __restrict__ dst, int* __restrict__ cnt){
  int e = blockIdx.x*256 + threadIdx.x;
  if (e < E_) atomicAdd(&cnt[dst[e]], 1);
}

__global__ void k_scan(const int* __restrict__ cnt, int* __restrict__ off, int* __restrict__ pos){
  __shared__ int part[256];
  int tid = threadIdx.x;
  const int CH = 13;               // 256*13 = 3328 >= 3200
  int base = tid*CH;
  int s = 0;
  for (int i = 0; i < CH; ++i){ int idx = base+i; s += (idx < N_) ? cnt[idx] : 0; }
  part[tid] = s; __syncthreads();
  for (int d = 1; d < 256; d <<= 1){
    int v = (tid >= d) ? part[tid-d] : 0;
    __syncthreads();
    part[tid] += v;
    __syncthreads();
  }
  int run = tid ? part[tid-1] : 0;
  for (int i = 0; i < CH; ++i){
    int idx = base+i;
    if (idx < N_){ off[idx] = run; pos[idx] = run; run += cnt[idx]; }
  }
  if (tid == 255) off[N_] = part[255];
}

__global__ void k_scatter(const int* __restrict__ dst, int* __restrict__ pos, int* __restrict__ eid){
  int e = blockIdx.x*256 + threadIdx.x;
  if (e < E_){ int p = atomicAdd(&pos[dst[e]], 1); eid[p] = e; }
}

// self-loop attr: per-target mean of incoming edge_attr
__global__ void k_sl(const float* __restrict__ ea, const int* __restrict__ off,
                     const int* __restrict__ eid, float* __restrict__ sl){
  int idx = blockIdx.x*256 + threadIdx.x;
  if (idx >= T_*N_) return;
  int t = idx / N_, n = idx % N_;
  int o = off[n], d = off[n+1] - o;
  float s0 = 0.f, s1 = 0.f;
  for (int j = 0; j < d; ++j){
    int e = eid[o+j];
    const float* p = ea + ((size_t)t*E_ + e)*2;
    s0 += p[0]; s1 += p[1];
  }
  float c = fmaxf((float)d, 1.f);
  sl[(size_t)idx*2]   = s0 / c;
  sl[(size_t)idx*2+1] = s1 / c;
}

// ---------------- generic GEMM tile body: C[M,N] = A[M,K] @ W[N,K]^T (+bias)(+relu) ----
// requires M%64==0, N%64==0, K%32==0 (tile fully in-bounds)
template<int ACT>
__device__ __forceinline__ void gemm_tile(const float* __restrict__ A, const float* __restrict__ W,
                                          const float* __restrict__ bias, float* __restrict__ C,
                                          int N, int K, int row0, int col0){
  __shared__ float As[32][68];
  __shared__ float Ws[32][68];
  const int tid = threadIdx.x;
  const int tr = tid >> 4, tc = tid & 15;
  const int lm = tid >> 2;          // 0..63
  const int lk = (tid & 3)*8;       // 0,8,16,24
  float acc[4][4] = {};
  for (int k0 = 0; k0 < K; k0 += 32){
    const float* Ap = A + (size_t)(row0+lm)*K + k0 + lk;
    const float* Wp = W + (size_t)(col0+lm)*K + k0 + lk;
#pragma unroll
    for (int j = 0; j < 8; ++j) As[lk+j][lm] = Ap[j];
#pragma unroll
    for (int j = 0; j < 8; ++j) Ws[lk+j][lm] = Wp[j];
    __syncthreads();
#pragma unroll
    for (int kk = 0; kk < 32; ++kk){
      float av[4], wv[4];
      *(float4*)av = *(const float4*)&As[kk][tr*4];
      *(float4*)wv = *(const float4*)&Ws[kk][tc*4];
#pragma unroll
      for (int i = 0; i < 4; ++i)
#pragma unroll
        for (int j = 0; j < 4; ++j)
          acc[i][j] = fmaf(av[i], wv[j], acc[i][j]);
    }
    __syncthreads();
  }
#pragma unroll
  for (int i = 0; i < 4; ++i){
    int r = row0 + tr*4 + i;
    float* Cr = C + (size_t)r*N + col0 + tc*4;
#pragma unroll
    for (int j = 0; j < 4; ++j){
      float v = acc[i][j];
      if (bias) v += bias[col0 + tc*4 + j];
      if (ACT == 1) v = fmaxf(v, 0.f);
      Cr[j] = v;
    }
  }
}

template<int ACT>
__global__ __launch_bounds__(256) void k_gemm(const float* __restrict__ A, const float* __restrict__ W,
                                              const float* __restrict__ bias, float* __restrict__ C,
                                              int M, int N, int K){
  gemm_tile<ACT>(A, W, bias, C, N, K, blockIdx.y*64, blockIdx.x*64);
}

// fused xl/xr: blocks with blockIdx.x < HC_/64 compute A@Wl^T -> xl, others A@Wr^T -> xr
__global__ __launch_bounds__(256) void k_gemm_lr(const float* __restrict__ A,
                                                 const float* __restrict__ Wl, const float* __restrict__ Wr,
                                                 float* __restrict__ xl, float* __restrict__ xr){
  int bx = blockIdx.x;
  if (bx < HC_/64)
    gemm_tile<0>(A, Wl, nullptr, xl, HC_, G_, blockIdx.y*64, bx*64);
  else
    gemm_tile<0>(A, Wr, nullptr, xr, HC_, G_, blockIdx.y*64, (bx - HC_/64)*64);
}

// ---------------- GAT edge logits ----------------
// one wave per (t, edge); logit[t*ET+e][h] = sum_c att[h,c]*leaky(xl[src]+xr[dst]+ee)
__global__ __launch_bounds__(256) void k_edge(const float* __restrict__ xl, const float* __restrict__ xr,
                                              const float* __restrict__ ea, const float* __restrict__ sl,
                                              const int* __restrict__ srcv, const int* __restrict__ dstv,
                                              const float* __restrict__ we, const float* __restrict__ att,
                                              float* __restrict__ logit){
  int w = blockIdx.x*4 + (threadIdx.x >> 6);
  if (w >= T_*ET_) return;
  int lane = threadIdx.x & 63;
  int t = w / ET_, e = w % ET_;
  int s, d; float a0, a1;
  if (e < E_){
    s = srcv[e]; d = dstv[e];
    const float* p = ea + ((size_t)t*E_ + e)*2;
    a0 = p[0]; a1 = p[1];
  } else {
    s = d = e - E_;
    const float* p = sl + ((size_t)t*N_ + s)*2;
    a0 = p[0]; a1 = p[1];
  }
  const float* xls = xl + ((size_t)t*N_ + s)*HC_;
  const float* xrd = xr + ((size_t)t*N_ + d)*HC_;
  float acc[4];
#pragma unroll
  for (int h = 0; h < 4; ++h){
    int c = h*64 + lane;
    float v = xls[c] + xrd[c] + a0*we[c*2] + a1*we[c*2+1];
    v = (v >= 0.f) ? v : NEG_*v;
    acc[h] = v * att[c];
  }
#pragma unroll
  for (int o = 32; o; o >>= 1){
#pragma unroll
    for (int h = 0; h < 4; ++h) acc[h] += __shfl_xor(acc[h], o, 64);
  }
  if (lane == 0){
    float4 r = make_float4(acc[0], acc[1], acc[2], acc[3]);
    *(float4*)&logit[(size_t)w*4] = r;
  }
}

// ---------------- GAT node: segment softmax + aggregate + mean-heads + bias + relu + residual + LN
__global__ __launch_bounds__(256) void k_node(const float* __restrict__ xl, const float* __restrict__ logit,
                                              const int* __restrict__ off, const int* __restrict__ eid,
                                              const int* __restrict__ srcv,
                                              const float* __restrict__ hin, const float* __restrict__ gb,
                                              const float* __restrict__ lw, const float* __restrict__ lb,
                                              float* __restrict__ hout){
  int w = blockIdx.x*4 + (threadIdx.x >> 6);
  if (w >= T_*N_) return;
  int lane = threadIdx.x & 63;
  int t = w / N_, n = w % N_;
  int o = off[n], deg = off[n+1] - o, deg1 = deg + 1;
  const float4* lg = (const float4*)logit + (size_t)t*ET_;

  float4 mx = make_float4(-1e30f, -1e30f, -1e30f, -1e30f);
  for (int j = lane; j < deg1; j += 64){
    int e = (j < deg) ? eid[o+j] : (E_ + n);
    float4 l = lg[e];
    mx.x = fmaxf(mx.x, l.x); mx.y = fmaxf(mx.y, l.y);
    mx.z = fmaxf(mx.z, l.z); mx.w = fmaxf(mx.w, l.w);
  }
#pragma unroll
  for (int o2 = 32; o2; o2 >>= 1){
    mx.x = fmaxf(mx.x, __shfl_xor(mx.x, o2, 64));
    mx.y = fmaxf(mx.y, __shfl_xor(mx.y, o2, 64));
    mx.z = fmaxf(mx.z, __shfl_xor(mx.z, o2, 64));
    mx.w = fmaxf(mx.w, __shfl_xor(mx.w, o2, 64));
  }
  float4 sm = make_float4(0.f, 0.f, 0.f, 0.f);
  for (int j = lane; j < deg1; j += 64){
    int e = (j < deg) ? eid[o+j] : (E_ + n);
    float4 l = lg[e];
    sm.x += expf(l.x - mx.x); sm.y += expf(l.y - mx.y);
    sm.z += expf(l.z - mx.z); sm.w += expf(l.w - mx.w);
  }
  sm.x = wred_sum(sm.x); sm.y = wred_sum(sm.y);
  sm.z = wred_sum(sm.z); sm.w = wred_sum(sm.w);
  float4 rs = make_float4(1.f/sm.x, 1.f/sm.y, 1.f/sm.z, 1.f/sm.w);

  float acc = 0.f;
  for (int j = 0; j < deg1; ++j){
    int e, s;
    if (j < deg){ e = eid[o+j]; s = srcv[e]; } else { e = E_ + n; s = n; }
    float4 l = lg[e];
    float w0 = expf(l.x - mx.x)*rs.x;
    float w1 = expf(l.y - mx.y)*rs.y;
    float w2 = expf(l.z - mx.z)*rs.z;
    float w3 = expf(l.w - mx.w)*rs.w;
    const float* xp = xl + ((size_t)t*N_ + s)*HC_;
    acc += w0*xp[lane] + w1*xp[64+lane] + w2*xp[128+lane] + w3*xp[192+lane];
  }
  float v = 0.25f*acc + gb[lane];
  v = fmaxf(v, 0.f);                      // relu
  v += hin[((size_t)t*N_ + n)*G_ + lane]; // residual
  float mu = wred_sum(v) * (1.f/64.f);
  float dd = v - mu;
  float var = wred_sum(dd*dd) * (1.f/64.f);
  float rstd = 1.f / sqrtf(var + EPS_);
  hout[((size_t)t*N_ + n)*G_ + lane] = dd*rstd*lw[lane] + lb[lane];
}

// ---------------- pooling: mean/max over 400 nodes per (t,graph) ----------------
__global__ __launch_bounds__(256) void k_pool(const float* __restrict__ h, float* __restrict__ pooled){
  int tb = blockIdx.x;                 // t*8+b
  int t = tb >> 3, b = tb & 7;
  int lane = threadIdx.x & 63, w = threadIdx.x >> 6;
  const float* hp = h + ((size_t)t*N_ + b*NP_)*G_;
  float s = 0.f, m = -1e30f;
  for (int n = w*100; n < (w+1)*100; ++n){
    float v = hp[(size_t)n*G_ + lane];
    s += v; m = fmaxf(m, v);
  }
  __shared__ float ss[4][64], mm[4][64];
  ss[w][lane] = s; mm[w][lane] = m;
  __syncthreads();
  if (w == 0){
    s = ss[0][lane] + ss[1][lane] + ss[2][lane] + ss[3][lane];
    m = fmaxf(fmaxf(mm[0][lane], mm[1][lane]), fmaxf(mm[2][lane], mm[3][lane]));
    float* pr = pooled + (size_t)tb*128;
    pr[lane] = s * (1.f/400.f);
    pr[64+lane] = m;
  }
}

// ---------------- fused transpose (tok->y) + motion ----------------
__global__ void k_tokout(const float* __restrict__ tok, float* __restrict__ y, float* __restrict__ mo){
  int i = blockIdx.x*256 + threadIdx.x;
  if (i >= B_*T_*D_) return;
  int c = i & 511;
  int t = (i >> 9) & 7;
  int b = i >> 12;
  float v = tok[((size_t)t*B_ + b)*D_ + c];
  y[i] = v;
  if (c < 256 && t < 7)
    mo[((size_t)b*7 + t)*256 + c] = tok[((size_t)(t+1)*B_ + b)*D_ + c] - v;
}

// ---------------- MHA: one block per (batch, head) ----------------
__global__ __launch_bounds__(64) void k_mha(const float* __restrict__ qkv, float* __restrict__ o){
  int bh = blockIdx.x;
  int b = bh >> 3, hd = bh & 7;
  __shared__ float q[8][64], k[8][64], v[8][64], p[8][8];
  int tid = threadIdx.x;
  int tt = tid >> 3, d0 = (tid & 7)*8;
  const float* qr = qkv + ((size_t)(b*8 + tt))*1536 + hd*64 + d0;
#pragma unroll
  for (int j = 0; j < 8; ++j){
    q[tt][d0+j] = qr[j];
    k[tt][d0+j] = qr[512+j];
    v[tt][d0+j] = qr[1024+j];
  }
  __syncthreads();
  int tq = tid >> 3, tk = tid & 7;
  float s = 0.f;
#pragma unroll
  for (int d = 0; d < 64; ++d) s += q[tq][d]*k[tk][d];
  p[tq][tk] = s * 0.125f;
  __syncthreads();
  if (tid < 8){
    float mx = -1e30f;
#pragma unroll
    for (int j = 0; j < 8; ++j) mx = fmaxf(mx, p[tid][j]);
    float smv = 0.f;
#pragma unroll
    for (int j = 0; j < 8; ++j){ float e = expf(p[tid][j]-mx); p[tid][j] = e; smv += e; }
    float r = 1.f/smv;
#pragma unroll
    for (int j = 0; j < 8; ++j) p[tid][j] *= r;
  }
  __syncthreads();
  float out[8];
#pragma unroll
  for (int j = 0; j < 8; ++j) out[j] = 0.f;
#pragma unroll
  for (int t2 = 0; t2 < 8; ++t2){
    float wv = p[tq][t2];
#pragma unroll
    for (int j = 0; j < 8; ++j) out[j] = fmaf(wv, v[t2][d0+j], out[j]);
  }
  float* orow = o + ((size_t)(b*8 + tq))*D_ + hd*64 + d0;
#pragma unroll
  for (int j = 0; j < 8; ++j) orow[j] = out[j];
}

// ---------------- residual + LayerNorm over 512, wave per row ----------------
__global__ __launch_bounds__(256) void k_lnadd(float* __restrict__ y, const float* __restrict__ res,
                                               const float* __restrict__ w, const float* __restrict__ b){
  int row = blockIdx.x*4 + (threadIdx.x >> 6);
  int lane = threadIdx.x & 63;
  float* yr = y + (size_t)row*D_;
  const float* rr = res + (size_t)row*D_;
  float v[8]; float s = 0.f;
#pragma unroll
  for (int i = 0; i < 8; ++i){ v[i] = yr[lane + i*64] + rr[lane + i*64]; s += v[i]; }
  s = wred_sum(s);
  float mu = s * (1.f/512.f);
  float qq = 0.f;
#pragma unroll
  for (int i = 0; i < 8; ++i){ float d = v[i]-mu; qq += d*d; }
  qq = wred_sum(qq);
  float rstd = 1.f / sqrtf(qq*(1.f/512.f) + EPS_);
#pragma unroll
  for (int i = 0; i < 8; ++i){
    int c = lane + i*64;
    yr[c] = (v[i]-mu)*rstd*w[c] + b[c];
  }
}

extern "C" void kernel_launch(void* const* d_in, const int* in_sizes, int n_in,
                              void* d_out, int out_size, void* d_ws, size_t ws_size,
                              hipStream_t stream){
  const float* x       = (const float*)d_in[0];
  const int*   ei      = (const int*)d_in[1];
  const float* eattr   = (const float*)d_in[2];
  const float* proj_w  = (const float*)d_in[4];
  const float* proj_b  = (const float*)d_in[5];
  const float* gat_wl  = (const float*)d_in[6];
  const float* gat_wr  = (const float*)d_in[7];
  const float* gat_we  = (const float*)d_in[8];
  const float* gat_att = (const float*)d_in[9];
  const float* gat_b   = (const float*)d_in[10];
  const float* ln_w    = (const float*)d_in[11];
  const float* ln_b    = (const float*)d_in[12];
  const float* n2t_w   = (const float*)d_in[13];
  const float* n2t_b   = (const float*)d_in[14];
  const float* wqkv    = (const float*)d_in[15];
  const float* bqkv    = (const float*)d_in[16];
  const float* wo      = (const float*)d_in[17];
  const float* bo      = (const float*)d_in[18];
  const float* w1      = (const float*)d_in[19];
  const float* b1      = (const float*)d_in[20];
  const float* w2      = (const float*)d_in[21];
  const float* b2      = (const float*)d_in[22];
  const float* ln1w    = (const float*)d_in[23];
  const float* ln1b    = (const float*)d_in[24];
  const float* ln2w    = (const float*)d_in[25];
  const float* ln2b    = (const float*)d_in[26];

  const int* src0 = ei;
  const int* dst0 = ei + E_;

  char* p = (char*)d_ws;
  auto alloc = [&](size_t bytes){ void* r = (void*)p; p += (bytes + 255) & ~(size_t)255; return r; };
  int* cnt   = (int*)alloc((size_t)N_*4);
  int* off   = (int*)alloc((size_t)(N_+1)*4);
  int* pos   = (int*)alloc((size_t)N_*4);
  int* eid   = (int*)alloc((size_t)E_*4);
  float* sl  = (float*)alloc((size_t)T_*N_*2*4);
  float* hA  = (float*)alloc((size_t)T_*N_*G_*4);
  float* hB  = (float*)alloc((size_t)T_*N_*G_*4);
  float* xl  = (float*)alloc((size_t)T_*N_*HC_*4);
  float* xr  = (float*)alloc((size_t)T_*N_*HC_*4);
  float* lg  = (float*)alloc((size_t)T_*ET_*4*4);
  float* pooled = (float*)alloc(64*128*4);
  float* tok    = (float*)alloc(64*512*4);
  float* qkv    = (float*)alloc(64*1536*4);
  float* attno  = (float*)alloc(64*512*4);
  float* mo     = (float*)alloc(64*512*4);
  float* f1     = (float*)alloc(64*2048*4);

  float* y    = (float*)d_out;          // [B,T,D] transformer state, final output 1
  float* mout = y + B_*T_*D_;           // motion, final output 2

  // CSR + self-loop attrs
  k_zero_i  <<<dim3((N_+255)/256), dim3(256), 0, stream>>>(cnt, N_);
  k_count   <<<dim3((E_+255)/256), dim3(256), 0, stream>>>(dst0, cnt);
  k_scan    <<<dim3(1), dim3(256), 0, stream>>>(cnt, off, pos);
  k_scatter <<<dim3((E_+255)/256), dim3(256), 0, stream>>>(dst0, pos, eid);
  k_sl      <<<dim3((T_*N_+255)/256), dim3(256), 0, stream>>>(eattr, off, eid, sl);

  // input projection
  k_gemm<0><<<dim3(1, (T_*N_)/64), dim3(256), 0, stream>>>(x, proj_w, proj_b, hA, T_*N_, G_, IND_);

  float* hcur = hA; float* hnext = hB;
  for (int i = 0; i < 3; ++i){
    k_gemm_lr<<<dim3(2*HC_/64, (T_*N_)/64), dim3(256), 0, stream>>>(hcur,
        gat_wl + (size_t)i*HC_*G_, gat_wr + (size_t)i*HC_*G_, xl, xr);
    k_edge<<<dim3((T_*ET_)/4), dim3(256), 0, stream>>>(xl, xr, eattr, sl, src0, dst0,
        gat_we + (size_t)i*HC_*2, gat_att + (size_t)i*HC_, lg);
    k_node<<<dim3((T_*N_)/4), dim3(256), 0, stream>>>(xl, lg, off, eid, src0, hcur,
        gat_b + i*G_, ln_w + i*G_, ln_b + i*G_, hnext);
    float* tmp = hcur; hcur = hnext; hnext = tmp;
  }

  // pool + node2token
  k_pool<<<dim3(T_*B_), dim3(256), 0, stream>>>(hcur, pooled);
  k_gemm<0><<<dim3(D_/64, 1), dim3(256), 0, stream>>>(pooled, n2t_w, n2t_b, tok, T_*B_, D_, 128);
  k_tokout<<<dim3((B_*T_*D_+255)/256), dim3(256), 0, stream>>>(tok, y, mout);

  // transformer encoder, 2 layers
  for (int l = 0; l < 2; ++l){
    k_gemm<0><<<dim3(1536/64, 1), dim3(256), 0, stream>>>(y, wqkv + (size_t)l*1536*512, bqkv + l*1536, qkv, 64, 1536, 512);
    k_mha<<<dim3(64), dim3(64), 0, stream>>>(qkv, attno);
    k_gemm<0><<<dim3(512/64, 1), dim3(256), 0, stream>>>(attno, wo + (size_t)l*512*512, bo + l*512, mo, 64, 512, 512);
    k_lnadd<<<dim3(16), dim3(256), 0, stream>>>(y, mo, ln1w + l*512, ln1b + l*512);
    k_gemm<1><<<dim3(2048/64, 1), dim3(256), 0, stream>>>(y, w1 + (size_t)l*2048*512, b1 + l*2048, f1, 64, 2048, 512);
    k_gemm<0><<<dim3(512/64, 1), dim3(256), 0, stream>>>(f1, w2 + (size_t)l*512*2048, b2 + l*512, mo, 64, 512, 2048);
    k_lnadd<<<dim3(16), dim3(256), 0, stream>>>(y, mo, ln2w + l*512, ln2b + l*512);
  }
}

// Round 3
// 981.923 us; speedup vs baseline: 1.0153x; 1.0153x over previous
//
#include <hip/hip_runtime.h>
#include <math.h>

#define T_ 8
#define N_ 3200
#define E_ 25600
#define ET_ 28800   // E_ + N_
#define B_ 8
#define NP_ 400
#define IND_ 128
#define G_ 64
#define HC_ 256
#define D_ 512
#define NEG_ 0.2f
#define EPS_ 1e-5f

__device__ __forceinline__ float wred_sum(float v){
#pragma unroll
  for (int o = 32; o; o >>= 1) v += __shfl_xor(v, o, 64);
  return v;
}

// ---------------- CSR build ----------------
__global__ void k_zero_i(int* p, int n){
  int i = blockIdx.x*256 + threadIdx.x;
  if (i < n) p[i] = 0;
}

__global__ void k_count(const int* __restrict__ dst, int* __restrict__ cnt){
  int e = blockIdx.x*256 + threadIdx.x;
  if (e < E_) atomicAdd(&cnt[dst[e]], 1);
}

__global__ void k_scan(const int* __restrict__ cnt, int* __restrict__ off, int* __restrict__ pos){
  __shared__ int part[256];
  int tid = threadIdx.x;
  const int CH = 13;               // 256*13 = 3328 >= 3200
  int base = tid*CH;
  int s = 0;
  for (int i = 0; i < CH; ++i){ int idx = base+i; s += (idx < N_) ? cnt[idx] : 0; }
  part[tid] = s; __syncthreads();
  for (int d = 1; d < 256; d <<= 1){
    int v = (tid >= d) ? part[tid-d] : 0;
    __syncthreads();
    part[tid] += v;
    __syncthreads();
  }
  int run = tid ? part[tid-1] : 0;
  for (int i = 0; i < CH; ++i){
    int idx = base+i;
    if (idx < N_){ off[idx] = run; pos[idx] = run; run += cnt[idx]; }
  }
  if (tid == 255) off[N_] = part[255];
}

__global__ void k_scatter(const int* __restrict__ dst, int* __restrict__ pos, int* __restrict__ eid){
  int e = blockIdx.x*256 + threadIdx.x;
  if (e < E_){ int p = atomicAdd(&pos[dst[e]], 1); eid[p] = e; }
}

// self-loop attr: per-target mean of incoming edge_attr
__global__ void k_sl(const float* __restrict__ ea, const int* __restrict__ off,
                     const int* __restrict__ eid, float* __restrict__ sl){
  int idx = blockIdx.x*256 + threadIdx.x;
  if (idx >= T_*N_) return;
  int t = idx / N_, n = idx % N_;
  int o = off[n], d = off[n+1] - o;
  float s0 = 0.f, s1 = 0.f;
  for (int j = 0; j < d; ++j){
    int e = eid[o+j];
    const float* p = ea + ((size_t)t*E_ + e)*2;
    s0 += p[0]; s1 += p[1];
  }
  float c = fmaxf((float)d, 1.f);
  sl[(size_t)idx*2]   = s0 / c;
  sl[(size_t)idx*2+1] = s1 / c;
}

// ---------------- generic GEMM tile body: C[M,N] = A[M,K] @ W[N,K]^T (+bias)(+relu) ----
// requires M%64==0, N%64==0, K%32==0 (tile fully in-bounds)
template<int ACT>
__device__ __forceinline__ void gemm_tile(const float* __restrict__ A, const float* __restrict__ W,
                                          const float* __restrict__ bias, float* __restrict__ C,
                                          int N, int K, int row0, int col0){
  __shared__ float As[32][68];
  __shared__ float Ws[32][68];
  const int tid = threadIdx.x;
  const int tr = tid >> 4, tc = tid & 15;
  const int lm = tid >> 2;          // 0..63
  const int lk = (tid & 3)*8;       // 0,8,16,24
  float acc[4][4] = {};
  for (int k0 = 0; k0 < K; k0 += 32){
    const float* Ap = A + (size_t)(row0+lm)*K + k0 + lk;
    const float* Wp = W + (size_t)(col0+lm)*K + k0 + lk;
#pragma unroll
    for (int j = 0; j < 8; ++j) As[lk+j][lm] = Ap[j];
#pragma unroll
    for (int j = 0; j < 8; ++j) Ws[lk+j][lm] = Wp[j];
    __syncthreads();
#pragma unroll
    for (int kk = 0; kk < 32; ++kk){
      float av[4], wv[4];
      *(float4*)av = *(const float4*)&As[kk][tr*4];
      *(float4*)wv = *(const float4*)&Ws[kk][tc*4];
#pragma unroll
      for (int i = 0; i < 4; ++i)
#pragma unroll
        for (int j = 0; j < 4; ++j)
          acc[i][j] = fmaf(av[i], wv[j], acc[i][j]);
    }
    __syncthreads();
  }
#pragma unroll
  for (int i = 0; i < 4; ++i){
    int r = row0 + tr*4 + i;
    float* Cr = C + (size_t)r*N + col0 + tc*4;
#pragma unroll
    for (int j = 0; j < 4; ++j){
      float v = acc[i][j];
      if (bias) v += bias[col0 + tc*4 + j];
      if (ACT == 1) v = fmaxf(v, 0.f);
      Cr[j] = v;
    }
  }
}

template<int ACT>
__global__ __launch_bounds__(256) void k_gemm(const float* __restrict__ A, const float* __restrict__ W,
                                              const float* __restrict__ bias, float* __restrict__ C,
                                              int M, int N, int K){
  gemm_tile<ACT>(A, W, bias, C, N, K, blockIdx.y*64, blockIdx.x*64);
}

// fused xl/xr: blocks with blockIdx.x < HC_/64 compute A@Wl^T -> xl, others A@Wr^T -> xr
__global__ __launch_bounds__(256) void k_gemm_lr(const float* __restrict__ A,
                                                 const float* __restrict__ Wl, const float* __restrict__ Wr,
                                                 float* __restrict__ xl, float* __restrict__ xr){
  int bx = blockIdx.x;
  if (bx < HC_/64)
    gemm_tile<0>(A, Wl, nullptr, xl, HC_, G_, blockIdx.y*64, bx*64);
  else
    gemm_tile<0>(A, Wr, nullptr, xr, HC_, G_, blockIdx.y*64, (bx - HC_/64)*64);
}

// ---------------- thin GEMM (M == 64): C[64,N] = A[64,K] @ W[N,K]^T (+bias)(+relu)
// wave per output column, lane per row. Grid = N/4 blocks of 256.
// Lane r streams A-row r (float4, L1-line reuse); W-row col read once per wave.
template<int ACT>
__global__ __launch_bounds__(256) void k_thin(const float* __restrict__ A, const float* __restrict__ W,
                                              const float* __restrict__ bias, float* __restrict__ C,
                                              int N, int K){
  const int col = blockIdx.x*4 + (threadIdx.x >> 6);
  const int row = threadIdx.x & 63;
  const float4* a4 = (const float4*)(A + (size_t)row*K);
  const float4* w4 = (const float4*)(W + (size_t)col*K);
  const int K4 = K >> 2;
  float acc = 0.f;
#pragma unroll 4
  for (int k = 0; k < K4; ++k){
    float4 a = a4[k], w = w4[k];
    acc = fmaf(a.x, w.x, fmaf(a.y, w.y, fmaf(a.z, w.z, fmaf(a.w, w.w, acc))));
  }
  float v = acc + bias[col];
  if (ACT == 1) v = fmaxf(v, 0.f);
  C[(size_t)row*N + col] = v;
}

// ---------------- GAT edge logits ----------------
// one wave per (t, edge); logit[t*ET+e][h] = sum_c att[h,c]*leaky(xl[src]+xr[dst]+ee)
__global__ __launch_bounds__(256) void k_edge(const float* __restrict__ xl, const float* __restrict__ xr,
                                              const float* __restrict__ ea, const float* __restrict__ sl,
                                              const int* __restrict__ srcv, const int* __restrict__ dstv,
                                              const float* __restrict__ we, const float* __restrict__ att,
                                              float* __restrict__ logit){
  int w = blockIdx.x*4 + (threadIdx.x >> 6);
  if (w >= T_*ET_) return;
  int lane = threadIdx.x & 63;
  int t = w / ET_, e = w % ET_;
  int s, d; float a0, a1;
  if (e < E_){
    s = srcv[e]; d = dstv[e];
    const float* p = ea + ((size_t)t*E_ + e)*2;
    a0 = p[0]; a1 = p[1];
  } else {
    s = d = e - E_;
    const float* p = sl + ((size_t)t*N_ + s)*2;
    a0 = p[0]; a1 = p[1];
  }
  const float* xls = xl + ((size_t)t*N_ + s)*HC_;
  const float* xrd = xr + ((size_t)t*N_ + d)*HC_;
  float acc[4];
#pragma unroll
  for (int h = 0; h < 4; ++h){
    int c = h*64 + lane;
    float v = xls[c] + xrd[c] + a0*we[c*2] + a1*we[c*2+1];
    v = (v >= 0.f) ? v : NEG_*v;
    acc[h] = v * att[c];
  }
#pragma unroll
  for (int o = 32; o; o >>= 1){
#pragma unroll
    for (int h = 0; h < 4; ++h) acc[h] += __shfl_xor(acc[h], o, 64);
  }
  if (lane == 0){
    float4 r = make_float4(acc[0], acc[1], acc[2], acc[3]);
    *(float4*)&logit[(size_t)w*4] = r;
  }
}

// ---------------- GAT node: segment softmax + aggregate + mean-heads + bias + relu + residual + LN
__global__ __launch_bounds__(256) void k_node(const float* __restrict__ xl, const float* __restrict__ logit,
                                              const int* __restrict__ off, const int* __restrict__ eid,
                                              const int* __restrict__ srcv,
                                              const float* __restrict__ hin, const float* __restrict__ gb,
                                              const float* __restrict__ lw, const float* __restrict__ lb,
                                              float* __restrict__ hout){
  int w = blockIdx.x*4 + (threadIdx.x >> 6);
  if (w >= T_*N_) return;
  int lane = threadIdx.x & 63;
  int t = w / N_, n = w % N_;
  int o = off[n], deg = off[n+1] - o, deg1 = deg + 1;
  const float4* lg = (const float4*)logit + (size_t)t*ET_;

  float4 mx = make_float4(-1e30f, -1e30f, -1e30f, -1e30f);
  for (int j = lane; j < deg1; j += 64){
    int e = (j < deg) ? eid[o+j] : (E_ + n);
    float4 l = lg[e];
    mx.x = fmaxf(mx.x, l.x); mx.y = fmaxf(mx.y, l.y);
    mx.z = fmaxf(mx.z, l.z); mx.w = fmaxf(mx.w, l.w);
  }
#pragma unroll
  for (int o2 = 32; o2; o2 >>= 1){
    mx.x = fmaxf(mx.x, __shfl_xor(mx.x, o2, 64));
    mx.y = fmaxf(mx.y, __shfl_xor(mx.y, o2, 64));
    mx.z = fmaxf(mx.z, __shfl_xor(mx.z, o2, 64));
    mx.w = fmaxf(mx.w, __shfl_xor(mx.w, o2, 64));
  }
  float4 sm = make_float4(0.f, 0.f, 0.f, 0.f);
  for (int j = lane; j < deg1; j += 64){
    int e = (j < deg) ? eid[o+j] : (E_ + n);
    float4 l = lg[e];
    sm.x += expf(l.x - mx.x); sm.y += expf(l.y - mx.y);
    sm.z += expf(l.z - mx.z); sm.w += expf(l.w - mx.w);
  }
  sm.x = wred_sum(sm.x); sm.y = wred_sum(sm.y);
  sm.z = wred_sum(sm.z); sm.w = wred_sum(sm.w);
  float4 rs = make_float4(1.f/sm.x, 1.f/sm.y, 1.f/sm.z, 1.f/sm.w);

  float acc = 0.f;
  for (int j = 0; j < deg1; ++j){
    int e, s;
    if (j < deg){ e = eid[o+j]; s = srcv[e]; } else { e = E_ + n; s = n; }
    float4 l = lg[e];
    float w0 = expf(l.x - mx.x)*rs.x;
    float w1 = expf(l.y - mx.y)*rs.y;
    float w2 = expf(l.z - mx.z)*rs.z;
    float w3 = expf(l.w - mx.w)*rs.w;
    const float* xp = xl + ((size_t)t*N_ + s)*HC_;
    acc += w0*xp[lane] + w1*xp[64+lane] + w2*xp[128+lane] + w3*xp[192+lane];
  }
  float v = 0.25f*acc + gb[lane];
  v = fmaxf(v, 0.f);                      // relu
  v += hin[((size_t)t*N_ + n)*G_ + lane]; // residual
  float mu = wred_sum(v) * (1.f/64.f);
  float dd = v - mu;
  float var = wred_sum(dd*dd) * (1.f/64.f);
  float rstd = 1.f / sqrtf(var + EPS_);
  hout[((size_t)t*N_ + n)*G_ + lane] = dd*rstd*lw[lane] + lb[lane];
}

// ---------------- pooling: mean/max over 400 nodes per (t,graph) ----------------
__global__ __launch_bounds__(256) void k_pool(const float* __restrict__ h, float* __restrict__ pooled){
  int tb = blockIdx.x;                 // t*8+b
  int t = tb >> 3, b = tb & 7;
  int lane = threadIdx.x & 63, w = threadIdx.x >> 6;
  const float* hp = h + ((size_t)t*N_ + b*NP_)*G_;
  float s = 0.f, m = -1e30f;
  for (int n = w*100; n < (w+1)*100; ++n){
    float v = hp[(size_t)n*G_ + lane];
    s += v; m = fmaxf(m, v);
  }
  __shared__ float ss[4][64], mm[4][64];
  ss[w][lane] = s; mm[w][lane] = m;
  __syncthreads();
  if (w == 0){
    s = ss[0][lane] + ss[1][lane] + ss[2][lane] + ss[3][lane];
    m = fmaxf(fmaxf(mm[0][lane], mm[1][lane]), fmaxf(mm[2][lane], mm[3][lane]));
    float* pr = pooled + (size_t)tb*128;
    pr[lane] = s * (1.f/400.f);
    pr[64+lane] = m;
  }
}

// ---------------- fused transpose (tok->y) + motion ----------------
__global__ void k_tokout(const float* __restrict__ tok, float* __restrict__ y, float* __restrict__ mo){
  int i = blockIdx.x*256 + threadIdx.x;
  if (i >= B_*T_*D_) return;
  int c = i & 511;
  int t = (i >> 9) & 7;
  int b = i >> 12;
  float v = tok[((size_t)t*B_ + b)*D_ + c];
  y[i] = v;
  if (c < 256 && t < 7)
    mo[((size_t)b*7 + t)*256 + c] = tok[((size_t)(t+1)*B_ + b)*D_ + c] - v;
}

// ---------------- MHA: one block per (batch, head) ----------------
__global__ __launch_bounds__(64) void k_mha(const float* __restrict__ qkv, float* __restrict__ o){
  int bh = blockIdx.x;
  int b = bh >> 3, hd = bh & 7;
  __shared__ float q[8][64], k[8][64], v[8][64], p[8][8];
  int tid = threadIdx.x;
  int tt = tid >> 3, d0 = (tid & 7)*8;
  const float* qr = qkv + ((size_t)(b*8 + tt))*1536 + hd*64 + d0;
#pragma unroll
  for (int j = 0; j < 8; ++j){
    q[tt][d0+j] = qr[j];
    k[tt][d0+j] = qr[512+j];
    v[tt][d0+j] = qr[1024+j];
  }
  __syncthreads();
  int tq = tid >> 3, tk = tid & 7;
  float s = 0.f;
#pragma unroll
  for (int d = 0; d < 64; ++d) s += q[tq][d]*k[tk][d];
  p[tq][tk] = s * 0.125f;
  __syncthreads();
  if (tid < 8){
    float mx = -1e30f;
#pragma unroll
    for (int j = 0; j < 8; ++j) mx = fmaxf(mx, p[tid][j]);
    float smv = 0.f;
#pragma unroll
    for (int j = 0; j < 8; ++j){ float e = expf(p[tid][j]-mx); p[tid][j] = e; smv += e; }
    float r = 1.f/smv;
#pragma unroll
    for (int j = 0; j < 8; ++j) p[tid][j] *= r;
  }
  __syncthreads();
  float out[8];
#pragma unroll
  for (int j = 0; j < 8; ++j) out[j] = 0.f;
#pragma unroll
  for (int t2 = 0; t2 < 8; ++t2){
    float wv = p[tq][t2];
#pragma unroll
    for (int j = 0; j < 8; ++j) out[j] = fmaf(wv, v[t2][d0+j], out[j]);
  }
  float* orow = o + ((size_t)(b*8 + tq))*D_ + hd*64 + d0;
#pragma unroll
  for (int j = 0; j < 8; ++j) orow[j] = out[j];
}

// ---------------- residual + LayerNorm over 512, wave per row ----------------
__global__ __launch_bounds__(256) void k_lnadd(float* __restrict__ y, const float* __restrict__ res,
                                               const float* __restrict__ w, const float* __restrict__ b){
  int row = blockIdx.x*4 + (threadIdx.x >> 6);
  int lane = threadIdx.x & 63;
  float* yr = y + (size_t)row*D_;
  const float* rr = res + (size_t)row*D_;
  float v[8]; float s = 0.f;
#pragma unroll
  for (int i = 0; i < 8; ++i){ v[i] = yr[lane + i*64] + rr[lane + i*64]; s += v[i]; }
  s = wred_sum(s);
  float mu = s * (1.f/512.f);
  float qq = 0.f;
#pragma unroll
  for (int i = 0; i < 8; ++i){ float d = v[i]-mu; qq += d*d; }
  qq = wred_sum(qq);
  float rstd = 1.f / sqrtf(qq*(1.f/512.f) + EPS_);
#pragma unroll
  for (int i = 0; i < 8; ++i){
    int c = lane + i*64;
    yr[c] = (v[i]-mu)*rstd*w[c] + b[c];
  }
}

extern "C" void kernel_launch(void* const* d_in, const int* in_sizes, int n_in,
                              void* d_out, int out_size, void* d_ws, size_t ws_size,
                              hipStream_t stream){
  const float* x       = (const float*)d_in[0];
  const int*   ei      = (const int*)d_in[1];
  const float* eattr   = (const float*)d_in[2];
  const float* proj_w  = (const float*)d_in[4];
  const float* proj_b  = (const float*)d_in[5];
  const float* gat_wl  = (const float*)d_in[6];
  const float* gat_wr  = (const float*)d_in[7];
  const float* gat_we  = (const float*)d_in[8];
  const float* gat_att = (const float*)d_in[9];
  const float* gat_b   = (const float*)d_in[10];
  const float* ln_w    = (const float*)d_in[11];
  const float* ln_b    = (const float*)d_in[12];
  const float* n2t_w   = (const float*)d_in[13];
  const float* n2t_b   = (const float*)d_in[14];
  const float* wqkv    = (const float*)d_in[15];
  const float* bqkv    = (const float*)d_in[16];
  const float* wo      = (const float*)d_in[17];
  const float* bo      = (const float*)d_in[18];
  const float* w1      = (const float*)d_in[19];
  const float* b1      = (const float*)d_in[20];
  const float* w2      = (const float*)d_in[21];
  const float* b2      = (const float*)d_in[22];
  const float* ln1w    = (const float*)d_in[23];
  const float* ln1b    = (const float*)d_in[24];
  const float* ln2w    = (const float*)d_in[25];
  const float* ln2b    = (const float*)d_in[26];

  const int* src0 = ei;
  const int* dst0 = ei + E_;

  char* p = (char*)d_ws;
  auto alloc = [&](size_t bytes){ void* r = (void*)p; p += (bytes + 255) & ~(size_t)255; return r; };
  int* cnt   = (int*)alloc((size_t)N_*4);
  int* off   = (int*)alloc((size_t)(N_+1)*4);
  int* pos   = (int*)alloc((size_t)N_*4);
  int* eid   = (int*)alloc((size_t)E_*4);
  float* sl  = (float*)alloc((size_t)T_*N_*2*4);
  float* hA  = (float*)alloc((size_t)T_*N_*G_*4);
  float* hB  = (float*)alloc((size_t)T_*N_*G_*4);
  float* xl  = (float*)alloc((size_t)T_*N_*HC_*4);
  float* xr  = (float*)alloc((size_t)T_*N_*HC_*4);
  float* lg  = (float*)alloc((size_t)T_*ET_*4*4);
  float* pooled = (float*)alloc(64*128*4);
  float* tok    = (float*)alloc(64*512*4);
  float* qkv    = (float*)alloc(64*1536*4);
  float* attno  = (float*)alloc(64*512*4);
  float* mo     = (float*)alloc(64*512*4);
  float* f1     = (float*)alloc(64*2048*4);

  float* y    = (float*)d_out;          // [B,T,D] transformer state, final output 1
  float* mout = y + B_*T_*D_;           // motion, final output 2

  // CSR + self-loop attrs
  k_zero_i  <<<dim3((N_+255)/256), dim3(256), 0, stream>>>(cnt, N_);
  k_count   <<<dim3((E_+255)/256), dim3(256), 0, stream>>>(dst0, cnt);
  k_scan    <<<dim3(1), dim3(256), 0, stream>>>(cnt, off, pos);
  k_scatter <<<dim3((E_+255)/256), dim3(256), 0, stream>>>(dst0, pos, eid);
  k_sl      <<<dim3((T_*N_+255)/256), dim3(256), 0, stream>>>(eattr, off, eid, sl);

  // input projection
  k_gemm<0><<<dim3(1, (T_*N_)/64), dim3(256), 0, stream>>>(x, proj_w, proj_b, hA, T_*N_, G_, IND_);

  float* hcur = hA; float* hnext = hB;
  for (int i = 0; i < 3; ++i){
    k_gemm_lr<<<dim3(2*HC_/64, (T_*N_)/64), dim3(256), 0, stream>>>(hcur,
        gat_wl + (size_t)i*HC_*G_, gat_wr + (size_t)i*HC_*G_, xl, xr);
    k_edge<<<dim3((T_*ET_)/4), dim3(256), 0, stream>>>(xl, xr, eattr, sl, src0, dst0,
        gat_we + (size_t)i*HC_*2, gat_att + (size_t)i*HC_, lg);
    k_node<<<dim3((T_*N_)/4), dim3(256), 0, stream>>>(xl, lg, off, eid, src0, hcur,
        gat_b + i*G_, ln_w + i*G_, ln_b + i*G_, hnext);
    float* tmp = hcur; hcur = hnext; hnext = tmp;
  }

  // pool + node2token (thin: M = T_*B_ = 64)
  k_pool<<<dim3(T_*B_), dim3(256), 0, stream>>>(hcur, pooled);
  k_thin<0><<<dim3(D_/4), dim3(256), 0, stream>>>(pooled, n2t_w, n2t_b, tok, D_, 128);
  k_tokout<<<dim3((B_*T_*D_+255)/256), dim3(256), 0, stream>>>(tok, y, mout);

  // transformer encoder, 2 layers (all GEMMs are M=64 thin)
  for (int l = 0; l < 2; ++l){
    k_thin<0><<<dim3(1536/4), dim3(256), 0, stream>>>(y, wqkv + (size_t)l*1536*512, bqkv + l*1536, qkv, 1536, 512);
    k_mha<<<dim3(64), dim3(64), 0, stream>>>(qkv, attno);
    k_thin<0><<<dim3(512/4), dim3(256), 0, stream>>>(attno, wo + (size_t)l*512*512, bo + l*512, mo, 512, 512);
    k_lnadd<<<dim3(16), dim3(256), 0, stream>>>(y, mo, ln1w + l*512, ln1b + l*512);
    k_thin<1><<<dim3(2048/4), dim3(256), 0, stream>>>(y, w1 + (size_t)l*2048*512, b1 + l*2048, f1, 2048, 512);
    k_thin<0><<<dim3(512/4), dim3(256), 0, stream>>>(f1, w2 + (size_t)l*512*2048, b2 + l*512, mo, 512, 2048);
    k_lnadd<<<dim3(16), dim3(256), 0, stream>>>(y, mo, ln2w + l*512, ln2b + l*512);
  }
}

// Round 4
// 955.540 us; speedup vs baseline: 1.0433x; 1.0276x over previous
//
#include <hip/hip_runtime.h>
#include <math.h>

#define T_ 8
#define N_ 3200
#define E_ 25600
#define ET_ 28800   // E_ + N_
#define B_ 8
#define NP_ 400
#define IND_ 128
#define G_ 64
#define HC_ 256
#define D_ 512
#define NEG_ 0.2f
#define EPS_ 1e-5f

__device__ __forceinline__ float wred_sum(float v){
#pragma unroll
  for (int o = 32; o; o >>= 1) v += __shfl_xor(v, o, 64);
  return v;
}

// ---------------- CSR build ----------------
__global__ void k_zero_i(int* p, int n){
  int i = blockIdx.x*256 + threadIdx.x;
  if (i < n) p[i] = 0;
}

__global__ void k_count(const int* __restrict__ dst, int* __restrict__ cnt){
  int e = blockIdx.x*256 + threadIdx.x;
  if (e < E_) atomicAdd(&cnt[dst[e]], 1);
}

__global__ void k_scan(const int* __restrict__ cnt, int* __restrict__ off, int* __restrict__ pos){
  __shared__ int part[256];
  int tid = threadIdx.x;
  const int CH = 13;               // 256*13 = 3328 >= 3200
  int base = tid*CH;
  int s = 0;
  for (int i = 0; i < CH; ++i){ int idx = base+i; s += (idx < N_) ? cnt[idx] : 0; }
  part[tid] = s; __syncthreads();
  for (int d = 1; d < 256; d <<= 1){
    int v = (tid >= d) ? part[tid-d] : 0;
    __syncthreads();
    part[tid] += v;
    __syncthreads();
  }
  int run = tid ? part[tid-1] : 0;
  for (int i = 0; i < CH; ++i){
    int idx = base+i;
    if (idx < N_){ off[idx] = run; pos[idx] = run; run += cnt[idx]; }
  }
  if (tid == 255) off[N_] = part[255];
}

__global__ void k_scatter(const int* __restrict__ dst, int* __restrict__ pos, int* __restrict__ eid){
  int e = blockIdx.x*256 + threadIdx.x;
  if (e < E_){ int p = atomicAdd(&pos[dst[e]], 1); eid[p] = e; }
}

// self-loop attr: per-target mean of incoming edge_attr
__global__ void k_sl(const float* __restrict__ ea, const int* __restrict__ off,
                     const int* __restrict__ eid, float* __restrict__ sl){
  int idx = blockIdx.x*256 + threadIdx.x;
  if (idx >= T_*N_) return;
  int t = idx / N_, n = idx % N_;
  int o = off[n], d = off[n+1] - o;
  float s0 = 0.f, s1 = 0.f;
  for (int j = 0; j < d; ++j){
    int e = eid[o+j];
    const float* p = ea + ((size_t)t*E_ + e)*2;
    s0 += p[0]; s1 += p[1];
  }
  float c = fmaxf((float)d, 1.f);
  sl[(size_t)idx*2]   = s0 / c;
  sl[(size_t)idx*2+1] = s1 / c;
}

// ---------------- generic GEMM tile body: C[M,N] = A[M,K] @ W[N,K]^T (+bias) ----
template<int ACT>
__device__ __forceinline__ void gemm_tile(const float* __restrict__ A, const float* __restrict__ W,
                                          const float* __restrict__ bias, float* __restrict__ C,
                                          int N, int K, int row0, int col0){
  __shared__ float As[32][68];
  __shared__ float Ws[32][68];
  const int tid = threadIdx.x;
  const int tr = tid >> 4, tc = tid & 15;
  const int lm = tid >> 2;          // 0..63
  const int lk = (tid & 3)*8;       // 0,8,16,24
  float acc[4][4] = {};
  for (int k0 = 0; k0 < K; k0 += 32){
    const float* Ap = A + (size_t)(row0+lm)*K + k0 + lk;
    const float* Wp = W + (size_t)(col0+lm)*K + k0 + lk;
#pragma unroll
    for (int j = 0; j < 8; ++j) As[lk+j][lm] = Ap[j];
#pragma unroll
    for (int j = 0; j < 8; ++j) Ws[lk+j][lm] = Wp[j];
    __syncthreads();
#pragma unroll
    for (int kk = 0; kk < 32; ++kk){
      float av[4], wv[4];
      *(float4*)av = *(const float4*)&As[kk][tr*4];
      *(float4*)wv = *(const float4*)&Ws[kk][tc*4];
#pragma unroll
      for (int i = 0; i < 4; ++i)
#pragma unroll
        for (int j = 0; j < 4; ++j)
          acc[i][j] = fmaf(av[i], wv[j], acc[i][j]);
    }
    __syncthreads();
  }
#pragma unroll
  for (int i = 0; i < 4; ++i){
    int r = row0 + tr*4 + i;
    float* Cr = C + (size_t)r*N + col0 + tc*4;
#pragma unroll
    for (int j = 0; j < 4; ++j){
      float v = acc[i][j];
      if (bias) v += bias[col0 + tc*4 + j];
      if (ACT == 1) v = fmaxf(v, 0.f);
      Cr[j] = v;
    }
  }
}

template<int ACT>
__global__ __launch_bounds__(256) void k_gemm(const float* __restrict__ A, const float* __restrict__ W,
                                              const float* __restrict__ bias, float* __restrict__ C,
                                              int M, int N, int K){
  gemm_tile<ACT>(A, W, bias, C, N, K, blockIdx.y*64, blockIdx.x*64);
}

// fused xl/xr
__global__ __launch_bounds__(256) void k_gemm_lr(const float* __restrict__ A,
                                                 const float* __restrict__ Wl, const float* __restrict__ Wr,
                                                 float* __restrict__ xl, float* __restrict__ xr){
  int bx = blockIdx.x;
  if (bx < HC_/64)
    gemm_tile<0>(A, Wl, nullptr, xl, HC_, G_, blockIdx.y*64, bx*64);
  else
    gemm_tile<0>(A, Wr, nullptr, xr, HC_, G_, blockIdx.y*64, (bx - HC_/64)*64);
}

// ---------------- thin GEMM, transposed activations ----------------
// Ct[N][64] = (At[K][64])^T @ W[N,K]^T : Ct[c][tok] = sum_k At[k][tok]*W[c][k]
// wave = 2 output features, lane = token. At reads coalesced (256B/wave-instr),
// W rows uniform float4, Ct stores coalesced. Grid = N/8 blocks of 256.
template<int ACT>
__global__ __launch_bounds__(256) void k_thin(const float* __restrict__ At, const float* __restrict__ W,
                                              const float* __restrict__ bias, float* __restrict__ Ct,
                                              int N, int K){
  const int wv = threadIdx.x >> 6;
  const int lane = threadIdx.x & 63;
  const int c0 = blockIdx.x*8 + wv*2;
  const float* w0 = W + (size_t)c0*K;
  const float* w1p = w0 + K;
  float acc0 = 0.f, acc1 = 0.f;
  for (int k = 0; k < K; k += 8){
    float a[8];
#pragma unroll
    for (int j = 0; j < 8; ++j) a[j] = At[(size_t)(k+j)*64 + lane];
    float4 wa = *(const float4*)(w0 + k);
    float4 wb = *(const float4*)(w0 + k + 4);
    float4 wc = *(const float4*)(w1p + k);
    float4 wd = *(const float4*)(w1p + k + 4);
    acc0 = fmaf(a[0], wa.x, acc0); acc1 = fmaf(a[0], wc.x, acc1);
    acc0 = fmaf(a[1], wa.y, acc0); acc1 = fmaf(a[1], wc.y, acc1);
    acc0 = fmaf(a[2], wa.z, acc0); acc1 = fmaf(a[2], wc.z, acc1);
    acc0 = fmaf(a[3], wa.w, acc0); acc1 = fmaf(a[3], wc.w, acc1);
    acc0 = fmaf(a[4], wb.x, acc0); acc1 = fmaf(a[4], wd.x, acc1);
    acc0 = fmaf(a[5], wb.y, acc0); acc1 = fmaf(a[5], wd.y, acc1);
    acc0 = fmaf(a[6], wb.z, acc0); acc1 = fmaf(a[6], wd.z, acc1);
    acc0 = fmaf(a[7], wb.w, acc0); acc1 = fmaf(a[7], wd.w, acc1);
  }
  float v0 = acc0 + bias[c0];
  float v1 = acc1 + bias[c0+1];
  if (ACT == 1){ v0 = fmaxf(v0, 0.f); v1 = fmaxf(v1, 0.f); }
  Ct[(size_t)c0*64 + lane] = v0;
  Ct[(size_t)(c0+1)*64 + lane] = v1;
}

// ---------------- GAT edge logits ----------------
__global__ __launch_bounds__(256) void k_edge(const float* __restrict__ xl, const float* __restrict__ xr,
                                              const float* __restrict__ ea, const float* __restrict__ sl,
                                              const int* __restrict__ srcv, const int* __restrict__ dstv,
                                              const float* __restrict__ we, const float* __restrict__ att,
                                              float* __restrict__ logit){
  int w = blockIdx.x*4 + (threadIdx.x >> 6);
  if (w >= T_*ET_) return;
  int lane = threadIdx.x & 63;
  int t = w / ET_, e = w % ET_;
  int s, d; float a0, a1;
  if (e < E_){
    s = srcv[e]; d = dstv[e];
    const float* p = ea + ((size_t)t*E_ + e)*2;
    a0 = p[0]; a1 = p[1];
  } else {
    s = d = e - E_;
    const float* p = sl + ((size_t)t*N_ + s)*2;
    a0 = p[0]; a1 = p[1];
  }
  const float* xls = xl + ((size_t)t*N_ + s)*HC_;
  const float* xrd = xr + ((size_t)t*N_ + d)*HC_;
  float acc[4];
#pragma unroll
  for (int h = 0; h < 4; ++h){
    int c = h*64 + lane;
    float v = xls[c] + xrd[c] + a0*we[c*2] + a1*we[c*2+1];
    v = (v >= 0.f) ? v : NEG_*v;
    acc[h] = v * att[c];
  }
#pragma unroll
  for (int o = 32; o; o >>= 1){
#pragma unroll
    for (int h = 0; h < 4; ++h) acc[h] += __shfl_xor(acc[h], o, 64);
  }
  if (lane == 0){
    float4 r = make_float4(acc[0], acc[1], acc[2], acc[3]);
    *(float4*)&logit[(size_t)w*4] = r;
  }
}

// ---------------- GAT node ----------------
__global__ __launch_bounds__(256) void k_node(const float* __restrict__ xl, const float* __restrict__ logit,
                                              const int* __restrict__ off, const int* __restrict__ eid,
                                              const int* __restrict__ srcv,
                                              const float* __restrict__ hin, const float* __restrict__ gb,
                                              const float* __restrict__ lw, const float* __restrict__ lb,
                                              float* __restrict__ hout){
  int w = blockIdx.x*4 + (threadIdx.x >> 6);
  if (w >= T_*N_) return;
  int lane = threadIdx.x & 63;
  int t = w / N_, n = w % N_;
  int o = off[n], deg = off[n+1] - o, deg1 = deg + 1;
  const float4* lg = (const float4*)logit + (size_t)t*ET_;

  float4 mx = make_float4(-1e30f, -1e30f, -1e30f, -1e30f);
  for (int j = lane; j < deg1; j += 64){
    int e = (j < deg) ? eid[o+j] : (E_ + n);
    float4 l = lg[e];
    mx.x = fmaxf(mx.x, l.x); mx.y = fmaxf(mx.y, l.y);
    mx.z = fmaxf(mx.z, l.z); mx.w = fmaxf(mx.w, l.w);
  }
#pragma unroll
  for (int o2 = 32; o2; o2 >>= 1){
    mx.x = fmaxf(mx.x, __shfl_xor(mx.x, o2, 64));
    mx.y = fmaxf(mx.y, __shfl_xor(mx.y, o2, 64));
    mx.z = fmaxf(mx.z, __shfl_xor(mx.z, o2, 64));
    mx.w = fmaxf(mx.w, __shfl_xor(mx.w, o2, 64));
  }
  float4 sm = make_float4(0.f, 0.f, 0.f, 0.f);
  for (int j = lane; j < deg1; j += 64){
    int e = (j < deg) ? eid[o+j] : (E_ + n);
    float4 l = lg[e];
    sm.x += expf(l.x - mx.x); sm.y += expf(l.y - mx.y);
    sm.z += expf(l.z - mx.z); sm.w += expf(l.w - mx.w);
  }
  sm.x = wred_sum(sm.x); sm.y = wred_sum(sm.y);
  sm.z = wred_sum(sm.z); sm.w = wred_sum(sm.w);
  float4 rs = make_float4(1.f/sm.x, 1.f/sm.y, 1.f/sm.z, 1.f/sm.w);

  float acc = 0.f;
  for (int j = 0; j < deg1; ++j){
    int e, s;
    if (j < deg){ e = eid[o+j]; s = srcv[e]; } else { e = E_ + n; s = n; }
    float4 l = lg[e];
    float w0 = expf(l.x - mx.x)*rs.x;
    float w1 = expf(l.y - mx.y)*rs.y;
    float w2 = expf(l.z - mx.z)*rs.z;
    float w3 = expf(l.w - mx.w)*rs.w;
    const float* xp = xl + ((size_t)t*N_ + s)*HC_;
    acc += w0*xp[lane] + w1*xp[64+lane] + w2*xp[128+lane] + w3*xp[192+lane];
  }
  float v = 0.25f*acc + gb[lane];
  v = fmaxf(v, 0.f);                      // relu
  v += hin[((size_t)t*N_ + n)*G_ + lane]; // residual
  float mu = wred_sum(v) * (1.f/64.f);
  float dd = v - mu;
  float var = wred_sum(dd*dd) * (1.f/64.f);
  float rstd = 1.f / sqrtf(var + EPS_);
  hout[((size_t)t*N_ + n)*G_ + lane] = dd*rstd*lw[lane] + lb[lane];
}

// ---------------- pooling -> pooled_t[128][64] (feature-major) ----------------
__global__ __launch_bounds__(256) void k_pool(const float* __restrict__ h, float* __restrict__ pooled_t){
  int tb = blockIdx.x;                 // token = t*8+b
  int t = tb >> 3, b = tb & 7;
  int lane = threadIdx.x & 63, w = threadIdx.x >> 6;
  const float* hp = h + ((size_t)t*N_ + b*NP_)*G_;
  float s = 0.f, m = -1e30f;
  for (int n = w*100; n < (w+1)*100; ++n){
    float v = hp[(size_t)n*G_ + lane];
    s += v; m = fmaxf(m, v);
  }
  __shared__ float ss[4][64], mm[4][64];
  ss[w][lane] = s; mm[w][lane] = m;
  __syncthreads();
  if (w == 0){
    s = ss[0][lane] + ss[1][lane] + ss[2][lane] + ss[3][lane];
    m = fmaxf(fmaxf(mm[0][lane], mm[1][lane]), fmaxf(mm[2][lane], mm[3][lane]));
    pooled_t[(size_t)lane*64 + tb]      = s * (1.f/400.f);
    pooled_t[(size_t)(64+lane)*64 + tb] = m;
  }
}

// ---------------- tok_t -> y, y_t, motion ----------------
// tok_t[512][64] rows = feature, cols = token (t*8+b). y rows = b*8+t.
__global__ void k_tokout(const float* __restrict__ tok_t, float* __restrict__ y,
                         float* __restrict__ yt, float* __restrict__ mo){
  int i = blockIdx.x*256 + threadIdx.x;
  if (i >= D_*64) return;
  int tk = i & 63;              // t*8+b
  int c = i >> 6;
  int t = tk >> 3, b = tk & 7;
  float v = tok_t[(size_t)c*64 + tk];
  int yrow = b*8 + t;
  y[(size_t)yrow*D_ + c] = v;
  yt[(size_t)c*64 + yrow] = v;
  if (c < 256 && t < 7)
    mo[((size_t)b*7 + t)*256 + c] = tok_t[(size_t)c*64 + (tk+8)] - v;  // (t+1)*8+b
}

// ---------------- MHA: reads qkv_t[1536][64], writes attno_t[512][64] ----------------
__global__ __launch_bounds__(64) void k_mha(const float* __restrict__ qkv_t, float* __restrict__ o_t){
  int bh = blockIdx.x;
  int b = bh >> 3, hd = bh & 7;
  __shared__ float q[8][64], k[8][64], v[8][64], p[8][8];
  int tid = threadIdx.x;
  int tt = tid >> 3, d0 = (tid & 7)*8;
  int row = b*8 + tt;           // y-row token
#pragma unroll
  for (int j = 0; j < 8; ++j){
    int f = hd*64 + d0 + j;
    q[tt][d0+j] = qkv_t[(size_t)f*64 + row];
    k[tt][d0+j] = qkv_t[(size_t)(512+f)*64 + row];
    v[tt][d0+j] = qkv_t[(size_t)(1024+f)*64 + row];
  }
  __syncthreads();
  int tq = tid >> 3, tk = tid & 7;
  float s = 0.f;
#pragma unroll
  for (int d = 0; d < 64; ++d) s += q[tq][d]*k[tk][d];
  p[tq][tk] = s * 0.125f;
  __syncthreads();
  if (tid < 8){
    float mx = -1e30f;
#pragma unroll
    for (int j = 0; j < 8; ++j) mx = fmaxf(mx, p[tid][j]);
    float smv = 0.f;
#pragma unroll
    for (int j = 0; j < 8; ++j){ float e = expf(p[tid][j]-mx); p[tid][j] = e; smv += e; }
    float r = 1.f/smv;
#pragma unroll
    for (int j = 0; j < 8; ++j) p[tid][j] *= r;
  }
  __syncthreads();
  float out[8];
#pragma unroll
  for (int j = 0; j < 8; ++j) out[j] = 0.f;
#pragma unroll
  for (int t2 = 0; t2 < 8; ++t2){
    float wv = p[tq][t2];
#pragma unroll
    for (int j = 0; j < 8; ++j) out[j] = fmaf(wv, v[t2][d0+j], out[j]);
  }
  int orow = b*8 + tq;
#pragma unroll
  for (int j = 0; j < 8; ++j) o_t[(size_t)(hd*64 + d0 + j)*64 + orow] = out[j];
}

// ---------------- residual(+transposed res) + LayerNorm; writes y and y_t ----------------
__global__ __launch_bounds__(256) void k_lnadd(float* __restrict__ y, float* __restrict__ yt,
                                               const float* __restrict__ res_t,
                                               const float* __restrict__ w, const float* __restrict__ b){
  int row = blockIdx.x*4 + (threadIdx.x >> 6);
  int lane = threadIdx.x & 63;
  float* yr = y + (size_t)row*D_;
  float v[8]; float s = 0.f;
#pragma unroll
  for (int i = 0; i < 8; ++i){
    int c = lane + i*64;
    v[i] = yr[c] + res_t[(size_t)c*64 + row];
    s += v[i];
  }
  s = wred_sum(s);
  float mu = s * (1.f/512.f);
  float qq = 0.f;
#pragma unroll
  for (int i = 0; i < 8; ++i){ float d = v[i]-mu; qq += d*d; }
  qq = wred_sum(qq);
  float rstd = 1.f / sqrtf(qq*(1.f/512.f) + EPS_);
#pragma unroll
  for (int i = 0; i < 8; ++i){
    int c = lane + i*64;
    float ov = (v[i]-mu)*rstd*w[c] + b[c];
    yr[c] = ov;
    yt[(size_t)c*64 + row] = ov;
  }
}

extern "C" void kernel_launch(void* const* d_in, const int* in_sizes, int n_in,
                              void* d_out, int out_size, void* d_ws, size_t ws_size,
                              hipStream_t stream){
  const float* x       = (const float*)d_in[0];
  const int*   ei      = (const int*)d_in[1];
  const float* eattr   = (const float*)d_in[2];
  const float* proj_w  = (const float*)d_in[4];
  const float* proj_b  = (const float*)d_in[5];
  const float* gat_wl  = (const float*)d_in[6];
  const float* gat_wr  = (const float*)d_in[7];
  const float* gat_we  = (const float*)d_in[8];
  const float* gat_att = (const float*)d_in[9];
  const float* gat_b   = (const float*)d_in[10];
  const float* ln_w    = (const float*)d_in[11];
  const float* ln_b    = (const float*)d_in[12];
  const float* n2t_w   = (const float*)d_in[13];
  const float* n2t_b   = (const float*)d_in[14];
  const float* wqkv    = (const float*)d_in[15];
  const float* bqkv    = (const float*)d_in[16];
  const float* wo      = (const float*)d_in[17];
  const float* bo      = (const float*)d_in[18];
  const float* w1      = (const float*)d_in[19];
  const float* b1      = (const float*)d_in[20];
  const float* w2      = (const float*)d_in[21];
  const float* b2      = (const float*)d_in[22];
  const float* ln1w    = (const float*)d_in[23];
  const float* ln1b    = (const float*)d_in[24];
  const float* ln2w    = (const float*)d_in[25];
  const float* ln2b    = (const float*)d_in[26];

  const int* src0 = ei;
  const int* dst0 = ei + E_;

  char* p = (char*)d_ws;
  auto alloc = [&](size_t bytes){ void* r = (void*)p; p += (bytes + 255) & ~(size_t)255; return r; };
  int* cnt   = (int*)alloc((size_t)N_*4);
  int* off   = (int*)alloc((size_t)(N_+1)*4);
  int* pos   = (int*)alloc((size_t)N_*4);
  int* eid   = (int*)alloc((size_t)E_*4);
  float* sl  = (float*)alloc((size_t)T_*N_*2*4);
  float* hA  = (float*)alloc((size_t)T_*N_*G_*4);
  float* hB  = (float*)alloc((size_t)T_*N_*G_*4);
  float* xl  = (float*)alloc((size_t)T_*N_*HC_*4);
  float* xr  = (float*)alloc((size_t)T_*N_*HC_*4);
  float* lg  = (float*)alloc((size_t)T_*ET_*4*4);
  float* pooled_t = (float*)alloc(128*64*4);
  float* tok_t    = (float*)alloc(512*64*4);
  float* yt       = (float*)alloc(512*64*4);
  float* qkv_t    = (float*)alloc(1536*64*4);
  float* attno_t  = (float*)alloc(512*64*4);
  float* mo_t     = (float*)alloc(512*64*4);
  float* f1t      = (float*)alloc(2048*64*4);

  float* y    = (float*)d_out;          // [B,T,D] transformer state, final output 1
  float* mout = y + B_*T_*D_;           // motion, final output 2

  // CSR + self-loop attrs
  k_zero_i  <<<dim3((N_+255)/256), dim3(256), 0, stream>>>(cnt, N_);
  k_count   <<<dim3((E_+255)/256), dim3(256), 0, stream>>>(dst0, cnt);
  k_scan    <<<dim3(1), dim3(256), 0, stream>>>(cnt, off, pos);
  k_scatter <<<dim3((E_+255)/256), dim3(256), 0, stream>>>(dst0, pos, eid);
  k_sl      <<<dim3((T_*N_+255)/256), dim3(256), 0, stream>>>(eattr, off, eid, sl);

  // input projection
  k_gemm<0><<<dim3(1, (T_*N_)/64), dim3(256), 0, stream>>>(x, proj_w, proj_b, hA, T_*N_, G_, IND_);

  float* hcur = hA; float* hnext = hB;
  for (int i = 0; i < 3; ++i){
    k_gemm_lr<<<dim3(2*HC_/64, (T_*N_)/64), dim3(256), 0, stream>>>(hcur,
        gat_wl + (size_t)i*HC_*G_, gat_wr + (size_t)i*HC_*G_, xl, xr);
    k_edge<<<dim3((T_*ET_)/4), dim3(256), 0, stream>>>(xl, xr, eattr, sl, src0, dst0,
        gat_we + (size_t)i*HC_*2, gat_att + (size_t)i*HC_, lg);
    k_node<<<dim3((T_*N_)/4), dim3(256), 0, stream>>>(xl, lg, off, eid, src0, hcur,
        gat_b + i*G_, ln_w + i*G_, ln_b + i*G_, hnext);
    float* tmp = hcur; hcur = hnext; hnext = tmp;
  }

  // pool + node2token (transposed chain)
  k_pool<<<dim3(T_*B_), dim3(256), 0, stream>>>(hcur, pooled_t);
  k_thin<0><<<dim3(D_/8), dim3(256), 0, stream>>>(pooled_t, n2t_w, n2t_b, tok_t, D_, 128);
  k_tokout<<<dim3((D_*64+255)/256), dim3(256), 0, stream>>>(tok_t, y, yt, mout);

  // transformer encoder, 2 layers (feature-major activations)
  for (int l = 0; l < 2; ++l){
    k_thin<0><<<dim3(1536/8), dim3(256), 0, stream>>>(yt, wqkv + (size_t)l*1536*512, bqkv + l*1536, qkv_t, 1536, 512);
    k_mha<<<dim3(64), dim3(64), 0, stream>>>(qkv_t, attno_t);
    k_thin<0><<<dim3(512/8), dim3(256), 0, stream>>>(attno_t, wo + (size_t)l*512*512, bo + l*512, mo_t, 512, 512);
    k_lnadd<<<dim3(16), dim3(256), 0, stream>>>(y, yt, mo_t, ln1w + l*512, ln1b + l*512);
    k_thin<1><<<dim3(2048/8), dim3(256), 0, stream>>>(yt, w1 + (size_t)l*2048*512, b1 + l*2048, f1t, 2048, 512);
    k_thin<0><<<dim3(512/8), dim3(256), 0, stream>>>(f1t, w2 + (size_t)l*512*2048, b2 + l*512, mo_t, 512, 2048);
    k_lnadd<<<dim3(16), dim3(256), 0, stream>>>(y, yt, mo_t, ln2w + l*512, ln2b + l*512);
  }
}

// Round 6
// 932.764 us; speedup vs baseline: 1.0688x; 1.0244x over previous
//
#include <hip/hip_runtime.h>
#include <math.h>

#define T_ 8
#define N_ 3200
#define E_ 25600
#define ET_ 28800   // E_ + N_
#define B_ 8
#define NP_ 400
#define IND_ 128
#define G_ 64
#define HC_ 256
#define D_ 512
#define NEG_ 0.2f
#define EPS_ 1e-5f

__device__ __forceinline__ float wred_sum(float v){
#pragma unroll
  for (int o = 32; o; o >>= 1) v += __shfl_xor(v, o, 64);
  return v;
}

// ---------------- CSR build ----------------
__global__ void k_zero_i(int* p, int n){
  int i = blockIdx.x*256 + threadIdx.x;
  if (i < n) p[i] = 0;
}

__global__ void k_count(const int* __restrict__ dst, int* __restrict__ cnt){
  int e = blockIdx.x*256 + threadIdx.x;
  if (e < E_) atomicAdd(&cnt[dst[e]], 1);
}

__global__ void k_scan(const int* __restrict__ cnt, int* __restrict__ off, int* __restrict__ pos){
  __shared__ int part[256];
  int tid = threadIdx.x;
  const int CH = 13;               // 256*13 = 3328 >= 3200
  int base = tid*CH;
  int s = 0;
  for (int i = 0; i < CH; ++i){ int idx = base+i; s += (idx < N_) ? cnt[idx] : 0; }
  part[tid] = s; __syncthreads();
  for (int d = 1; d < 256; d <<= 1){
    int v = (tid >= d) ? part[tid-d] : 0;
    __syncthreads();
    part[tid] += v;
    __syncthreads();
  }
  int run = tid ? part[tid-1] : 0;
  for (int i = 0; i < CH; ++i){
    int idx = base+i;
    if (idx < N_){ off[idx] = run; pos[idx] = run; run += cnt[idx]; }
  }
  if (tid == 255) off[N_] = part[255];
}

__global__ void k_scatter(const int* __restrict__ dst, int* __restrict__ pos, int* __restrict__ eid){
  int e = blockIdx.x*256 + threadIdx.x;
  if (e < E_){ int p = atomicAdd(&pos[dst[e]], 1); eid[p] = e; }
}

// self-loop attr: per-target mean of incoming edge_attr
__global__ void k_sl(const float* __restrict__ ea, const int* __restrict__ off,
                     const int* __restrict__ eid, float* __restrict__ sl){
  int idx = blockIdx.x*256 + threadIdx.x;
  if (idx >= T_*N_) return;
  int t = idx / N_, n = idx % N_;
  int o = off[n], d = off[n+1] - o;
  float s0 = 0.f, s1 = 0.f;
  for (int j = 0; j < d; ++j){
    int e = eid[o+j];
    const float* p = ea + ((size_t)t*E_ + e)*2;
    s0 += p[0]; s1 += p[1];
  }
  float c = fmaxf((float)d, 1.f);
  sl[(size_t)idx*2]   = s0 / c;
  sl[(size_t)idx*2+1] = s1 / c;
}

// ---------------- generic GEMM tile body: C[M,N] = A[M,K] @ W[N,K]^T (+bias) ----
template<int ACT>
__device__ __forceinline__ void gemm_tile(const float* __restrict__ A, const float* __restrict__ W,
                                          const float* __restrict__ bias, float* __restrict__ C,
                                          int N, int K, int row0, int col0){
  __shared__ float As[32][68];
  __shared__ float Ws[32][68];
  const int tid = threadIdx.x;
  const int tr = tid >> 4, tc = tid & 15;
  const int lm = tid >> 2;          // 0..63
  const int lk = (tid & 3)*8;       // 0,8,16,24
  float acc[4][4] = {};
  for (int k0 = 0; k0 < K; k0 += 32){
    const float* Ap = A + (size_t)(row0+lm)*K + k0 + lk;
    const float* Wp = W + (size_t)(col0+lm)*K + k0 + lk;
#pragma unroll
    for (int j = 0; j < 8; ++j) As[lk+j][lm] = Ap[j];
#pragma unroll
    for (int j = 0; j < 8; ++j) Ws[lk+j][lm] = Wp[j];
    __syncthreads();
#pragma unroll
    for (int kk = 0; kk < 32; ++kk){
      float av[4], wv[4];
      *(float4*)av = *(const float4*)&As[kk][tr*4];
      *(float4*)wv = *(const float4*)&Ws[kk][tc*4];
#pragma unroll
      for (int i = 0; i < 4; ++i)
#pragma unroll
        for (int j = 0; j < 4; ++j)
          acc[i][j] = fmaf(av[i], wv[j], acc[i][j]);
    }
    __syncthreads();
  }
#pragma unroll
  for (int i = 0; i < 4; ++i){
    int r = row0 + tr*4 + i;
    float* Cr = C + (size_t)r*N + col0 + tc*4;
#pragma unroll
    for (int j = 0; j < 4; ++j){
      float v = acc[i][j];
      if (bias) v += bias[col0 + tc*4 + j];
      if (ACT == 1) v = fmaxf(v, 0.f);
      Cr[j] = v;
    }
  }
}

template<int ACT>
__global__ __launch_bounds__(256) void k_gemm(const float* __restrict__ A, const float* __restrict__ W,
                                              const float* __restrict__ bias, float* __restrict__ C,
                                              int M, int N, int K){
  gemm_tile<ACT>(A, W, bias, C, N, K, blockIdx.y*64, blockIdx.x*64);
}

// fused xl/xr
__global__ __launch_bounds__(256) void k_gemm_lr(const float* __restrict__ A,
                                                 const float* __restrict__ Wl, const float* __restrict__ Wr,
                                                 float* __restrict__ xl, float* __restrict__ xr){
  int bx = blockIdx.x;
  if (bx < HC_/64)
    gemm_tile<0>(A, Wl, nullptr, xl, HC_, G_, blockIdx.y*64, bx*64);
  else
    gemm_tile<0>(A, Wr, nullptr, xr, HC_, G_, blockIdx.y*64, (bx - HC_/64)*64);
}

// ---------------- thin GEMM v3: feature-major activations, LDS-staged weights ----
// Ct[c][tok] = bias[c] + sum_k At[k][tok]*W[c][k], c in [blockIdx.x*FB, +FB)
// 256 threads: fg = tid>>6 owns FB/4 features; lane = token.
// Weight tile W[FB][KC] staged via coalesced float4 (FB*KC/1024 per thread in flight).
template<int ACT, int KC, int FB>
__global__ __launch_bounds__(256) void k_tgemm(const float* __restrict__ At, const float* __restrict__ W,
                                               const float* __restrict__ bias, float* __restrict__ Ct,
                                               int K){
  constexpr int FPG = FB/4;
  __shared__ float Ws[FB*KC];
  const int tid = threadIdx.x;
  const int c0 = blockIdx.x*FB;
  const int lane = tid & 63;
  const int fg = tid >> 6;        // 0..3 (wave-uniform)
  float acc[FPG];
#pragma unroll
  for (int i = 0; i < FPG; ++i) acc[i] = 0.f;

  for (int k0 = 0; k0 < K; k0 += KC){
    constexpr int TOT4 = FB*KC/4;     // float4s in tile
#pragma unroll
    for (int i = 0; i < TOT4/256; ++i){
      int idx = tid + i*256;
      int r = idx / (KC/4), cc = idx & (KC/4 - 1);
      *(float4*)&Ws[r*KC + cc*4] = *(const float4*)(W + (size_t)(c0+r)*K + k0 + cc*4);
    }
    __syncthreads();
    const float* ap = At + (size_t)k0*64 + lane;
#pragma unroll 8
    for (int k = 0; k < KC; ++k){
      float a = ap[(size_t)k*64];
#pragma unroll
      for (int i = 0; i < FPG; ++i)
        acc[i] = fmaf(a, Ws[(fg*FPG + i)*KC + k], acc[i]);
    }
    __syncthreads();
  }
#pragma unroll
  for (int i = 0; i < FPG; ++i){
    int c = c0 + fg*FPG + i;
    float v = acc[i] + bias[c];
    if (ACT == 1) v = fmaxf(v, 0.f);
    Ct[(size_t)c*64 + lane] = v;
  }
}

// ---------------- GAT edge logits ----------------
__global__ __launch_bounds__(256) void k_edge(const float* __restrict__ xl, const float* __restrict__ xr,
                                              const float* __restrict__ ea, const float* __restrict__ sl,
                                              const int* __restrict__ srcv, const int* __restrict__ dstv,
                                              const float* __restrict__ we, const float* __restrict__ att,
                                              float* __restrict__ logit){
  int w = blockIdx.x*4 + (threadIdx.x >> 6);
  if (w >= T_*ET_) return;
  int lane = threadIdx.x & 63;
  int t = w / ET_, e = w % ET_;
  int s, d; float a0, a1;
  if (e < E_){
    s = srcv[e]; d = dstv[e];
    const float* p = ea + ((size_t)t*E_ + e)*2;
    a0 = p[0]; a1 = p[1];
  } else {
    s = d = e - E_;
    const float* p = sl + ((size_t)t*N_ + s)*2;
    a0 = p[0]; a1 = p[1];
  }
  const float* xls = xl + ((size_t)t*N_ + s)*HC_;
  const float* xrd = xr + ((size_t)t*N_ + d)*HC_;
  float acc[4];
#pragma unroll
  for (int h = 0; h < 4; ++h){
    int c = h*64 + lane;
    float v = xls[c] + xrd[c] + a0*we[c*2] + a1*we[c*2+1];
    v = (v >= 0.f) ? v : NEG_*v;
    acc[h] = v * att[c];
  }
#pragma unroll
  for (int o = 32; o; o >>= 1){
#pragma unroll
    for (int h = 0; h < 4; ++h) acc[h] += __shfl_xor(acc[h], o, 64);
  }
  if (lane == 0){
    float4 r = make_float4(acc[0], acc[1], acc[2], acc[3]);
    *(float4*)&logit[(size_t)w*4] = r;
  }
}

// ---------------- GAT node ----------------
__global__ __launch_bounds__(256) void k_node(const float* __restrict__ xl, const float* __restrict__ logit,
                                              const int* __restrict__ off, const int* __restrict__ eid,
                                              const int* __restrict__ srcv,
                                              const float* __restrict__ hin, const float* __restrict__ gb,
                                              const float* __restrict__ lw, const float* __restrict__ lb,
                                              float* __restrict__ hout){
  int w = blockIdx.x*4 + (threadIdx.x >> 6);
  if (w >= T_*N_) return;
  int lane = threadIdx.x & 63;
  int t = w / N_, n = w % N_;
  int o = off[n], deg = off[n+1] - o, deg1 = deg + 1;
  const float4* lg = (const float4*)logit + (size_t)t*ET_;

  float4 mx = make_float4(-1e30f, -1e30f, -1e30f, -1e30f);
  for (int j = lane; j < deg1; j += 64){
    int e = (j < deg) ? eid[o+j] : (E_ + n);
    float4 l = lg[e];
    mx.x = fmaxf(mx.x, l.x); mx.y = fmaxf(mx.y, l.y);
    mx.z = fmaxf(mx.z, l.z); mx.w = fmaxf(mx.w, l.w);
  }
#pragma unroll
  for (int o2 = 32; o2; o2 >>= 1){
    mx.x = fmaxf(mx.x, __shfl_xor(mx.x, o2, 64));
    mx.y = fmaxf(mx.y, __shfl_xor(mx.y, o2, 64));
    mx.z = fmaxf(mx.z, __shfl_xor(mx.z, o2, 64));
    mx.w = fmaxf(mx.w, __shfl_xor(mx.w, o2, 64));
  }
  float4 sm = make_float4(0.f, 0.f, 0.f, 0.f);
  for (int j = lane; j < deg1; j += 64){
    int e = (j < deg) ? eid[o+j] : (E_ + n);
    float4 l = lg[e];
    sm.x += expf(l.x - mx.x); sm.y += expf(l.y - mx.y);
    sm.z += expf(l.z - mx.z); sm.w += expf(l.w - mx.w);
  }
  sm.x = wred_sum(sm.x); sm.y = wred_sum(sm.y);
  sm.z = wred_sum(sm.z); sm.w = wred_sum(sm.w);
  float4 rs = make_float4(1.f/sm.x, 1.f/sm.y, 1.f/sm.z, 1.f/sm.w);

  float acc = 0.f;
  for (int j = 0; j < deg1; ++j){
    int e, s;
    if (j < deg){ e = eid[o+j]; s = srcv[e]; } else { e = E_ + n; s = n; }
    float4 l = lg[e];
    float w0 = expf(l.x - mx.x)*rs.x;
    float w1 = expf(l.y - mx.y)*rs.y;
    float w2 = expf(l.z - mx.z)*rs.z;
    float w3 = expf(l.w - mx.w)*rs.w;
    const float* xp = xl + ((size_t)t*N_ + s)*HC_;
    acc += w0*xp[lane] + w1*xp[64+lane] + w2*xp[128+lane] + w3*xp[192+lane];
  }
  float v = 0.25f*acc + gb[lane];
  v = fmaxf(v, 0.f);                      // relu
  v += hin[((size_t)t*N_ + n)*G_ + lane]; // residual
  float mu = wred_sum(v) * (1.f/64.f);
  float dd = v - mu;
  float var = wred_sum(dd*dd) * (1.f/64.f);
  float rstd = 1.f / sqrtf(var + EPS_);
  hout[((size_t)t*N_ + n)*G_ + lane] = dd*rstd*lw[lane] + lb[lane];
}

// ---------------- pooling -> pooled_t[128][64] (feature-major) ----------------
__global__ __launch_bounds__(256) void k_pool(const float* __restrict__ h, float* __restrict__ pooled_t){
  int tb = blockIdx.x;                 // token = t*8+b
  int t = tb >> 3, b = tb & 7;
  int lane = threadIdx.x & 63, w = threadIdx.x >> 6;
  const float* hp = h + ((size_t)t*N_ + b*NP_)*G_;
  float s = 0.f, m = -1e30f;
  for (int n = w*100; n < (w+1)*100; ++n){
    float v = hp[(size_t)n*G_ + lane];
    s += v; m = fmaxf(m, v);
  }
  __shared__ float ss[4][64], mm[4][64];
  ss[w][lane] = s; mm[w][lane] = m;
  __syncthreads();
  if (w == 0){
    s = ss[0][lane] + ss[1][lane] + ss[2][lane] + ss[3][lane];
    m = fmaxf(fmaxf(mm[0][lane], mm[1][lane]), fmaxf(mm[2][lane], mm[3][lane]));
    pooled_t[(size_t)lane*64 + tb]      = s * (1.f/400.f);
    pooled_t[(size_t)(64+lane)*64 + tb] = m;
  }
}

// ---------------- tok_t -> y, y_t, motion ----------------
__global__ void k_tokout(const float* __restrict__ tok_t, float* __restrict__ y,
                         float* __restrict__ yt, float* __restrict__ mo){
  int i = blockIdx.x*256 + threadIdx.x;
  if (i >= D_*64) return;
  int tk = i & 63;              // t*8+b
  int c = i >> 6;
  int t = tk >> 3, b = tk & 7;
  float v = tok_t[(size_t)c*64 + tk];
  int yrow = b*8 + t;
  y[(size_t)yrow*D_ + c] = v;
  yt[(size_t)c*64 + yrow] = v;
  if (c < 256 && t < 7)
    mo[((size_t)b*7 + t)*256 + c] = tok_t[(size_t)c*64 + (tk+8)] - v;  // (t+1)*8+b
}

// ---------------- MHA: reads qkv_t[1536][64], writes attno_t[512][64] ----------------
__global__ __launch_bounds__(64) void k_mha(const float* __restrict__ qkv_t, float* __restrict__ o_t){
  int bh = blockIdx.x;
  int b = bh >> 3, hd = bh & 7;
  __shared__ float q[8][64], k[8][64], v[8][64], p[8][8];
  int tid = threadIdx.x;
  int tt = tid >> 3, d0 = (tid & 7)*8;
  int row = b*8 + tt;           // y-row token
#pragma unroll
  for (int j = 0; j < 8; ++j){
    int f = hd*64 + d0 + j;
    q[tt][d0+j] = qkv_t[(size_t)f*64 + row];
    k[tt][d0+j] = qkv_t[(size_t)(512+f)*64 + row];
    v[tt][d0+j] = qkv_t[(size_t)(1024+f)*64 + row];
  }
  __syncthreads();
  int tq = tid >> 3, tk = tid & 7;
  float s = 0.f;
#pragma unroll
  for (int d = 0; d < 64; ++d) s += q[tq][d]*k[tk][d];
  p[tq][tk] = s * 0.125f;
  __syncthreads();
  if (tid < 8){
    float mx = -1e30f;
#pragma unroll
    for (int j = 0; j < 8; ++j) mx = fmaxf(mx, p[tid][j]);
    float smv = 0.f;
#pragma unroll
    for (int j = 0; j < 8; ++j){ float e = expf(p[tid][j]-mx); p[tid][j] = e; smv += e; }
    float r = 1.f/smv;
#pragma unroll
    for (int j = 0; j < 8; ++j) p[tid][j] *= r;
  }
  __syncthreads();
  float out[8];
#pragma unroll
  for (int j = 0; j < 8; ++j) out[j] = 0.f;
#pragma unroll
  for (int t2 = 0; t2 < 8; ++t2){
    float wv = p[tq][t2];
#pragma unroll
    for (int j = 0; j < 8; ++j) out[j] = fmaf(wv, v[t2][d0+j], out[j]);
  }
  int orow = b*8 + tq;
#pragma unroll
  for (int j = 0; j < 8; ++j) o_t[(size_t)(hd*64 + d0 + j)*64 + orow] = out[j];
}

// ---------------- residual(+transposed res) + LayerNorm; writes y and y_t ----------------
__global__ __launch_bounds__(256) void k_lnadd(float* __restrict__ y, float* __restrict__ yt,
                                               const float* __restrict__ res_t,
                                               const float* __restrict__ w, const float* __restrict__ b){
  int row = blockIdx.x*4 + (threadIdx.x >> 6);
  int lane = threadIdx.x & 63;
  float* yr = y + (size_t)row*D_;
  float v[8]; float s = 0.f;
#pragma unroll
  for (int i = 0; i < 8; ++i){
    int c = lane + i*64;
    v[i] = yr[c] + res_t[(size_t)c*64 + row];
    s += v[i];
  }
  s = wred_sum(s);
  float mu = s * (1.f/512.f);
  float qq = 0.f;
#pragma unroll
  for (int i = 0; i < 8; ++i){ float d = v[i]-mu; qq += d*d; }
  qq = wred_sum(qq);
  float rstd = 1.f / sqrtf(qq*(1.f/512.f) + EPS_);
#pragma unroll
  for (int i = 0; i < 8; ++i){
    int c = lane + i*64;
    float ov = (v[i]-mu)*rstd*w[c] + b[c];
    yr[c] = ov;
    yt[(size_t)c*64 + row] = ov;
  }
}

extern "C" void kernel_launch(void* const* d_in, const int* in_sizes, int n_in,
                              void* d_out, int out_size, void* d_ws, size_t ws_size,
                              hipStream_t stream){
  const float* x       = (const float*)d_in[0];
  const int*   ei      = (const int*)d_in[1];
  const float* eattr   = (const float*)d_in[2];
  const float* proj_w  = (const float*)d_in[4];
  const float* proj_b  = (const float*)d_in[5];
  const float* gat_wl  = (const float*)d_in[6];
  const float* gat_wr  = (const float*)d_in[7];
  const float* gat_we  = (const float*)d_in[8];
  const float* gat_att = (const float*)d_in[9];
  const float* gat_b   = (const float*)d_in[10];
  const float* ln_w    = (const float*)d_in[11];
  const float* ln_b    = (const float*)d_in[12];
  const float* n2t_w   = (const float*)d_in[13];
  const float* n2t_b   = (const float*)d_in[14];
  const float* wqkv    = (const float*)d_in[15];
  const float* bqkv    = (const float*)d_in[16];
  const float* wo      = (const float*)d_in[17];
  const float* bo      = (const float*)d_in[18];
  const float* w1      = (const float*)d_in[19];
  const float* b1      = (const float*)d_in[20];
  const float* w2      = (const float*)d_in[21];
  const float* b2      = (const float*)d_in[22];
  const float* ln1w    = (const float*)d_in[23];
  const float* ln1b    = (const float*)d_in[24];
  const float* ln2w    = (const float*)d_in[25];
  const float* ln2b    = (const float*)d_in[26];

  const int* src0 = ei;
  const int* dst0 = ei + E_;

  char* p = (char*)d_ws;
  auto alloc = [&](size_t bytes){ void* r = (void*)p; p += (bytes + 255) & ~(size_t)255; return r; };
  int* cnt   = (int*)alloc((size_t)N_*4);
  int* off   = (int*)alloc((size_t)(N_+1)*4);
  int* pos   = (int*)alloc((size_t)N_*4);
  int* eid   = (int*)alloc((size_t)E_*4);
  float* sl  = (float*)alloc((size_t)T_*N_*2*4);
  float* hA  = (float*)alloc((size_t)T_*N_*G_*4);
  float* hB  = (float*)alloc((size_t)T_*N_*G_*4);
  float* xl  = (float*)alloc((size_t)T_*N_*HC_*4);
  float* xr  = (float*)alloc((size_t)T_*N_*HC_*4);
  float* lg  = (float*)alloc((size_t)T_*ET_*4*4);
  float* pooled_t = (float*)alloc(128*64*4);
  float* tok_t    = (float*)alloc(512*64*4);
  float* yt       = (float*)alloc(512*64*4);
  float* qkv_t    = (float*)alloc(1536*64*4);
  float* attno_t  = (float*)alloc(512*64*4);
  float* mo_t     = (float*)alloc(512*64*4);
  float* f1t      = (float*)alloc(2048*64*4);

  float* y    = (float*)d_out;          // [B,T,D] transformer state, final output 1
  float* mout = y + B_*T_*D_;           // motion, final output 2

  // CSR + self-loop attrs
  k_zero_i  <<<dim3((N_+255)/256), dim3(256), 0, stream>>>(cnt, N_);
  k_count   <<<dim3((E_+255)/256), dim3(256), 0, stream>>>(dst0, cnt);
  k_scan    <<<dim3(1), dim3(256), 0, stream>>>(cnt, off, pos);
  k_scatter <<<dim3((E_+255)/256), dim3(256), 0, stream>>>(dst0, pos, eid);
  k_sl      <<<dim3((T_*N_+255)/256), dim3(256), 0, stream>>>(eattr, off, eid, sl);

  // input projection
  k_gemm<0><<<dim3(1, (T_*N_)/64), dim3(256), 0, stream>>>(x, proj_w, proj_b, hA, T_*N_, G_, IND_);

  float* hcur = hA; float* hnext = hB;
  for (int i = 0; i < 3; ++i){
    k_gemm_lr<<<dim3(2*HC_/64, (T_*N_)/64), dim3(256), 0, stream>>>(hcur,
        gat_wl + (size_t)i*HC_*G_, gat_wr + (size_t)i*HC_*G_, xl, xr);
    k_edge<<<dim3((T_*ET_)/4), dim3(256), 0, stream>>>(xl, xr, eattr, sl, src0, dst0,
        gat_we + (size_t)i*HC_*2, gat_att + (size_t)i*HC_, lg);
    k_node<<<dim3((T_*N_)/4), dim3(256), 0, stream>>>(xl, lg, off, eid, src0, hcur,
        gat_b + i*G_, ln_w + i*G_, ln_b + i*G_, hnext);
    float* tmp = hcur; hcur = hnext; hnext = tmp;
  }

  // pool + node2token (transposed chain)
  k_pool<<<dim3(T_*B_), dim3(256), 0, stream>>>(hcur, pooled_t);
  k_tgemm<0,128,8><<<dim3(D_/8), dim3(256), 0, stream>>>(pooled_t, n2t_w, n2t_b, tok_t, 128);
  k_tokout<<<dim3((D_*64+255)/256), dim3(256), 0, stream>>>(tok_t, y, yt, mout);

  // transformer encoder, 2 layers (feature-major activations)
  for (int l = 0; l < 2; ++l){
    k_tgemm<0,256,16><<<dim3(1536/16), dim3(256), 0, stream>>>(yt, wqkv + (size_t)l*1536*512, bqkv + l*1536, qkv_t, 512);
    k_mha<<<dim3(64), dim3(64), 0, stream>>>(qkv_t, attno_t);
    k_tgemm<0,256,8><<<dim3(512/8), dim3(256), 0, stream>>>(attno_t, wo + (size_t)l*512*512, bo + l*512, mo_t, 512);
    k_lnadd<<<dim3(16), dim3(256), 0, stream>>>(y, yt, mo_t, ln1w + l*512, ln1b + l*512);
    k_tgemm<1,256,16><<<dim3(2048/16), dim3(256), 0, stream>>>(yt, w1 + (size_t)l*2048*512, b1 + l*2048, f1t, 512);
    k_tgemm<0,256,8><<<dim3(512/8), dim3(256), 0, stream>>>(f1t, w2 + (size_t)l*512*2048, b2 + l*512, mo_t, 2048);
    k_lnadd<<<dim3(16), dim3(256), 0, stream>>>(y, yt, mo_t, ln2w + l*512, ln2b + l*512);
  }
}

// Round 9
// 800.042 us; speedup vs baseline: 1.2461x; 1.1659x over previous
//
#include <hip/hip_runtime.h>
#include <math.h>

#define T_ 8
#define N_ 3200
#define E_ 25600
#define B_ 8
#define NP_ 400
#define IND_ 128
#define G_ 64
#define HC_ 256
#define D_ 512
#define NEG_ 0.2f
#define EPS_ 1e-5f

__device__ __forceinline__ float wred_sum(float v){
#pragma unroll
  for (int o = 32; o; o >>= 1) v += __shfl_xor(v, o, 64);
  return v;
}

// ---------------- CSR build ----------------
__global__ void k_zero_i(int* p, int n){
  int i = blockIdx.x*256 + threadIdx.x;
  if (i < n) p[i] = 0;
}

__global__ void k_count(const int* __restrict__ dst, int* __restrict__ cnt){
  int e = blockIdx.x*256 + threadIdx.x;
  if (e < E_) atomicAdd(&cnt[dst[e]], 1);
}

__global__ void k_scan(const int* __restrict__ cnt, int* __restrict__ off, int* __restrict__ pos){
  __shared__ int part[256];
  int tid = threadIdx.x;
  const int CH = 13;               // 256*13 = 3328 >= 3200
  int base = tid*CH;
  int s = 0;
  for (int i = 0; i < CH; ++i){ int idx = base+i; s += (idx < N_) ? cnt[idx] : 0; }
  part[tid] = s; __syncthreads();
  for (int d = 1; d < 256; d <<= 1){
    int v = (tid >= d) ? part[tid-d] : 0;
    __syncthreads();
    part[tid] += v;
    __syncthreads();
  }
  int run = tid ? part[tid-1] : 0;
  for (int i = 0; i < CH; ++i){
    int idx = base+i;
    if (idx < N_){ off[idx] = run; pos[idx] = run; run += cnt[idx]; }
  }
  if (tid == 255) off[N_] = part[255];
}

__global__ void k_scatter(const int* __restrict__ dst, int* __restrict__ pos, int* __restrict__ eid){
  int e = blockIdx.x*256 + threadIdx.x;
  if (e < E_){ int p = atomicAdd(&pos[dst[e]], 1); eid[p] = e; }
}

// self-loop attr: per-target mean of incoming edge_attr
__global__ void k_sl(const float* __restrict__ ea, const int* __restrict__ off,
                     const int* __restrict__ eid, float* __restrict__ sl){
  int idx = blockIdx.x*256 + threadIdx.x;
  if (idx >= T_*N_) return;
  int t = idx / N_, n = idx % N_;
  int o = off[n], d = off[n+1] - o;
  float s0 = 0.f, s1 = 0.f;
  for (int j = 0; j < d; ++j){
    int e = eid[o+j];
    const float* p = ea + ((size_t)t*E_ + e)*2;
    s0 += p[0]; s1 += p[1];
  }
  float c = fmaxf((float)d, 1.f);
  sl[(size_t)idx*2]   = s0 / c;
  sl[(size_t)idx*2+1] = s1 / c;
}

// ---------------- generic GEMM tile body: C[M,N] = A[M,K] @ W[N,K]^T (+bias) ----
template<int ACT>
__device__ __forceinline__ void gemm_tile(const float* __restrict__ A, const float* __restrict__ W,
                                          const float* __restrict__ bias, float* __restrict__ C,
                                          int N, int K, int row0, int col0){
  __shared__ float As[32][68];
  __shared__ float Ws[32][68];
  const int tid = threadIdx.x;
  const int tr = tid >> 4, tc = tid & 15;
  const int lm = tid >> 2;          // 0..63
  const int lk = (tid & 3)*8;       // 0,8,16,24
  float acc[4][4] = {};
  for (int k0 = 0; k0 < K; k0 += 32){
    const float* Ap = A + (size_t)(row0+lm)*K + k0 + lk;
    const float* Wp = W + (size_t)(col0+lm)*K + k0 + lk;
#pragma unroll
    for (int j = 0; j < 8; ++j) As[lk+j][lm] = Ap[j];
#pragma unroll
    for (int j = 0; j < 8; ++j) Ws[lk+j][lm] = Wp[j];
    __syncthreads();
#pragma unroll
    for (int kk = 0; kk < 32; ++kk){
      float av[4], wv[4];
      *(float4*)av = *(const float4*)&As[kk][tr*4];
      *(float4*)wv = *(const float4*)&Ws[kk][tc*4];
#pragma unroll
      for (int i = 0; i < 4; ++i)
#pragma unroll
        for (int j = 0; j < 4; ++j)
          acc[i][j] = fmaf(av[i], wv[j], acc[i][j]);
    }
    __syncthreads();
  }
#pragma unroll
  for (int i = 0; i < 4; ++i){
    int r = row0 + tr*4 + i;
    float* Cr = C + (size_t)r*N + col0 + tc*4;
#pragma unroll
    for (int j = 0; j < 4; ++j){
      float v = acc[i][j];
      if (bias) v += bias[col0 + tc*4 + j];
      if (ACT == 1) v = fmaxf(v, 0.f);
      Cr[j] = v;
    }
  }
}

template<int ACT>
__global__ __launch_bounds__(256) void k_gemm(const float* __restrict__ A, const float* __restrict__ W,
                                              const float* __restrict__ bias, float* __restrict__ C,
                                              int M, int N, int K){
  gemm_tile<ACT>(A, W, bias, C, N, K, blockIdx.y*64, blockIdx.x*64);
}

// fused xl/xr
__global__ __launch_bounds__(256) void k_gemm_lr(const float* __restrict__ A,
                                                 const float* __restrict__ Wl, const float* __restrict__ Wr,
                                                 float* __restrict__ xl, float* __restrict__ xr){
  int bx = blockIdx.x;
  if (bx < HC_/64)
    gemm_tile<0>(A, Wl, nullptr, xl, HC_, G_, blockIdx.y*64, bx*64);
  else
    gemm_tile<0>(A, Wr, nullptr, xr, HC_, G_, blockIdx.y*64, (bx - HC_/64)*64);
}

// ---------------- thin GEMM: feature-major activations, LDS-staged weights ----
template<int ACT, int KC, int FB>
__global__ __launch_bounds__(256) void k_tgemm(const float* __restrict__ At, const float* __restrict__ W,
                                               const float* __restrict__ bias, float* __restrict__ Ct,
                                               int K){
  constexpr int FPG = FB/4;
  __shared__ float Ws[FB*KC];
  const int tid = threadIdx.x;
  const int c0 = blockIdx.x*FB;
  const int lane = tid & 63;
  const int fg = tid >> 6;        // 0..3 (wave-uniform)
  float acc[FPG];
#pragma unroll
  for (int i = 0; i < FPG; ++i) acc[i] = 0.f;

  for (int k0 = 0; k0 < K; k0 += KC){
    constexpr int TOT4 = FB*KC/4;     // float4s in tile
#pragma unroll
    for (int i = 0; i < TOT4/256; ++i){
      int idx = tid + i*256;
      int r = idx / (KC/4), cc = idx & (KC/4 - 1);
      *(float4*)&Ws[r*KC + cc*4] = *(const float4*)(W + (size_t)(c0+r)*K + k0 + cc*4);
    }
    __syncthreads();
    const float* ap = At + (size_t)k0*64 + lane;
#pragma unroll 8
    for (int k = 0; k < KC; ++k){
      float a = ap[(size_t)k*64];
#pragma unroll
      for (int i = 0; i < FPG; ++i)
        acc[i] = fmaf(a, Ws[(fg*FPG + i)*KC + k], acc[i]);
    }
    __syncthreads();
  }
#pragma unroll
  for (int i = 0; i < FPG; ++i){
    int c = c0 + fg*FPG + i;
    float v = acc[i] + bias[c];
    if (ACT == 1) v = fmaxf(v, 0.f);
    Ct[(size_t)c*64 + lane] = v;
  }
}

// ---------------- fused GAT layer: edge logits + online segment-softmax +
// aggregation + head-mean + bias + relu + residual + LayerNorm.
// Wave per (t,node); t = blockIdx.x & 7 pins each t to one XCD (L2 affinity:
// xl[t] slice is 3.27 MB < 4 MB per-XCD L2). xl[src] gathered ONCE per edge,
// consumed for both logit and aggregation from registers.
__global__ __launch_bounds__(256) void k_gat(const float* __restrict__ xl, const float* __restrict__ xr,
                                             const float* __restrict__ ea, const float* __restrict__ sl,
                                             const int* __restrict__ off, const int* __restrict__ eid,
                                             const int* __restrict__ srcv,
                                             const float* __restrict__ we, const float* __restrict__ att,
                                             const float* __restrict__ hin, const float* __restrict__ gb,
                                             const float* __restrict__ lw, const float* __restrict__ lb,
                                             float* __restrict__ hout){
  const int b = blockIdx.x;
  const int t = b & 7;
  const int n = (b >> 3)*4 + (threadIdx.x >> 6);
  const int lane = threadIdx.x & 63;

  float attc[4], we0[4], we1[4], xrn[4];
  const float* xrp = xr + ((size_t)t*N_ + n)*HC_;
#pragma unroll
  for (int h = 0; h < 4; ++h){
    int c = h*64 + lane;
    attc[h] = att[c];
    we0[h]  = we[c*2];
    we1[h]  = we[c*2+1];
    xrn[h]  = xrp[c];
  }

  const int o = off[n], deg = off[n+1] - o;
  float m[4], s[4], acc[4];

  // self-loop edge first (src = n, attrs = sl)
  {
    const float* p2 = sl + ((size_t)t*N_ + n)*2;
    float a0 = p2[0], a1 = p2[1];
    const float* xls = xl + ((size_t)t*N_ + n)*HC_;
#pragma unroll
    for (int h = 0; h < 4; ++h){
      float xv = xls[h*64 + lane];
      float v = xv + xrn[h] + a0*we0[h] + a1*we1[h];
      v = (v >= 0.f) ? v : NEG_*v;
      float lg = wred_sum(v * attc[h]);
      m[h] = lg; s[h] = 1.f; acc[h] = xv;   // exp(0) = 1
    }
  }

  for (int j = 0; j < deg; ++j){
    int e = eid[o + j];
    int src = srcv[e];
    const float* p2 = ea + ((size_t)t*E_ + e)*2;
    float a0 = p2[0], a1 = p2[1];
    const float* xls = xl + ((size_t)t*N_ + src)*HC_;
    float xv[4], lg[4];
#pragma unroll
    for (int h = 0; h < 4; ++h){
      xv[h] = xls[h*64 + lane];
      float v = xv[h] + xrn[h] + a0*we0[h] + a1*we1[h];
      v = (v >= 0.f) ? v : NEG_*v;
      lg[h] = v * attc[h];
    }
#pragma unroll
    for (int o2 = 32; o2; o2 >>= 1){
#pragma unroll
      for (int h = 0; h < 4; ++h) lg[h] += __shfl_xor(lg[h], o2, 64);
    }
#pragma unroll
    for (int h = 0; h < 4; ++h){
      if (lg[h] > m[h]){                    // wave-uniform branch
        float sc = expf(m[h] - lg[h]);
        s[h]   = s[h]*sc + 1.f;
        acc[h] = acc[h]*sc + xv[h];
        m[h]   = lg[h];
      } else {
        float pe = expf(lg[h] - m[h]);
        s[h]   += pe;
        acc[h] += pe*xv[h];
      }
    }
  }

  float out = 0.25f*(acc[0]/s[0] + acc[1]/s[1] + acc[2]/s[2] + acc[3]/s[3]);
  float v = out + gb[lane];
  v = fmaxf(v, 0.f);                          // relu
  v += hin[((size_t)t*N_ + n)*G_ + lane];     // residual
  float mu = wred_sum(v) * (1.f/64.f);
  float dd = v - mu;
  float var = wred_sum(dd*dd) * (1.f/64.f);
  float rstd = 1.f / sqrtf(var + EPS_);
  hout[((size_t)t*N_ + n)*G_ + lane] = dd*rstd*lw[lane] + lb[lane];
}

// ---------------- pooling -> pooled_t[128][64] (feature-major) ----------------
__global__ __launch_bounds__(256) void k_pool(const float* __restrict__ h, float* __restrict__ pooled_t){
  int tb = blockIdx.x;                 // token = t*8+b
  int t = tb >> 3, b = tb & 7;
  int lane = threadIdx.x & 63, w = threadIdx.x >> 6;
  const float* hp = h + ((size_t)t*N_ + b*NP_)*G_;
  float s = 0.f, m = -1e30f;
  for (int n = w*100; n < (w+1)*100; ++n){
    float v = hp[(size_t)n*G_ + lane];
    s += v; m = fmaxf(m, v);
  }
  __shared__ float ss[4][64], mm[4][64];
  ss[w][lane] = s; mm[w][lane] = m;
  __syncthreads();
  if (w == 0){
    s = ss[0][lane] + ss[1][lane] + ss[2][lane] + ss[3][lane];
    m = fmaxf(fmaxf(mm[0][lane], mm[1][lane]), fmaxf(mm[2][lane], mm[3][lane]));
    pooled_t[(size_t)lane*64 + tb]      = s * (1.f/400.f);
    pooled_t[(size_t)(64+lane)*64 + tb] = m;
  }
}

// ---------------- tok_t -> y, y_t, motion ----------------
__global__ void k_tokout(const float* __restrict__ tok_t, float* __restrict__ y,
                         float* __restrict__ yt, float* __restrict__ mo){
  int i = blockIdx.x*256 + threadIdx.x;
  if (i >= D_*64) return;
  int tk = i & 63;              // t*8+b
  int c = i >> 6;
  int t = tk >> 3, b = tk & 7;
  float v = tok_t[(size_t)c*64 + tk];
  int yrow = b*8 + t;
  y[(size_t)yrow*D_ + c] = v;
  yt[(size_t)c*64 + yrow] = v;
  if (c < 256 && t < 7)
    mo[((size_t)b*7 + t)*256 + c] = tok_t[(size_t)c*64 + (tk+8)] - v;  // (t+1)*8+b
}

// ---------------- MHA: reads qkv_t[1536][64], writes attno_t[512][64] ----------------
__global__ __launch_bounds__(64) void k_mha(const float* __restrict__ qkv_t, float* __restrict__ o_t){
  int bh = blockIdx.x;
  int b = bh >> 3, hd = bh & 7;
  __shared__ float q[8][64], k[8][64], v[8][64], p[8][8];
  int tid = threadIdx.x;
  int tt = tid >> 3, d0 = (tid & 7)*8;
  int row = b*8 + tt;           // y-row token
#pragma unroll
  for (int j = 0; j < 8; ++j){
    int f = hd*64 + d0 + j;
    q[tt][d0+j] = qkv_t[(size_t)f*64 + row];
    k[tt][d0+j] = qkv_t[(size_t)(512+f)*64 + row];
    v[tt][d0+j] = qkv_t[(size_t)(1024+f)*64 + row];
  }
  __syncthreads();
  int tq = tid >> 3, tk = tid & 7;
  float s = 0.f;
#pragma unroll
  for (int d = 0; d < 64; ++d) s += q[tq][d]*k[tk][d];
  p[tq][tk] = s * 0.125f;
  __syncthreads();
  if (tid < 8){
    float mx = -1e30f;
#pragma unroll
    for (int j = 0; j < 8; ++j) mx = fmaxf(mx, p[tid][j]);
    float smv = 0.f;
#pragma unroll
    for (int j = 0; j < 8; ++j){ float e = expf(p[tid][j]-mx); p[tid][j] = e; smv += e; }
    float r = 1.f/smv;
#pragma unroll
    for (int j = 0; j < 8; ++j) p[tid][j] *= r;
  }
  __syncthreads();
  float out[8];
#pragma unroll
  for (int j = 0; j < 8; ++j) out[j] = 0.f;
#pragma unroll
  for (int t2 = 0; t2 < 8; ++t2){
    float wv = p[tq][t2];
#pragma unroll
    for (int j = 0; j < 8; ++j) out[j] = fmaf(wv, v[t2][d0+j], out[j]);
  }
  int orow = b*8 + tq;
#pragma unroll
  for (int j = 0; j < 8; ++j) o_t[(size_t)(hd*64 + d0 + j)*64 + orow] = out[j];
}

// ---------------- residual(+transposed res) + LayerNorm; writes y and y_t ----------------
__global__ __launch_bounds__(256) void k_lnadd(float* __restrict__ y, float* __restrict__ yt,
                                               const float* __restrict__ res_t,
                                               const float* __restrict__ w, const float* __restrict__ b){
  int row = blockIdx.x*4 + (threadIdx.x >> 6);
  int lane = threadIdx.x & 63;
  float* yr = y + (size_t)row*D_;
  float v[8]; float s = 0.f;
#pragma unroll
  for (int i = 0; i < 8; ++i){
    int c = lane + i*64;
    v[i] = yr[c] + res_t[(size_t)c*64 + row];
    s += v[i];
  }
  s = wred_sum(s);
  float mu = s * (1.f/512.f);
  float qq = 0.f;
#pragma unroll
  for (int i = 0; i < 8; ++i){ float d = v[i]-mu; qq += d*d; }
  qq = wred_sum(qq);
  float rstd = 1.f / sqrtf(qq*(1.f/512.f) + EPS_);
#pragma unroll
  for (int i = 0; i < 8; ++i){
    int c = lane + i*64;
    float ov = (v[i]-mu)*rstd*w[c] + b[c];
    yr[c] = ov;
    yt[(size_t)c*64 + row] = ov;
  }
}

extern "C" void kernel_launch(void* const* d_in, const int* in_sizes, int n_in,
                              void* d_out, int out_size, void* d_ws, size_t ws_size,
                              hipStream_t stream){
  const float* x       = (const float*)d_in[0];
  const int*   ei      = (const int*)d_in[1];
  const float* eattr   = (const float*)d_in[2];
  const float* proj_w  = (const float*)d_in[4];
  const float* proj_b  = (const float*)d_in[5];
  const float* gat_wl  = (const float*)d_in[6];
  const float* gat_wr  = (const float*)d_in[7];
  const float* gat_we  = (const float*)d_in[8];
  const float* gat_att = (const float*)d_in[9];
  const float* gat_b   = (const float*)d_in[10];
  const float* ln_w    = (const float*)d_in[11];
  const float* ln_b    = (const float*)d_in[12];
  const float* n2t_w   = (const float*)d_in[13];
  const float* n2t_b   = (const float*)d_in[14];
  const float* wqkv    = (const float*)d_in[15];
  const float* bqkv    = (const float*)d_in[16];
  const float* wo      = (const float*)d_in[17];
  const float* bo      = (const float*)d_in[18];
  const float* w1      = (const float*)d_in[19];
  const float* b1      = (const float*)d_in[20];
  const float* w2      = (const float*)d_in[21];
  const float* b2      = (const float*)d_in[22];
  const float* ln1w    = (const float*)d_in[23];
  const float* ln1b    = (const float*)d_in[24];
  const float* ln2w    = (const float*)d_in[25];
  const float* ln2b    = (const float*)d_in[26];

  const int* src0 = ei;
  const int* dst0 = ei + E_;

  char* p = (char*)d_ws;
  auto alloc = [&](size_t bytes){ void* r = (void*)p; p += (bytes + 255) & ~(size_t)255; return r; };
  int* cnt   = (int*)alloc((size_t)N_*4);
  int* off   = (int*)alloc((size_t)(N_+1)*4);
  int* pos   = (int*)alloc((size_t)N_*4);
  int* eid   = (int*)alloc((size_t)E_*4);
  float* sl  = (float*)alloc((size_t)T_*N_*2*4);
  float* hA  = (float*)alloc((size_t)T_*N_*G_*4);
  float* hB  = (float*)alloc((size_t)T_*N_*G_*4);
  float* xl  = (float*)alloc((size_t)T_*N_*HC_*4);
  float* xr  = (float*)alloc((size_t)T_*N_*HC_*4);
  float* pooled_t = (float*)alloc(128*64*4);
  float* tok_t    = (float*)alloc(512*64*4);
  float* yt       = (float*)alloc(512*64*4);
  float* qkv_t    = (float*)alloc(1536*64*4);
  float* attno_t  = (float*)alloc(512*64*4);
  float* mo_t     = (float*)alloc(512*64*4);
  float* f1t      = (float*)alloc(2048*64*4);

  float* y    = (float*)d_out;          // [B,T,D] transformer state, final output 1
  float* mout = y + B_*T_*D_;           // motion, final output 2

  // CSR + self-loop attrs
  k_zero_i  <<<dim3((N_+255)/256), dim3(256), 0, stream>>>(cnt, N_);
  k_count   <<<dim3((E_+255)/256), dim3(256), 0, stream>>>(dst0, cnt);
  k_scan    <<<dim3(1), dim3(256), 0, stream>>>(cnt, off, pos);
  k_scatter <<<dim3((E_+255)/256), dim3(256), 0, stream>>>(dst0, pos, eid);
  k_sl      <<<dim3((T_*N_+255)/256), dim3(256), 0, stream>>>(eattr, off, eid, sl);

  // input projection
  k_gemm<0><<<dim3(1, (T_*N_)/64), dim3(256), 0, stream>>>(x, proj_w, proj_b, hA, T_*N_, G_, IND_);

  float* hcur = hA; float* hnext = hB;
  for (int i = 0; i < 3; ++i){
    k_gemm_lr<<<dim3(2*HC_/64, (T_*N_)/64), dim3(256), 0, stream>>>(hcur,
        gat_wl + (size_t)i*HC_*G_, gat_wr + (size_t)i*HC_*G_, xl, xr);
    k_gat<<<dim3(T_*N_/4), dim3(256), 0, stream>>>(xl, xr, eattr, sl, off, eid, src0,
        gat_we + (size_t)i*HC_*2, gat_att + (size_t)i*HC_, hcur,
        gat_b + i*G_, ln_w + i*G_, ln_b + i*G_, hnext);
    float* tmp = hcur; hcur = hnext; hnext = tmp;
  }

  // pool + node2token (transposed chain)
  k_pool<<<dim3(T_*B_), dim3(256), 0, stream>>>(hcur, pooled_t);
  k_tgemm<0,128,8><<<dim3(D_/8), dim3(256), 0, stream>>>(pooled_t, n2t_w, n2t_b, tok_t, 128);
  k_tokout<<<dim3((D_*64+255)/256), dim3(256), 0, stream>>>(tok_t, y, yt, mout);

  // transformer encoder, 2 layers (feature-major activations)
  for (int l = 0; l < 2; ++l){
    k_tgemm<0,256,16><<<dim3(1536/16), dim3(256), 0, stream>>>(yt, wqkv + (size_t)l*1536*512, bqkv + l*1536, qkv_t, 512);
    k_mha<<<dim3(64), dim3(64), 0, stream>>>(qkv_t, attno_t);
    k_tgemm<0,256,8><<<dim3(512/8), dim3(256), 0, stream>>>(attno_t, wo + (size_t)l*512*512, bo + l*512, mo_t, 512);
    k_lnadd<<<dim3(16), dim3(256), 0, stream>>>(y, yt, mo_t, ln1w + l*512, ln1b + l*512);
    k_tgemm<1,256,16><<<dim3(2048/16), dim3(256), 0, stream>>>(yt, w1 + (size_t)l*2048*512, b1 + l*2048, f1t, 512);
    k_tgemm<0,256,8><<<dim3(512/8), dim3(256), 0, stream>>>(f1t, w2 + (size_t)l*512*2048, b2 + l*512, mo_t, 2048);
    k_lnadd<<<dim3(16), dim3(256), 0, stream>>>(y, yt, mo_t, ln2w + l*512, ln2b + l*512);
  }
}

// Round 10
// 681.877 us; speedup vs baseline: 1.4620x; 1.1733x over previous
//
#include <hip/hip_runtime.h>
#include <math.h>

#define T_ 8
#define N_ 3200
#define E_ 25600
#define B_ 8
#define NP_ 400
#define IND_ 128
#define G_ 64
#define HC_ 256
#define D_ 512
#define NEG_ 0.2f
#define EPS_ 1e-5f

__device__ __forceinline__ float wred_sum(float v){
#pragma unroll
  for (int o = 32; o; o >>= 1) v += __shfl_xor(v, o, 64);
  return v;
}

// ---------------- CSR build ----------------
__global__ void k_zero_i(int* p, int n){
  int i = blockIdx.x*256 + threadIdx.x;
  if (i < n) p[i] = 0;
}

__global__ void k_count(const int* __restrict__ dst, int* __restrict__ cnt){
  int e = blockIdx.x*256 + threadIdx.x;
  if (e < E_) atomicAdd(&cnt[dst[e]], 1);
}

__global__ void k_scan(const int* __restrict__ cnt, int* __restrict__ off, int* __restrict__ pos){
  __shared__ int part[256];
  int tid = threadIdx.x;
  const int CH = 13;               // 256*13 = 3328 >= 3200
  int base = tid*CH;
  int s = 0;
  for (int i = 0; i < CH; ++i){ int idx = base+i; s += (idx < N_) ? cnt[idx] : 0; }
  part[tid] = s; __syncthreads();
  for (int d = 1; d < 256; d <<= 1){
    int v = (tid >= d) ? part[tid-d] : 0;
    __syncthreads();
    part[tid] += v;
    __syncthreads();
  }
  int run = tid ? part[tid-1] : 0;
  for (int i = 0; i < CH; ++i){
    int idx = base+i;
    if (idx < N_){ off[idx] = run; pos[idx] = run; run += cnt[idx]; }
  }
  if (tid == 255) off[N_] = part[255];
}

__global__ void k_scatter(const int* __restrict__ dst, int* __restrict__ pos, int* __restrict__ eid){
  int e = blockIdx.x*256 + threadIdx.x;
  if (e < E_){ int p = atomicAdd(&pos[dst[e]], 1); eid[p] = e; }
}

// self-loop attr: per-target mean of incoming edge_attr
__global__ void k_sl(const float* __restrict__ ea, const int* __restrict__ off,
                     const int* __restrict__ eid, float* __restrict__ sl){
  int idx = blockIdx.x*256 + threadIdx.x;
  if (idx >= T_*N_) return;
  int t = idx / N_, n = idx % N_;
  int o = off[n], d = off[n+1] - o;
  float s0 = 0.f, s1 = 0.f;
  for (int j = 0; j < d; ++j){
    int e = eid[o+j];
    const float* p = ea + ((size_t)t*E_ + e)*2;
    s0 += p[0]; s1 += p[1];
  }
  float c = fmaxf((float)d, 1.f);
  sl[(size_t)idx*2]   = s0 / c;
  sl[(size_t)idx*2+1] = s1 / c;
}

// ---------------- generic GEMM tile body: C[M,N] = A[M,K] @ W[N,K]^T (+bias) ----
template<int ACT>
__device__ __forceinline__ void gemm_tile(const float* __restrict__ A, const float* __restrict__ W,
                                          const float* __restrict__ bias, float* __restrict__ C,
                                          int N, int K, int row0, int col0){
  __shared__ float As[32][68];
  __shared__ float Ws[32][68];
  const int tid = threadIdx.x;
  const int tr = tid >> 4, tc = tid & 15;
  const int lm = tid >> 2;          // 0..63
  const int lk = (tid & 3)*8;       // 0,8,16,24
  float acc[4][4] = {};
  for (int k0 = 0; k0 < K; k0 += 32){
    const float* Ap = A + (size_t)(row0+lm)*K + k0 + lk;
    const float* Wp = W + (size_t)(col0+lm)*K + k0 + lk;
#pragma unroll
    for (int j = 0; j < 8; ++j) As[lk+j][lm] = Ap[j];
#pragma unroll
    for (int j = 0; j < 8; ++j) Ws[lk+j][lm] = Wp[j];
    __syncthreads();
#pragma unroll
    for (int kk = 0; kk < 32; ++kk){
      float av[4], wv[4];
      *(float4*)av = *(const float4*)&As[kk][tr*4];
      *(float4*)wv = *(const float4*)&Ws[kk][tc*4];
#pragma unroll
      for (int i = 0; i < 4; ++i)
#pragma unroll
        for (int j = 0; j < 4; ++j)
          acc[i][j] = fmaf(av[i], wv[j], acc[i][j]);
    }
    __syncthreads();
  }
#pragma unroll
  for (int i = 0; i < 4; ++i){
    int r = row0 + tr*4 + i;
    float* Cr = C + (size_t)r*N + col0 + tc*4;
#pragma unroll
    for (int j = 0; j < 4; ++j){
      float v = acc[i][j];
      if (bias) v += bias[col0 + tc*4 + j];
      if (ACT == 1) v = fmaxf(v, 0.f);
      Cr[j] = v;
    }
  }
}

template<int ACT>
__global__ __launch_bounds__(256) void k_gemm(const float* __restrict__ A, const float* __restrict__ W,
                                              const float* __restrict__ bias, float* __restrict__ C,
                                              int M, int N, int K){
  gemm_tile<ACT>(A, W, bias, C, N, K, blockIdx.y*64, blockIdx.x*64);
}

// fused xl/xr
__global__ __launch_bounds__(256) void k_gemm_lr(const float* __restrict__ A,
                                                 const float* __restrict__ Wl, const float* __restrict__ Wr,
                                                 float* __restrict__ xl, float* __restrict__ xr){
  int bx = blockIdx.x;
  if (bx < HC_/64)
    gemm_tile<0>(A, Wl, nullptr, xl, HC_, G_, blockIdx.y*64, bx*64);
  else
    gemm_tile<0>(A, Wr, nullptr, xr, HC_, G_, blockIdx.y*64, (bx - HC_/64)*64);
}

// ---------------- thin GEMM: feature-major activations, LDS-staged weights ----
template<int ACT, int KC, int FB>
__global__ __launch_bounds__(256) void k_tgemm(const float* __restrict__ At, const float* __restrict__ W,
                                               const float* __restrict__ bias, float* __restrict__ Ct,
                                               int K){
  constexpr int FPG = FB/4;
  __shared__ float Ws[FB*KC];
  const int tid = threadIdx.x;
  const int c0 = blockIdx.x*FB;
  const int lane = tid & 63;
  const int fg = tid >> 6;        // 0..3 (wave-uniform)
  float acc[FPG];
#pragma unroll
  for (int i = 0; i < FPG; ++i) acc[i] = 0.f;

  for (int k0 = 0; k0 < K; k0 += KC){
    constexpr int TOT4 = FB*KC/4;     // float4s in tile
#pragma unroll
    for (int i = 0; i < TOT4/256; ++i){
      int idx = tid + i*256;
      int r = idx / (KC/4), cc = idx & (KC/4 - 1);
      *(float4*)&Ws[r*KC + cc*4] = *(const float4*)(W + (size_t)(c0+r)*K + k0 + cc*4);
    }
    __syncthreads();
    const float* ap = At + (size_t)k0*64 + lane;
#pragma unroll 8
    for (int k = 0; k < KC; ++k){
      float a = ap[(size_t)k*64];
#pragma unroll
      for (int i = 0; i < FPG; ++i)
        acc[i] = fmaf(a, Ws[(fg*FPG + i)*KC + k], acc[i]);
    }
    __syncthreads();
  }
#pragma unroll
  for (int i = 0; i < FPG; ++i){
    int c = c0 + fg*FPG + i;
    float v = acc[i] + bias[c];
    if (ACT == 1) v = fmaxf(v, 0.f);
    Ct[(size_t)c*64 + lane] = v;
  }
}

// ---------------- fused GAT layer v2: head-sliced lanes ----------------
// Wave per (t,node). lane = h*16 + l16; lane owns channels c0 = h*64+l16*4 .. +3
// of head h. Head reduce = 4-round butterfly within 16 lanes (all heads at once).
// Branchless online softmax, __expf, 2-stage gather pipeline. t pinned to XCD.
__global__ __launch_bounds__(256) void k_gat(const float* __restrict__ xl, const float* __restrict__ xr,
                                             const float* __restrict__ ea, const float* __restrict__ sl,
                                             const int* __restrict__ off, const int* __restrict__ eid,
                                             const int* __restrict__ srcv,
                                             const float* __restrict__ we, const float* __restrict__ att,
                                             const float* __restrict__ hin, const float* __restrict__ gb,
                                             const float* __restrict__ lw, const float* __restrict__ lb,
                                             float* __restrict__ hout){
  const int b = blockIdx.x;
  const int t = b & 7;
  const int n = (b >> 3)*4 + (threadIdx.x >> 6);
  const int lane = threadIdx.x & 63;
  const int h   = lane >> 4;
  const int l16 = lane & 15;
  const int c0  = h*64 + l16*4;

  const float4 attc = *(const float4*)(att + c0);
  const float4 wea  = *(const float4*)(we + 2*c0);      // we0[0],we1[0],we0[1],we1[1]
  const float4 web  = *(const float4*)(we + 2*c0 + 4);  // we0[2],we1[2],we0[3],we1[3]
  const float4 xrn  = *(const float4*)(xr + ((size_t)t*N_ + n)*HC_ + c0);
  const float* xlt = xl + (size_t)t*N_*HC_ + c0;

  const int o = off[n], deg = off[n+1] - o;

  float m, s; float4 acc;
  // self-loop edge (src = n, attrs = sl)
  {
    float2 a2 = *(const float2*)(sl + ((size_t)t*N_ + n)*2);
    float4 xv = *(const float4*)(xlt + (size_t)n*HC_);
    float v0 = xv.x + xrn.x + a2.x*wea.x + a2.y*wea.y;
    float v1 = xv.y + xrn.y + a2.x*wea.z + a2.y*wea.w;
    float v2 = xv.z + xrn.z + a2.x*web.x + a2.y*web.y;
    float v3 = xv.w + xrn.w + a2.x*web.z + a2.y*web.w;
    v0 = (v0 >= 0.f)? v0 : NEG_*v0;
    v1 = (v1 >= 0.f)? v1 : NEG_*v1;
    v2 = (v2 >= 0.f)? v2 : NEG_*v2;
    v3 = (v3 >= 0.f)? v3 : NEG_*v3;
    float p = v0*attc.x + v1*attc.y + v2*attc.z + v3*attc.w;
    p += __shfl_xor(p, 1, 64); p += __shfl_xor(p, 2, 64);
    p += __shfl_xor(p, 4, 64); p += __shfl_xor(p, 8, 64);
    m = p; s = 1.f; acc = xv;
  }

  if (deg > 0){
    int e = eid[o];
    float2 a2 = *(const float2*)(ea + ((size_t)t*E_ + e)*2);
    float4 xnext = *(const float4*)(xlt + (size_t)srcv[e]*HC_);
    for (int j = 0; j < deg; ++j){
      float4 xv = xnext; float2 ac = a2;
      if (j+1 < deg){
        int e2 = eid[o+j+1];
        a2 = *(const float2*)(ea + ((size_t)t*E_ + e2)*2);
        xnext = *(const float4*)(xlt + (size_t)srcv[e2]*HC_);
      }
      float v0 = xv.x + xrn.x + ac.x*wea.x + ac.y*wea.y;
      float v1 = xv.y + xrn.y + ac.x*wea.z + ac.y*wea.w;
      float v2 = xv.z + xrn.z + ac.x*web.x + ac.y*web.y;
      float v3 = xv.w + xrn.w + ac.x*web.z + ac.y*web.w;
      v0 = (v0 >= 0.f)? v0 : NEG_*v0;
      v1 = (v1 >= 0.f)? v1 : NEG_*v1;
      v2 = (v2 >= 0.f)? v2 : NEG_*v2;
      v3 = (v3 >= 0.f)? v3 : NEG_*v3;
      float p = v0*attc.x + v1*attc.y + v2*attc.z + v3*attc.w;
      p += __shfl_xor(p, 1, 64); p += __shfl_xor(p, 2, 64);
      p += __shfl_xor(p, 4, 64); p += __shfl_xor(p, 8, 64);
      float nm = fmaxf(m, p);
      float e1 = __expf(m - nm);
      float e2v = __expf(p - nm);
      s = fmaf(s, e1, e2v);
      acc.x = fmaf(acc.x, e1, e2v*xv.x);
      acc.y = fmaf(acc.y, e1, e2v*xv.y);
      acc.z = fmaf(acc.z, e1, e2v*xv.z);
      acc.w = fmaf(acc.w, e1, e2v*xv.w);
      m = nm;
    }
  }

  float inv = 1.f / s;
  float o0 = acc.x*inv, o1 = acc.y*inv, o2 = acc.z*inv, o3 = acc.w*inv;
  // head mean: sum across the 4 head groups (xor 16, 32)
  o0 += __shfl_xor(o0, 16, 64); o1 += __shfl_xor(o1, 16, 64);
  o2 += __shfl_xor(o2, 16, 64); o3 += __shfl_xor(o3, 16, 64);
  o0 += __shfl_xor(o0, 32, 64); o1 += __shfl_xor(o1, 32, 64);
  o2 += __shfl_xor(o2, 32, 64); o3 += __shfl_xor(o3, 32, 64);

  const int g0 = l16*4;
  float4 gbv = *(const float4*)(gb + g0);
  float4 hv  = *(const float4*)(hin + ((size_t)t*N_ + n)*G_ + g0);
  float w0 = fmaxf(0.25f*o0 + gbv.x, 0.f) + hv.x;
  float w1 = fmaxf(0.25f*o1 + gbv.y, 0.f) + hv.y;
  float w2 = fmaxf(0.25f*o2 + gbv.z, 0.f) + hv.z;
  float w3 = fmaxf(0.25f*o3 + gbv.w, 0.f) + hv.w;

  float ssum = w0 + w1 + w2 + w3;
  ssum += __shfl_xor(ssum, 1, 64); ssum += __shfl_xor(ssum, 2, 64);
  ssum += __shfl_xor(ssum, 4, 64); ssum += __shfl_xor(ssum, 8, 64);
  float mu = ssum * (1.f/64.f);
  float d0 = w0-mu, d1 = w1-mu, d2 = w2-mu, d3 = w3-mu;
  float q = d0*d0 + d1*d1 + d2*d2 + d3*d3;
  q += __shfl_xor(q, 1, 64); q += __shfl_xor(q, 2, 64);
  q += __shfl_xor(q, 4, 64); q += __shfl_xor(q, 8, 64);
  float rstd = 1.f / sqrtf(q*(1.f/64.f) + EPS_);

  if (h == 0){
    float4 lwv = *(const float4*)(lw + g0);
    float4 lbv = *(const float4*)(lb + g0);
    float4 r;
    r.x = d0*rstd*lwv.x + lbv.x;
    r.y = d1*rstd*lwv.y + lbv.y;
    r.z = d2*rstd*lwv.z + lbv.z;
    r.w = d3*rstd*lwv.w + lbv.w;
    *(float4*)(hout + ((size_t)t*N_ + n)*G_ + g0) = r;
  }
}

// ---------------- pooling -> pooled_t[128][64] (feature-major) ----------------
__global__ __launch_bounds__(256) void k_pool(const float* __restrict__ h, float* __restrict__ pooled_t){
  int tb = blockIdx.x;                 // token = t*8+b
  int t = tb >> 3, b = tb & 7;
  int lane = threadIdx.x & 63, w = threadIdx.x >> 6;
  const float* hp = h + ((size_t)t*N_ + b*NP_)*G_;
  float s = 0.f, m = -1e30f;
  for (int n = w*100; n < (w+1)*100; ++n){
    float v = hp[(size_t)n*G_ + lane];
    s += v; m = fmaxf(m, v);
  }
  __shared__ float ss[4][64], mm[4][64];
  ss[w][lane] = s; mm[w][lane] = m;
  __syncthreads();
  if (w == 0){
    s = ss[0][lane] + ss[1][lane] + ss[2][lane] + ss[3][lane];
    m = fmaxf(fmaxf(mm[0][lane], mm[1][lane]), fmaxf(mm[2][lane], mm[3][lane]));
    pooled_t[(size_t)lane*64 + tb]      = s * (1.f/400.f);
    pooled_t[(size_t)(64+lane)*64 + tb] = m;
  }
}

// ---------------- tok_t -> y, y_t, motion ----------------
__global__ void k_tokout(const float* __restrict__ tok_t, float* __restrict__ y,
                         float* __restrict__ yt, float* __restrict__ mo){
  int i = blockIdx.x*256 + threadIdx.x;
  if (i >= D_*64) return;
  int tk = i & 63;              // t*8+b
  int c = i >> 6;
  int t = tk >> 3, b = tk & 7;
  float v = tok_t[(size_t)c*64 + tk];
  int yrow = b*8 + t;
  y[(size_t)yrow*D_ + c] = v;
  yt[(size_t)c*64 + yrow] = v;
  if (c < 256 && t < 7)
    mo[((size_t)b*7 + t)*256 + c] = tok_t[(size_t)c*64 + (tk+8)] - v;  // (t+1)*8+b
}

// ---------------- MHA: reads qkv_t[1536][64], writes attno_t[512][64] ----------------
__global__ __launch_bounds__(64) void k_mha(const float* __restrict__ qkv_t, float* __restrict__ o_t){
  int bh = blockIdx.x;
  int b = bh >> 3, hd = bh & 7;
  __shared__ float q[8][64], k[8][64], v[8][64], p[8][8];
  int tid = threadIdx.x;
  int tt = tid >> 3, d0 = (tid & 7)*8;
  int row = b*8 + tt;           // y-row token
#pragma unroll
  for (int j = 0; j < 8; ++j){
    int f = hd*64 + d0 + j;
    q[tt][d0+j] = qkv_t[(size_t)f*64 + row];
    k[tt][d0+j] = qkv_t[(size_t)(512+f)*64 + row];
    v[tt][d0+j] = qkv_t[(size_t)(1024+f)*64 + row];
  }
  __syncthreads();
  int tq = tid >> 3, tk = tid & 7;
  float s = 0.f;
#pragma unroll
  for (int d = 0; d < 64; ++d) s += q[tq][d]*k[tk][d];
  p[tq][tk] = s * 0.125f;
  __syncthreads();
  if (tid < 8){
    float mx = -1e30f;
#pragma unroll
    for (int j = 0; j < 8; ++j) mx = fmaxf(mx, p[tid][j]);
    float smv = 0.f;
#pragma unroll
    for (int j = 0; j < 8; ++j){ float e = expf(p[tid][j]-mx); p[tid][j] = e; smv += e; }
    float r = 1.f/smv;
#pragma unroll
    for (int j = 0; j < 8; ++j) p[tid][j] *= r;
  }
  __syncthreads();
  float out[8];
#pragma unroll
  for (int j = 0; j < 8; ++j) out[j] = 0.f;
#pragma unroll
  for (int t2 = 0; t2 < 8; ++t2){
    float wv = p[tq][t2];
#pragma unroll
    for (int j = 0; j < 8; ++j) out[j] = fmaf(wv, v[t2][d0+j], out[j]);
  }
  int orow = b*8 + tq;
#pragma unroll
  for (int j = 0; j < 8; ++j) o_t[(size_t)(hd*64 + d0 + j)*64 + orow] = out[j];
}

// ---------------- residual(+transposed res) + LayerNorm; writes y and y_t ----------------
__global__ __launch_bounds__(256) void k_lnadd(float* __restrict__ y, float* __restrict__ yt,
                                               const float* __restrict__ res_t,
                                               const float* __restrict__ w, const float* __restrict__ b){
  int row = blockIdx.x*4 + (threadIdx.x >> 6);
  int lane = threadIdx.x & 63;
  float* yr = y + (size_t)row*D_;
  float v[8]; float s = 0.f;
#pragma unroll
  for (int i = 0; i < 8; ++i){
    int c = lane + i*64;
    v[i] = yr[c] + res_t[(size_t)c*64 + row];
    s += v[i];
  }
  s = wred_sum(s);
  float mu = s * (1.f/512.f);
  float qq = 0.f;
#pragma unroll
  for (int i = 0; i < 8; ++i){ float d = v[i]-mu; qq += d*d; }
  qq = wred_sum(qq);
  float rstd = 1.f / sqrtf(qq*(1.f/512.f) + EPS_);
#pragma unroll
  for (int i = 0; i < 8; ++i){
    int c = lane + i*64;
    float ov = (v[i]-mu)*rstd*w[c] + b[c];
    yr[c] = ov;
    yt[(size_t)c*64 + row] = ov;
  }
}

extern "C" void kernel_launch(void* const* d_in, const int* in_sizes, int n_in,
                              void* d_out, int out_size, void* d_ws, size_t ws_size,
                              hipStream_t stream){
  const float* x       = (const float*)d_in[0];
  const int*   ei      = (const int*)d_in[1];
  const float* eattr   = (const float*)d_in[2];
  const float* proj_w  = (const float*)d_in[4];
  const float* proj_b  = (const float*)d_in[5];
  const float* gat_wl  = (const float*)d_in[6];
  const float* gat_wr  = (const float*)d_in[7];
  const float* gat_we  = (const float*)d_in[8];
  const float* gat_att = (const float*)d_in[9];
  const float* gat_b   = (const float*)d_in[10];
  const float* ln_w    = (const float*)d_in[11];
  const float* ln_b    = (const float*)d_in[12];
  const float* n2t_w   = (const float*)d_in[13];
  const float* n2t_b   = (const float*)d_in[14];
  const float* wqkv    = (const float*)d_in[15];
  const float* bqkv    = (const float*)d_in[16];
  const float* wo      = (const float*)d_in[17];
  const float* bo      = (const float*)d_in[18];
  const float* w1      = (const float*)d_in[19];
  const float* b1      = (const float*)d_in[20];
  const float* w2      = (const float*)d_in[21];
  const float* b2      = (const float*)d_in[22];
  const float* ln1w    = (const float*)d_in[23];
  const float* ln1b    = (const float*)d_in[24];
  const float* ln2w    = (const float*)d_in[25];
  const float* ln2b    = (const float*)d_in[26];

  const int* src0 = ei;
  const int* dst0 = ei + E_;

  char* p = (char*)d_ws;
  auto alloc = [&](size_t bytes){ void* r = (void*)p; p += (bytes + 255) & ~(size_t)255; return r; };
  int* cnt   = (int*)alloc((size_t)N_*4);
  int* off   = (int*)alloc((size_t)(N_+1)*4);
  int* pos   = (int*)alloc((size_t)N_*4);
  int* eid   = (int*)alloc((size_t)E_*4);
  float* sl  = (float*)alloc((size_t)T_*N_*2*4);
  float* hA  = (float*)alloc((size_t)T_*N_*G_*4);
  float* hB  = (float*)alloc((size_t)T_*N_*G_*4);
  float* xl  = (float*)alloc((size_t)T_*N_*HC_*4);
  float* xr  = (float*)alloc((size_t)T_*N_*HC_*4);
  float* pooled_t = (float*)alloc(128*64*4);
  float* tok_t    = (float*)alloc(512*64*4);
  float* yt       = (float*)alloc(512*64*4);
  float* qkv_t    = (float*)alloc(1536*64*4);
  float* attno_t  = (float*)alloc(512*64*4);
  float* mo_t     = (float*)alloc(512*64*4);
  float* f1t      = (float*)alloc(2048*64*4);

  float* y    = (float*)d_out;          // [B,T,D] transformer state, final output 1
  float* mout = y + B_*T_*D_;           // motion, final output 2

  // CSR + self-loop attrs
  k_zero_i  <<<dim3((N_+255)/256), dim3(256), 0, stream>>>(cnt, N_);
  k_count   <<<dim3((E_+255)/256), dim3(256), 0, stream>>>(dst0, cnt);
  k_scan    <<<dim3(1), dim3(256), 0, stream>>>(cnt, off, pos);
  k_scatter <<<dim3((E_+255)/256), dim3(256), 0, stream>>>(dst0, pos, eid);
  k_sl      <<<dim3((T_*N_+255)/256), dim3(256), 0, stream>>>(eattr, off, eid, sl);

  // input projection
  k_gemm<0><<<dim3(1, (T_*N_)/64), dim3(256), 0, stream>>>(x, proj_w, proj_b, hA, T_*N_, G_, IND_);

  float* hcur = hA; float* hnext = hB;
  for (int i = 0; i < 3; ++i){
    k_gemm_lr<<<dim3(2*HC_/64, (T_*N_)/64), dim3(256), 0, stream>>>(hcur,
        gat_wl + (size_t)i*HC_*G_, gat_wr + (size_t)i*HC_*G_, xl, xr);
    k_gat<<<dim3(T_*N_/4), dim3(256), 0, stream>>>(xl, xr, eattr, sl, off, eid, src0,
        gat_we + (size_t)i*HC_*2, gat_att + (size_t)i*HC_, hcur,
        gat_b + i*G_, ln_w + i*G_, ln_b + i*G_, hnext);
    float* tmp = hcur; hcur = hnext; hnext = tmp;
  }

  // pool + node2token (transposed chain)
  k_pool<<<dim3(T_*B_), dim3(256), 0, stream>>>(hcur, pooled_t);
  k_tgemm<0,128,8><<<dim3(D_/8), dim3(256), 0, stream>>>(pooled_t, n2t_w, n2t_b, tok_t, 128);
  k_tokout<<<dim3((D_*64+255)/256), dim3(256), 0, stream>>>(tok_t, y, yt, mout);

  // transformer encoder, 2 layers (feature-major activations)
  for (int l = 0; l < 2; ++l){
    k_tgemm<0,256,16><<<dim3(1536/16), dim3(256), 0, stream>>>(yt, wqkv + (size_t)l*1536*512, bqkv + l*1536, qkv_t, 512);
    k_mha<<<dim3(64), dim3(64), 0, stream>>>(qkv_t, attno_t);
    k_tgemm<0,256,8><<<dim3(512/8), dim3(256), 0, stream>>>(attno_t, wo + (size_t)l*512*512, bo + l*512, mo_t, 512);
    k_lnadd<<<dim3(16), dim3(256), 0, stream>>>(y, yt, mo_t, ln1w + l*512, ln1b + l*512);
    k_tgemm<1,256,16><<<dim3(2048/16), dim3(256), 0, stream>>>(yt, w1 + (size_t)l*2048*512, b1 + l*2048, f1t, 512);
    k_tgemm<0,256,8><<<dim3(512/8), dim3(256), 0, stream>>>(f1t, w2 + (size_t)l*512*2048, b2 + l*512, mo_t, 2048);
    k_lnadd<<<dim3(16), dim3(256), 0, stream>>>(y, yt, mo_t, ln2w + l*512, ln2b + l*512);
  }
}

// Round 12
// 644.522 us; speedup vs baseline: 1.5467x; 1.0580x over previous
//
#include <hip/hip_runtime.h>
#include <math.h>

#define T_ 8
#define N_ 3200
#define E_ 25600
#define B_ 8
#define NP_ 400
#define IND_ 128
#define G_ 64
#define HC_ 256
#define D_ 512
#define NEG_ 0.2f
#define EPS_ 1e-5f

__device__ __forceinline__ float wred_sum(float v){
#pragma unroll
  for (int o = 32; o; o >>= 1) v += __shfl_xor(v, o, 64);
  return v;
}

// ---------------- CSR build ----------------
__global__ void k_zero_i(int* p, int n){
  int i = blockIdx.x*256 + threadIdx.x;
  if (i < n) p[i] = 0;
}

__global__ void k_count(const int* __restrict__ dst, int* __restrict__ cnt){
  int e = blockIdx.x*256 + threadIdx.x;
  if (e < E_) atomicAdd(&cnt[dst[e]], 1);
}

__global__ void k_scan(const int* __restrict__ cnt, int* __restrict__ off, int* __restrict__ pos){
  __shared__ int part[256];
  int tid = threadIdx.x;
  const int CH = 13;               // 256*13 = 3328 >= 3200
  int base = tid*CH;
  int s = 0;
  for (int i = 0; i < CH; ++i){ int idx = base+i; s += (idx < N_) ? cnt[idx] : 0; }
  part[tid] = s; __syncthreads();
  for (int d = 1; d < 256; d <<= 1){
    int v = (tid >= d) ? part[tid-d] : 0;
    __syncthreads();
    part[tid] += v;
    __syncthreads();
  }
  int run = tid ? part[tid-1] : 0;
  for (int i = 0; i < CH; ++i){
    int idx = base+i;
    if (idx < N_){ off[idx] = run; pos[idx] = run; run += cnt[idx]; }
  }
  if (tid == 255) off[N_] = part[255];
}

__global__ void k_scatter(const int* __restrict__ dst, int* __restrict__ pos, int* __restrict__ eid){
  int e = blockIdx.x*256 + threadIdx.x;
  if (e < E_){ int p = atomicAdd(&pos[dst[e]], 1); eid[p] = e; }
}

// self-loop attr: per-target mean of incoming edge_attr
__global__ void k_sl(const float* __restrict__ ea, const int* __restrict__ off,
                     const int* __restrict__ eid, float* __restrict__ sl){
  int idx = blockIdx.x*256 + threadIdx.x;
  if (idx >= T_*N_) return;
  int t = idx / N_, n = idx % N_;
  int o = off[n], d = off[n+1] - o;
  float s0 = 0.f, s1 = 0.f;
  for (int j = 0; j < d; ++j){
    int e = eid[o+j];
    const float* p = ea + ((size_t)t*E_ + e)*2;
    s0 += p[0]; s1 += p[1];
  }
  float c = fmaxf((float)d, 1.f);
  sl[(size_t)idx*2]   = s0 / c;
  sl[(size_t)idx*2+1] = s1 / c;
}

// ---------------- generic GEMM tile body: C[M,N] = A[M,K] @ W[N,K]^T (+bias) ----
template<int ACT>
__device__ __forceinline__ void gemm_tile(const float* __restrict__ A, const float* __restrict__ W,
                                          const float* __restrict__ bias, float* __restrict__ C,
                                          int N, int K, int row0, int col0){
  __shared__ float As[32][68];
  __shared__ float Ws[32][68];
  const int tid = threadIdx.x;
  const int tr = tid >> 4, tc = tid & 15;
  const int lm = tid >> 2;          // 0..63
  const int lk = (tid & 3)*8;       // 0,8,16,24
  float acc[4][4] = {};
  for (int k0 = 0; k0 < K; k0 += 32){
    const float* Ap = A + (size_t)(row0+lm)*K + k0 + lk;
    const float* Wp = W + (size_t)(col0+lm)*K + k0 + lk;
#pragma unroll
    for (int j = 0; j < 8; ++j) As[lk+j][lm] = Ap[j];
#pragma unroll
    for (int j = 0; j < 8; ++j) Ws[lk+j][lm] = Wp[j];
    __syncthreads();
#pragma unroll
    for (int kk = 0; kk < 32; ++kk){
      float av[4], wv[4];
      *(float4*)av = *(const float4*)&As[kk][tr*4];
      *(float4*)wv = *(const float4*)&Ws[kk][tc*4];
#pragma unroll
      for (int i = 0; i < 4; ++i)
#pragma unroll
        for (int j = 0; j < 4; ++j)
          acc[i][j] = fmaf(av[i], wv[j], acc[i][j]);
    }
    __syncthreads();
  }
#pragma unroll
  for (int i = 0; i < 4; ++i){
    int r = row0 + tr*4 + i;
    float* Cr = C + (size_t)r*N + col0 + tc*4;
#pragma unroll
    for (int j = 0; j < 4; ++j){
      float v = acc[i][j];
      if (bias) v += bias[col0 + tc*4 + j];
      if (ACT == 1) v = fmaxf(v, 0.f);
      Cr[j] = v;
    }
  }
}

template<int ACT>
__global__ __launch_bounds__(256) void k_gemm(const float* __restrict__ A, const float* __restrict__ W,
                                              const float* __restrict__ bias, float* __restrict__ C,
                                              int M, int N, int K){
  gemm_tile<ACT>(A, W, bias, C, N, K, blockIdx.y*64, blockIdx.x*64);
}

// fused xl/xr
__global__ __launch_bounds__(256) void k_gemm_lr(const float* __restrict__ A,
                                                 const float* __restrict__ Wl, const float* __restrict__ Wr,
                                                 float* __restrict__ xl, float* __restrict__ xr){
  int bx = blockIdx.x;
  if (bx < HC_/64)
    gemm_tile<0>(A, Wl, nullptr, xl, HC_, G_, blockIdx.y*64, bx*64);
  else
    gemm_tile<0>(A, Wr, nullptr, xr, HC_, G_, blockIdx.y*64, (bx - HC_/64)*64);
}

// ---------------- thin GEMM v4: LDS-staged At AND W, double-buffered ----
// Ct[c][tok] = bias[c] + sum_k At[k][tok]*W[c][k]; FB=8 features/block.
// Per chunk: At[KC][64] (8 float4/thread) + W[FB][KC] (1 float4/thread) staged
// via registers -> LDS; next chunk's loads issued before compute (latency hidden).
template<int ACT, int KC, int FB>
__global__ __launch_bounds__(256) void k_tgemm(const float* __restrict__ At, const float* __restrict__ W,
                                               const float* __restrict__ bias, float* __restrict__ Ct,
                                               int K){
  constexpr int FPG = FB/4;
  constexpr int APT = KC*64/4/256;        // float4s of At per thread (8 @ KC=128)
  constexpr int WPT = (FB*KC/4 + 255)/256;// float4s of W per thread (1)
  __shared__ float AtS[2][KC*64];
  __shared__ float WsS[2][FB*KC];
  const int tid = threadIdx.x;
  const int c0 = blockIdx.x*FB;
  const int lane = tid & 63;
  const int fg = tid >> 6;                // wave-uniform
  float acc[FPG];
#pragma unroll
  for (int i = 0; i < FPG; ++i) acc[i] = 0.f;

  float4 ra[APT]; float4 rw[WPT];
  const int wr = tid / (KC/4);            // W row for this thread's float4
  const int wc = tid % (KC/4);

  auto load_chunk = [&](int k0){
    const float4* ap = (const float4*)(At + (size_t)k0*64);
#pragma unroll
    for (int i = 0; i < APT; ++i) ra[i] = ap[tid + i*256];
#pragma unroll
    for (int i = 0; i < WPT; ++i)
      rw[i] = *(const float4*)(W + (size_t)(c0+wr)*K + k0 + wc*4);
  };
  auto store_chunk = [&](int buf){
    float4* as = (float4*)AtS[buf];
#pragma unroll
    for (int i = 0; i < APT; ++i) as[tid + i*256] = ra[i];
#pragma unroll
    for (int i = 0; i < WPT; ++i)
      *(float4*)&WsS[buf][wr*KC + wc*4] = rw[i];
  };

  const int nc = K / KC;
  load_chunk(0);
  store_chunk(0);
  __syncthreads();
  for (int c = 0; c < nc; ++c){
    const int buf = c & 1;
    if (c+1 < nc) load_chunk((c+1)*KC);   // in-flight during compute
#pragma unroll 8
    for (int k = 0; k < KC; ++k){
      float a = AtS[buf][k*64 + lane];
#pragma unroll
      for (int i = 0; i < FPG; ++i)
        acc[i] = fmaf(a, WsS[buf][(fg*FPG + i)*KC + k], acc[i]);
    }
    if (c+1 < nc){
      __syncthreads();
      store_chunk(buf^1);
      __syncthreads();
    }
  }
#pragma unroll
  for (int i = 0; i < FPG; ++i){
    int c = c0 + fg*FPG + i;
    float v = acc[i] + bias[c];
    if (ACT == 1) v = fmaxf(v, 0.f);
    Ct[(size_t)c*64 + lane] = v;
  }
}

// ---------------- fused GAT layer v2: head-sliced lanes ----------------
__global__ __launch_bounds__(256) void k_gat(const float* __restrict__ xl, const float* __restrict__ xr,
                                             const float* __restrict__ ea, const float* __restrict__ sl,
                                             const int* __restrict__ off, const int* __restrict__ eid,
                                             const int* __restrict__ srcv,
                                             const float* __restrict__ we, const float* __restrict__ att,
                                             const float* __restrict__ hin, const float* __restrict__ gb,
                                             const float* __restrict__ lw, const float* __restrict__ lb,
                                             float* __restrict__ hout){
  const int b = blockIdx.x;
  const int t = b & 7;
  const int n = (b >> 3)*4 + (threadIdx.x >> 6);
  const int lane = threadIdx.x & 63;
  const int h   = lane >> 4;
  const int l16 = lane & 15;
  const int c0  = h*64 + l16*4;

  const float4 attc = *(const float4*)(att + c0);
  const float4 wea  = *(const float4*)(we + 2*c0);
  const float4 web  = *(const float4*)(we + 2*c0 + 4);
  const float4 xrn  = *(const float4*)(xr + ((size_t)t*N_ + n)*HC_ + c0);
  const float* xlt = xl + (size_t)t*N_*HC_ + c0;

  const int o = off[n], deg = off[n+1] - o;

  float m, s; float4 acc;
  {
    float2 a2 = *(const float2*)(sl + ((size_t)t*N_ + n)*2);
    float4 xv = *(const float4*)(xlt + (size_t)n*HC_);
    float v0 = xv.x + xrn.x + a2.x*wea.x + a2.y*wea.y;
    float v1 = xv.y + xrn.y + a2.x*wea.z + a2.y*wea.w;
    float v2 = xv.z + xrn.z + a2.x*web.x + a2.y*web.y;
    float v3 = xv.w + xrn.w + a2.x*web.z + a2.y*web.w;
    v0 = (v0 >= 0.f)? v0 : NEG_*v0;
    v1 = (v1 >= 0.f)? v1 : NEG_*v1;
    v2 = (v2 >= 0.f)? v2 : NEG_*v2;
    v3 = (v3 >= 0.f)? v3 : NEG_*v3;
    float p = v0*attc.x + v1*attc.y + v2*attc.z + v3*attc.w;
    p += __shfl_xor(p, 1, 64); p += __shfl_xor(p, 2, 64);
    p += __shfl_xor(p, 4, 64); p += __shfl_xor(p, 8, 64);
    m = p; s = 1.f; acc = xv;
  }

  if (deg > 0){
    int e = eid[o];
    float2 a2 = *(const float2*)(ea + ((size_t)t*E_ + e)*2);
    float4 xnext = *(const float4*)(xlt + (size_t)srcv[e]*HC_);
    for (int j = 0; j < deg; ++j){
      float4 xv = xnext; float2 ac = a2;
      if (j+1 < deg){
        int e2 = eid[o+j+1];
        a2 = *(const float2*)(ea + ((size_t)t*E_ + e2)*2);
        xnext = *(const float4*)(xlt + (size_t)srcv[e2]*HC_);
      }
      float v0 = xv.x + xrn.x + ac.x*wea.x + ac.y*wea.y;
      float v1 = xv.y + xrn.y + ac.x*wea.z + ac.y*wea.w;
      float v2 = xv.z + xrn.z + ac.x*web.x + ac.y*web.y;
      float v3 = xv.w + xrn.w + ac.x*web.z + ac.y*web.w;
      v0 = (v0 >= 0.f)? v0 : NEG_*v0;
      v1 = (v1 >= 0.f)? v1 : NEG_*v1;
      v2 = (v2 >= 0.f)? v2 : NEG_*v2;
      v3 = (v3 >= 0.f)? v3 : NEG_*v3;
      float p = v0*attc.x + v1*attc.y + v2*attc.z + v3*attc.w;
      p += __shfl_xor(p, 1, 64); p += __shfl_xor(p, 2, 64);
      p += __shfl_xor(p, 4, 64); p += __shfl_xor(p, 8, 64);
      float nm = fmaxf(m, p);
      float e1 = __expf(m - nm);
      float e2v = __expf(p - nm);
      s = fmaf(s, e1, e2v);
      acc.x = fmaf(acc.x, e1, e2v*xv.x);
      acc.y = fmaf(acc.y, e1, e2v*xv.y);
      acc.z = fmaf(acc.z, e1, e2v*xv.z);
      acc.w = fmaf(acc.w, e1, e2v*xv.w);
      m = nm;
    }
  }

  float inv = 1.f / s;
  float o0 = acc.x*inv, o1 = acc.y*inv, o2 = acc.z*inv, o3 = acc.w*inv;
  o0 += __shfl_xor(o0, 16, 64); o1 += __shfl_xor(o1, 16, 64);
  o2 += __shfl_xor(o2, 16, 64); o3 += __shfl_xor(o3, 16, 64);
  o0 += __shfl_xor(o0, 32, 64); o1 += __shfl_xor(o1, 32, 64);
  o2 += __shfl_xor(o2, 32, 64); o3 += __shfl_xor(o3, 32, 64);

  const int g0 = l16*4;
  float4 gbv = *(const float4*)(gb + g0);
  float4 hv  = *(const float4*)(hin + ((size_t)t*N_ + n)*G_ + g0);
  float w0 = fmaxf(0.25f*o0 + gbv.x, 0.f) + hv.x;
  float w1 = fmaxf(0.25f*o1 + gbv.y, 0.f) + hv.y;
  float w2 = fmaxf(0.25f*o2 + gbv.z, 0.f) + hv.z;
  float w3 = fmaxf(0.25f*o3 + gbv.w, 0.f) + hv.w;

  float ssum = w0 + w1 + w2 + w3;
  ssum += __shfl_xor(ssum, 1, 64); ssum += __shfl_xor(ssum, 2, 64);
  ssum += __shfl_xor(ssum, 4, 64); ssum += __shfl_xor(ssum, 8, 64);
  float mu = ssum * (1.f/64.f);
  float d0 = w0-mu, d1 = w1-mu, d2 = w2-mu, d3 = w3-mu;
  float q = d0*d0 + d1*d1 + d2*d2 + d3*d3;
  q += __shfl_xor(q, 1, 64); q += __shfl_xor(q, 2, 64);
  q += __shfl_xor(q, 4, 64); q += __shfl_xor(q, 8, 64);
  float rstd = 1.f / sqrtf(q*(1.f/64.f) + EPS_);

  if (h == 0){
    float4 lwv = *(const float4*)(lw + g0);
    float4 lbv = *(const float4*)(lb + g0);
    float4 r;
    r.x = d0*rstd*lwv.x + lbv.x;
    r.y = d1*rstd*lwv.y + lbv.y;
    r.z = d2*rstd*lwv.z + lbv.z;
    r.w = d3*rstd*lwv.w + lbv.w;
    *(float4*)(hout + ((size_t)t*N_ + n)*G_ + g0) = r;
  }
}

// ---------------- pooling -> pooled_t[128][64] (feature-major) ----------------
__global__ __launch_bounds__(256) void k_pool(const float* __restrict__ h, float* __restrict__ pooled_t){
  int tb = blockIdx.x;                 // token = t*8+b
  int t = tb >> 3, b = tb & 7;
  int lane = threadIdx.x & 63, w = threadIdx.x >> 6;
  const float* hp = h + ((size_t)t*N_ + b*NP_)*G_;
  float s = 0.f, m = -1e30f;
  for (int n = w*100; n < (w+1)*100; ++n){
    float v = hp[(size_t)n*G_ + lane];
    s += v; m = fmaxf(m, v);
  }
  __shared__ float ss[4][64], mm[4][64];
  ss[w][lane] = s; mm[w][lane] = m;
  __syncthreads();
  if (w == 0){
    s = ss[0][lane] + ss[1][lane] + ss[2][lane] + ss[3][lane];
    m = fmaxf(fmaxf(mm[0][lane], mm[1][lane]), fmaxf(mm[2][lane], mm[3][lane]));
    pooled_t[(size_t)lane*64 + tb]      = s * (1.f/400.f);
    pooled_t[(size_t)(64+lane)*64 + tb] = m;
  }
}

// ---------------- tok_t -> y, y_t, motion ----------------
__global__ void k_tokout(const float* __restrict__ tok_t, float* __restrict__ y,
                         float* __restrict__ yt, float* __restrict__ mo){
  int i = blockIdx.x*256 + threadIdx.x;
  if (i >= D_*64) return;
  int tk = i & 63;              // t*8+b
  int c = i >> 6;
  int t = tk >> 3, b = tk & 7;
  float v = tok_t[(size_t)c*64 + tk];
  int yrow = b*8 + t;
  y[(size_t)yrow*D_ + c] = v;
  yt[(size_t)c*64 + yrow] = v;
  if (c < 256 && t < 7)
    mo[((size_t)b*7 + t)*256 + c] = tok_t[(size_t)c*64 + (tk+8)] - v;  // (t+1)*8+b
}

// ---------------- MHA: reads qkv_t[1536][64], writes attno_t[512][64] ----------------
__global__ __launch_bounds__(64) void k_mha(const float* __restrict__ qkv_t, float* __restrict__ o_t){
  int bh = blockIdx.x;
  int b = bh >> 3, hd = bh & 7;
  __shared__ float q[8][64], k[8][64], v[8][64], p[8][8];
  int tid = threadIdx.x;
  int tt = tid >> 3, d0 = (tid & 7)*8;
  int row = b*8 + tt;           // y-row token
#pragma unroll
  for (int j = 0; j < 8; ++j){
    int f = hd*64 + d0 + j;
    q[tt][d0+j] = qkv_t[(size_t)f*64 + row];
    k[tt][d0+j] = qkv_t[(size_t)(512+f)*64 + row];
    v[tt][d0+j] = qkv_t[(size_t)(1024+f)*64 + row];
  }
  __syncthreads();
  int tq = tid >> 3, tk = tid & 7;
  float s = 0.f;
#pragma unroll
  for (int d = 0; d < 64; ++d) s += q[tq][d]*k[tk][d];
  p[tq][tk] = s * 0.125f;
  __syncthreads();
  if (tid < 8){
    float mx = -1e30f;
#pragma unroll
    for (int j = 0; j < 8; ++j) mx = fmaxf(mx, p[tid][j]);
    float smv = 0.f;
#pragma unroll
    for (int j = 0; j < 8; ++j){ float e = expf(p[tid][j]-mx); p[tid][j] = e; smv += e; }
    float r = 1.f/smv;
#pragma unroll
    for (int j = 0; j < 8; ++j) p[tid][j] *= r;
  }
  __syncthreads();
  float out[8];
#pragma unroll
  for (int j = 0; j < 8; ++j) out[j] = 0.f;
#pragma unroll
  for (int t2 = 0; t2 < 8; ++t2){
    float wv = p[tq][t2];
#pragma unroll
    for (int j = 0; j < 8; ++j) out[j] = fmaf(wv, v[t2][d0+j], out[j]);
  }
  int orow = b*8 + tq;
#pragma unroll
  for (int j = 0; j < 8; ++j) o_t[(size_t)(hd*64 + d0 + j)*64 + orow] = out[j];
}

// ---------------- residual(+transposed res) + LayerNorm; writes y and y_t ----------------
__global__ __launch_bounds__(256) void k_lnadd(float* __restrict__ y, float* __restrict__ yt,
                                               const float* __restrict__ res_t,
                                               const float* __restrict__ w, const float* __restrict__ b){
  int row = blockIdx.x*4 + (threadIdx.x >> 6);
  int lane = threadIdx.x & 63;
  float* yr = y + (size_t)row*D_;
  float v[8]; float s = 0.f;
#pragma unroll
  for (int i = 0; i < 8; ++i){
    int c = lane + i*64;
    v[i] = yr[c] + res_t[(size_t)c*64 + row];
    s += v[i];
  }
  s = wred_sum(s);
  float mu = s * (1.f/512.f);
  float qq = 0.f;
#pragma unroll
  for (int i = 0; i < 8; ++i){ float d = v[i]-mu; qq += d*d; }
  qq = wred_sum(qq);
  float rstd = 1.f / sqrtf(qq*(1.f/512.f) + EPS_);
#pragma unroll
  for (int i = 0; i < 8; ++i){
    int c = lane + i*64;
    float ov = (v[i]-mu)*rstd*w[c] + b[c];
    yr[c] = ov;
    yt[(size_t)c*64 + row] = ov;
  }
}

extern "C" void kernel_launch(void* const* d_in, const int* in_sizes, int n_in,
                              void* d_out, int out_size, void* d_ws, size_t ws_size,
                              hipStream_t stream){
  const float* x       = (const float*)d_in[0];
  const int*   ei      = (const int*)d_in[1];
  const float* eattr   = (const float*)d_in[2];
  const float* proj_w  = (const float*)d_in[4];
  const float* proj_b  = (const float*)d_in[5];
  const float* gat_wl  = (const float*)d_in[6];
  const float* gat_wr  = (const float*)d_in[7];
  const float* gat_we  = (const float*)d_in[8];
  const float* gat_att = (const float*)d_in[9];
  const float* gat_b   = (const float*)d_in[10];
  const float* ln_w    = (const float*)d_in[11];
  const float* ln_b    = (const float*)d_in[12];
  const float* n2t_w   = (const float*)d_in[13];
  const float* n2t_b   = (const float*)d_in[14];
  const float* wqkv    = (const float*)d_in[15];
  const float* bqkv    = (const float*)d_in[16];
  const float* wo      = (const float*)d_in[17];
  const float* bo      = (const float*)d_in[18];
  const float* w1      = (const float*)d_in[19];
  const float* b1      = (const float*)d_in[20];
  const float* w2      = (const float*)d_in[21];
  const float* b2      = (const float*)d_in[22];
  const float* ln1w    = (const float*)d_in[23];
  const float* ln1b    = (const float*)d_in[24];
  const float* ln2w    = (const float*)d_in[25];
  const float* ln2b    = (const float*)d_in[26];

  const int* src0 = ei;
  const int* dst0 = ei + E_;

  char* p = (char*)d_ws;
  auto alloc = [&](size_t bytes){ void* r = (void*)p; p += (bytes + 255) & ~(size_t)255; return r; };
  int* cnt   = (int*)alloc((size_t)N_*4);
  int* off   = (int*)alloc((size_t)(N_+1)*4);
  int* pos   = (int*)alloc((size_t)N_*4);
  int* eid   = (int*)alloc((size_t)E_*4);
  float* sl  = (float*)alloc((size_t)T_*N_*2*4);
  float* hA  = (float*)alloc((size_t)T_*N_*G_*4);
  float* hB  = (float*)alloc((size_t)T_*N_*G_*4);
  float* xl  = (float*)alloc((size_t)T_*N_*HC_*4);
  float* xr  = (float*)alloc((size_t)T_*N_*HC_*4);
  float* pooled_t = (float*)alloc(128*64*4);
  float* tok_t    = (float*)alloc(512*64*4);
  float* yt       = (float*)alloc(512*64*4);
  float* qkv_t    = (float*)alloc(1536*64*4);
  float* attno_t  = (float*)alloc(512*64*4);
  float* mo_t     = (float*)alloc(512*64*4);
  float* f1t      = (float*)alloc(2048*64*4);

  float* y    = (float*)d_out;          // [B,T,D] transformer state, final output 1
  float* mout = y + B_*T_*D_;           // motion, final output 2

  // CSR + self-loop attrs
  k_zero_i  <<<dim3((N_+255)/256), dim3(256), 0, stream>>>(cnt, N_);
  k_count   <<<dim3((E_+255)/256), dim3(256), 0, stream>>>(dst0, cnt);
  k_scan    <<<dim3(1), dim3(256), 0, stream>>>(cnt, off, pos);
  k_scatter <<<dim3((E_+255)/256), dim3(256), 0, stream>>>(dst0, pos, eid);
  k_sl      <<<dim3((T_*N_+255)/256), dim3(256), 0, stream>>>(eattr, off, eid, sl);

  // input projection
  k_gemm<0><<<dim3(1, (T_*N_)/64), dim3(256), 0, stream>>>(x, proj_w, proj_b, hA, T_*N_, G_, IND_);

  float* hcur = hA; float* hnext = hB;
  for (int i = 0; i < 3; ++i){
    k_gemm_lr<<<dim3(2*HC_/64, (T_*N_)/64), dim3(256), 0, stream>>>(hcur,
        gat_wl + (size_t)i*HC_*G_, gat_wr + (size_t)i*HC_*G_, xl, xr);
    k_gat<<<dim3(T_*N_/4), dim3(256), 0, stream>>>(xl, xr, eattr, sl, off, eid, src0,
        gat_we + (size_t)i*HC_*2, gat_att + (size_t)i*HC_, hcur,
        gat_b + i*G_, ln_w + i*G_, ln_b + i*G_, hnext);
    float* tmp = hcur; hcur = hnext; hnext = tmp;
  }

  // pool + node2token (transposed chain)
  k_pool<<<dim3(T_*B_), dim3(256), 0, stream>>>(hcur, pooled_t);
  k_tgemm<0,128,8><<<dim3(D_/8), dim3(256), 0, stream>>>(pooled_t, n2t_w, n2t_b, tok_t, 128);
  k_tokout<<<dim3((D_*64+255)/256), dim3(256), 0, stream>>>(tok_t, y, yt, mout);

  // transformer encoder, 2 layers (feature-major activations)
  for (int l = 0; l < 2; ++l){
    k_tgemm<0,128,8><<<dim3(1536/8), dim3(256), 0, stream>>>(yt, wqkv + (size_t)l*1536*512, bqkv + l*1536, qkv_t, 512);
    k_mha<<<dim3(64), dim3(64), 0, stream>>>(qkv_t, attno_t);
    k_tgemm<0,128,8><<<dim3(512/8), dim3(256), 0, stream>>>(attno_t, wo + (size_t)l*512*512, bo + l*512, mo_t, 512);
    k_lnadd<<<dim3(16), dim3(256), 0, stream>>>(y, yt, mo_t, ln1w + l*512, ln1b + l*512);
    k_tgemm<1,128,8><<<dim3(2048/8), dim3(256), 0, stream>>>(yt, w1 + (size_t)l*2048*512, b1 + l*2048, f1t, 512);
    k_tgemm<0,128,8><<<dim3(512/8), dim3(256), 0, stream>>>(f1t, w2 + (size_t)l*512*2048, b2 + l*512, mo_t, 2048);
    k_lnadd<<<dim3(16), dim3(256), 0, stream>>>(y, yt, mo_t, ln2w + l*512, ln2b + l*512);
  }
}

// Round 14
// 461.427 us; speedup vs baseline: 2.1605x; 1.3968x over previous
//
#include <hip/hip_runtime.h>
#include <math.h>

#define T_ 8
#define N_ 3200
#define E_ 25600
#define B_ 8
#define NP_ 400
#define IND_ 128
#define G_ 64
#define HC_ 256
#define D_ 512
#define NEG_ 0.2f
#define EPS_ 1e-5f

__device__ __forceinline__ float wred_sum(float v){
#pragma unroll
  for (int o = 32; o; o >>= 1) v += __shfl_xor(v, o, 64);
  return v;
}

// ---------------- CSR build ----------------
__global__ void k_zero_i(int* p, int n){
  int i = blockIdx.x*256 + threadIdx.x;
  if (i < n) p[i] = 0;
}

__global__ void k_zero_f4(float4* p, int n4){
  int i = blockIdx.x*256 + threadIdx.x;
  if (i < n4) p[i] = make_float4(0.f,0.f,0.f,0.f);
}

__global__ void k_count(const int* __restrict__ dst, int* __restrict__ cnt){
  int e = blockIdx.x*256 + threadIdx.x;
  if (e < E_) atomicAdd(&cnt[dst[e]], 1);
}

__global__ void k_scan(const int* __restrict__ cnt, int* __restrict__ off, int* __restrict__ pos){
  __shared__ int part[256];
  int tid = threadIdx.x;
  const int CH = 13;               // 256*13 = 3328 >= 3200
  int base = tid*CH;
  int s = 0;
  for (int i = 0; i < CH; ++i){ int idx = base+i; s += (idx < N_) ? cnt[idx] : 0; }
  part[tid] = s; __syncthreads();
  for (int d = 1; d < 256; d <<= 1){
    int v = (tid >= d) ? part[tid-d] : 0;
    __syncthreads();
    part[tid] += v;
    __syncthreads();
  }
  int run = tid ? part[tid-1] : 0;
  for (int i = 0; i < CH; ++i){
    int idx = base+i;
    if (idx < N_){ off[idx] = run; pos[idx] = run; run += cnt[idx]; }
  }
  if (tid == 255) off[N_] = part[255];
}

__global__ void k_scatter(const int* __restrict__ dst, int* __restrict__ pos, int* __restrict__ eid){
  int e = blockIdx.x*256 + threadIdx.x;
  if (e < E_){ int p = atomicAdd(&pos[dst[e]], 1); eid[p] = e; }
}

// self-loop attr: per-target mean of incoming edge_attr
__global__ void k_sl(const float* __restrict__ ea, const int* __restrict__ off,
                     const int* __restrict__ eid, float* __restrict__ sl){
  int idx = blockIdx.x*256 + threadIdx.x;
  if (idx >= T_*N_) return;
  int t = idx / N_, n = idx % N_;
  int o = off[n], d = off[n+1] - o;
  float s0 = 0.f, s1 = 0.f;
  for (int j = 0; j < d; ++j){
    int e = eid[o+j];
    const float* p = ea + ((size_t)t*E_ + e)*2;
    s0 += p[0]; s1 += p[1];
  }
  float c = fmaxf((float)d, 1.f);
  sl[(size_t)idx*2]   = s0 / c;
  sl[(size_t)idx*2+1] = s1 / c;
}

// ---------------- generic GEMM tile body: C[M,N] = A[M,K] @ W[N,K]^T (+bias) ----
template<int ACT>
__device__ __forceinline__ void gemm_tile(const float* __restrict__ A, const float* __restrict__ W,
                                          const float* __restrict__ bias, float* __restrict__ C,
                                          int N, int K, int row0, int col0){
  __shared__ float As[32][68];
  __shared__ float Ws[32][68];
  const int tid = threadIdx.x;
  const int tr = tid >> 4, tc = tid & 15;
  const int lm = tid >> 2;          // 0..63
  const int lk = (tid & 3)*8;       // 0,8,16,24
  float acc[4][4] = {};
  for (int k0 = 0; k0 < K; k0 += 32){
    const float* Ap = A + (size_t)(row0+lm)*K + k0 + lk;
    const float* Wp = W + (size_t)(col0+lm)*K + k0 + lk;
#pragma unroll
    for (int j = 0; j < 8; ++j) As[lk+j][lm] = Ap[j];
#pragma unroll
    for (int j = 0; j < 8; ++j) Ws[lk+j][lm] = Wp[j];
    __syncthreads();
#pragma unroll
    for (int kk = 0; kk < 32; ++kk){
      float av[4], wv[4];
      *(float4*)av = *(const float4*)&As[kk][tr*4];
      *(float4*)wv = *(const float4*)&Ws[kk][tc*4];
#pragma unroll
      for (int i = 0; i < 4; ++i)
#pragma unroll
        for (int j = 0; j < 4; ++j)
          acc[i][j] = fmaf(av[i], wv[j], acc[i][j]);
    }
    __syncthreads();
  }
#pragma unroll
  for (int i = 0; i < 4; ++i){
    int r = row0 + tr*4 + i;
    float* Cr = C + (size_t)r*N + col0 + tc*4;
#pragma unroll
    for (int j = 0; j < 4; ++j){
      float v = acc[i][j];
      if (bias) v += bias[col0 + tc*4 + j];
      if (ACT == 1) v = fmaxf(v, 0.f);
      Cr[j] = v;
    }
  }
}

template<int ACT>
__global__ __launch_bounds__(256) void k_gemm(const float* __restrict__ A, const float* __restrict__ W,
                                              const float* __restrict__ bias, float* __restrict__ C,
                                              int M, int N, int K){
  gemm_tile<ACT>(A, W, bias, C, N, K, blockIdx.y*64, blockIdx.x*64);
}

// fused xl/xr
__global__ __launch_bounds__(256) void k_gemm_lr(const float* __restrict__ A,
                                                 const float* __restrict__ Wl, const float* __restrict__ Wr,
                                                 float* __restrict__ xl, float* __restrict__ xr){
  int bx = blockIdx.x;
  if (bx < HC_/64)
    gemm_tile<0>(A, Wl, nullptr, xl, HC_, G_, blockIdx.y*64, bx*64);
  else
    gemm_tile<0>(A, Wr, nullptr, xr, HC_, G_, blockIdx.y*64, (bx - HC_/64)*64);
}

// ---------------- thin GEMM v5: split-K, atomic accumulate ----------------
// grid = (N/FB, K/KC). Block stages At[KC][64] + W[FB][KC] into LDS, computes
// a partial Ct[c][tok] and atomicAdds it. Bias/activation applied by consumers.
// LDS = 36KB -> 4 blocks/CU; blocks per GEMM 256-1024 -> all CUs stream weights.
template<int KC, int FB>
__global__ __launch_bounds__(256) void k_tgemm_sk(const float* __restrict__ At, const float* __restrict__ W,
                                                  float* __restrict__ Ct, int K){
  constexpr int FPG = FB/4;
  constexpr int APT = KC*64/(4*256);      // float4s of At per thread (8 @ KC=128)
  __shared__ float AtS[KC*64];
  __shared__ float WsS[FB*KC];
  const int tid = threadIdx.x;
  const int c0 = blockIdx.x*FB;
  const int k0 = blockIdx.y*KC;
  const int lane = tid & 63;
  const int fg = tid >> 6;                // wave-uniform
  {
    const float4* ap = (const float4*)(At + (size_t)k0*64);
    float4* as = (float4*)AtS;
#pragma unroll
    for (int i = 0; i < APT; ++i) as[tid + i*256] = ap[tid + i*256];
    const int wr = tid / (KC/4), wc = tid % (KC/4);
    *(float4*)&WsS[wr*KC + wc*4] = *(const float4*)(W + (size_t)(c0+wr)*K + k0 + wc*4);
  }
  __syncthreads();
  float acc[FPG] = {};
#pragma unroll 8
  for (int k = 0; k < KC; ++k){
    float a = AtS[k*64 + lane];
#pragma unroll
    for (int i = 0; i < FPG; ++i)
      acc[i] = fmaf(a, WsS[(fg*FPG + i)*KC + k], acc[i]);
  }
#pragma unroll
  for (int i = 0; i < FPG; ++i)
    atomicAdd(&Ct[(size_t)(c0 + fg*FPG + i)*64 + lane], acc[i]);
}

// bias + relu epilogue for f1 (feature-major [nfeat][64])
__global__ void k_relub(float* __restrict__ f, const float* __restrict__ b, int total){
  int i = blockIdx.x*256 + threadIdx.x;
  if (i >= total) return;
  int c = i >> 6;
  f[i] = fmaxf(f[i] + b[c], 0.f);
}

// ---------------- fused GAT layer v2: head-sliced lanes ----------------
__global__ __launch_bounds__(256) void k_gat(const float* __restrict__ xl, const float* __restrict__ xr,
                                             const float* __restrict__ ea, const float* __restrict__ sl,
                                             const int* __restrict__ off, const int* __restrict__ eid,
                                             const int* __restrict__ srcv,
                                             const float* __restrict__ we, const float* __restrict__ att,
                                             const float* __restrict__ hin, const float* __restrict__ gb,
                                             const float* __restrict__ lw, const float* __restrict__ lb,
                                             float* __restrict__ hout){
  const int b = blockIdx.x;
  const int t = b & 7;
  const int n = (b >> 3)*4 + (threadIdx.x >> 6);
  const int lane = threadIdx.x & 63;
  const int h   = lane >> 4;
  const int l16 = lane & 15;
  const int c0  = h*64 + l16*4;

  const float4 attc = *(const float4*)(att + c0);
  const float4 wea  = *(const float4*)(we + 2*c0);
  const float4 web  = *(const float4*)(we + 2*c0 + 4);
  const float4 xrn  = *(const float4*)(xr + ((size_t)t*N_ + n)*HC_ + c0);
  const float* xlt = xl + (size_t)t*N_*HC_ + c0;

  const int o = off[n], deg = off[n+1] - o;

  float m, s; float4 acc;
  {
    float2 a2 = *(const float2*)(sl + ((size_t)t*N_ + n)*2);
    float4 xv = *(const float4*)(xlt + (size_t)n*HC_);
    float v0 = xv.x + xrn.x + a2.x*wea.x + a2.y*wea.y;
    float v1 = xv.y + xrn.y + a2.x*wea.z + a2.y*wea.w;
    float v2 = xv.z + xrn.z + a2.x*web.x + a2.y*web.y;
    float v3 = xv.w + xrn.w + a2.x*web.z + a2.y*web.w;
    v0 = (v0 >= 0.f)? v0 : NEG_*v0;
    v1 = (v1 >= 0.f)? v1 : NEG_*v1;
    v2 = (v2 >= 0.f)? v2 : NEG_*v2;
    v3 = (v3 >= 0.f)? v3 : NEG_*v3;
    float p = v0*attc.x + v1*attc.y + v2*attc.z + v3*attc.w;
    p += __shfl_xor(p, 1, 64); p += __shfl_xor(p, 2, 64);
    p += __shfl_xor(p, 4, 64); p += __shfl_xor(p, 8, 64);
    m = p; s = 1.f; acc = xv;
  }

  if (deg > 0){
    int e = eid[o];
    float2 a2 = *(const float2*)(ea + ((size_t)t*E_ + e)*2);
    float4 xnext = *(const float4*)(xlt + (size_t)srcv[e]*HC_);
    for (int j = 0; j < deg; ++j){
      float4 xv = xnext; float2 ac = a2;
      if (j+1 < deg){
        int e2 = eid[o+j+1];
        a2 = *(const float2*)(ea + ((size_t)t*E_ + e2)*2);
        xnext = *(const float4*)(xlt + (size_t)srcv[e2]*HC_);
      }
      float v0 = xv.x + xrn.x + ac.x*wea.x + ac.y*wea.y;
      float v1 = xv.y + xrn.y + ac.x*wea.z + ac.y*wea.w;
      float v2 = xv.z + xrn.z + ac.x*web.x + ac.y*web.y;
      float v3 = xv.w + xrn.w + ac.x*web.z + ac.y*web.w;
      v0 = (v0 >= 0.f)? v0 : NEG_*v0;
      v1 = (v1 >= 0.f)? v1 : NEG_*v1;
      v2 = (v2 >= 0.f)? v2 : NEG_*v2;
      v3 = (v3 >= 0.f)? v3 : NEG_*v3;
      float p = v0*attc.x + v1*attc.y + v2*attc.z + v3*attc.w;
      p += __shfl_xor(p, 1, 64); p += __shfl_xor(p, 2, 64);
      p += __shfl_xor(p, 4, 64); p += __shfl_xor(p, 8, 64);
      float nm = fmaxf(m, p);
      float e1 = __expf(m - nm);
      float e2v = __expf(p - nm);
      s = fmaf(s, e1, e2v);
      acc.x = fmaf(acc.x, e1, e2v*xv.x);
      acc.y = fmaf(acc.y, e1, e2v*xv.y);
      acc.z = fmaf(acc.z, e1, e2v*xv.z);
      acc.w = fmaf(acc.w, e1, e2v*xv.w);
      m = nm;
    }
  }

  float inv = 1.f / s;
  float o0 = acc.x*inv, o1 = acc.y*inv, o2 = acc.z*inv, o3 = acc.w*inv;
  o0 += __shfl_xor(o0, 16, 64); o1 += __shfl_xor(o1, 16, 64);
  o2 += __shfl_xor(o2, 16, 64); o3 += __shfl_xor(o3, 16, 64);
  o0 += __shfl_xor(o0, 32, 64); o1 += __shfl_xor(o1, 32, 64);
  o2 += __shfl_xor(o2, 32, 64); o3 += __shfl_xor(o3, 32, 64);

  const int g0 = l16*4;
  float4 gbv = *(const float4*)(gb + g0);
  float4 hv  = *(const float4*)(hin + ((size_t)t*N_ + n)*G_ + g0);
  float w0 = fmaxf(0.25f*o0 + gbv.x, 0.f) + hv.x;
  float w1 = fmaxf(0.25f*o1 + gbv.y, 0.f) + hv.y;
  float w2 = fmaxf(0.25f*o2 + gbv.z, 0.f) + hv.z;
  float w3 = fmaxf(0.25f*o3 + gbv.w, 0.f) + hv.w;

  float ssum = w0 + w1 + w2 + w3;
  ssum += __shfl_xor(ssum, 1, 64); ssum += __shfl_xor(ssum, 2, 64);
  ssum += __shfl_xor(ssum, 4, 64); ssum += __shfl_xor(ssum, 8, 64);
  float mu = ssum * (1.f/64.f);
  float d0 = w0-mu, d1 = w1-mu, d2 = w2-mu, d3 = w3-mu;
  float q = d0*d0 + d1*d1 + d2*d2 + d3*d3;
  q += __shfl_xor(q, 1, 64); q += __shfl_xor(q, 2, 64);
  q += __shfl_xor(q, 4, 64); q += __shfl_xor(q, 8, 64);
  float rstd = 1.f / sqrtf(q*(1.f/64.f) + EPS_);

  if (h == 0){
    float4 lwv = *(const float4*)(lw + g0);
    float4 lbv = *(const float4*)(lb + g0);
    float4 r;
    r.x = d0*rstd*lwv.x + lbv.x;
    r.y = d1*rstd*lwv.y + lbv.y;
    r.z = d2*rstd*lwv.z + lbv.z;
    r.w = d3*rstd*lwv.w + lbv.w;
    *(float4*)(hout + ((size_t)t*N_ + n)*G_ + g0) = r;
  }
}

// ---------------- pooling -> pooled_t[128][64] (feature-major) ----------------
__global__ __launch_bounds__(256) void k_pool(const float* __restrict__ h, float* __restrict__ pooled_t){
  int tb = blockIdx.x;                 // token = t*8+b
  int t = tb >> 3, b = tb & 7;
  int lane = threadIdx.x & 63, w = threadIdx.x >> 6;
  const float* hp = h + ((size_t)t*N_ + b*NP_)*G_;
  float s = 0.f, m = -1e30f;
  for (int n = w*100; n < (w+1)*100; ++n){
    float v = hp[(size_t)n*G_ + lane];
    s += v; m = fmaxf(m, v);
  }
  __shared__ float ss[4][64], mm[4][64];
  ss[w][lane] = s; mm[w][lane] = m;
  __syncthreads();
  if (w == 0){
    s = ss[0][lane] + ss[1][lane] + ss[2][lane] + ss[3][lane];
    m = fmaxf(fmaxf(mm[0][lane], mm[1][lane]), fmaxf(mm[2][lane], mm[3][lane]));
    pooled_t[(size_t)lane*64 + tb]      = s * (1.f/400.f);
    pooled_t[(size_t)(64+lane)*64 + tb] = m;
  }
}

// ---------------- tok_t (raw sums) + n2t bias -> y, y_t, motion ----------------
__global__ void k_tokout(const float* __restrict__ tok_t, const float* __restrict__ n2tb,
                         float* __restrict__ y, float* __restrict__ yt, float* __restrict__ mo){
  int i = blockIdx.x*256 + threadIdx.x;
  if (i >= D_*64) return;
  int tk = i & 63;              // t*8+b
  int c = i >> 6;
  int t = tk >> 3, b = tk & 7;
  float bb = n2tb[c];
  float v = tok_t[(size_t)c*64 + tk] + bb;
  int yrow = b*8 + t;
  y[(size_t)yrow*D_ + c] = v;
  yt[(size_t)c*64 + yrow] = v;
  if (c < 256 && t < 7)
    mo[((size_t)b*7 + t)*256 + c] = (tok_t[(size_t)c*64 + (tk+8)] + bb) - v;  // (t+1)*8+b
}

// ---------------- MHA: reads raw qkv_t + bias, writes attno_t[512][64] ----------------
__global__ __launch_bounds__(64) void k_mha(const float* __restrict__ qkv_t, const float* __restrict__ bqkv,
                                            float* __restrict__ o_t){
  int bh = blockIdx.x;
  int b = bh >> 3, hd = bh & 7;
  __shared__ float q[8][64], k[8][64], v[8][64], p[8][8];
  int tid = threadIdx.x;
  int tt = tid >> 3, d0 = (tid & 7)*8;
  int row = b*8 + tt;           // y-row token
#pragma unroll
  for (int j = 0; j < 8; ++j){
    int f = hd*64 + d0 + j;
    q[tt][d0+j] = qkv_t[(size_t)f*64 + row] + bqkv[f];
    k[tt][d0+j] = qkv_t[(size_t)(512+f)*64 + row] + bqkv[512+f];
    v[tt][d0+j] = qkv_t[(size_t)(1024+f)*64 + row] + bqkv[1024+f];
  }
  __syncthreads();
  int tq = tid >> 3, tk = tid & 7;
  float s = 0.f;
#pragma unroll
  for (int d = 0; d < 64; ++d) s += q[tq][d]*k[tk][d];
  p[tq][tk] = s * 0.125f;
  __syncthreads();
  if (tid < 8){
    float mx = -1e30f;
#pragma unroll
    for (int j = 0; j < 8; ++j) mx = fmaxf(mx, p[tid][j]);
    float smv = 0.f;
#pragma unroll
    for (int j = 0; j < 8; ++j){ float e = expf(p[tid][j]-mx); p[tid][j] = e; smv += e; }
    float r = 1.f/smv;
#pragma unroll
    for (int j = 0; j < 8; ++j) p[tid][j] *= r;
  }
  __syncthreads();
  float out[8];
#pragma unroll
  for (int j = 0; j < 8; ++j) out[j] = 0.f;
#pragma unroll
  for (int t2 = 0; t2 < 8; ++t2){
    float wv = p[tq][t2];
#pragma unroll
    for (int j = 0; j < 8; ++j) out[j] = fmaf(wv, v[t2][d0+j], out[j]);
  }
  int orow = b*8 + tq;
#pragma unroll
  for (int j = 0; j < 8; ++j) o_t[(size_t)(hd*64 + d0 + j)*64 + orow] = out[j];
}

// ---------------- residual(+transposed raw res + bias) + LayerNorm; writes y and y_t ---
__global__ __launch_bounds__(256) void k_lnadd(float* __restrict__ y, float* __restrict__ yt,
                                               const float* __restrict__ res_t, const float* __restrict__ rbias,
                                               const float* __restrict__ w, const float* __restrict__ b){
  int row = blockIdx.x*4 + (threadIdx.x >> 6);
  int lane = threadIdx.x & 63;
  float* yr = y + (size_t)row*D_;
  float v[8]; float s = 0.f;
#pragma unroll
  for (int i = 0; i < 8; ++i){
    int c = lane + i*64;
    v[i] = yr[c] + res_t[(size_t)c*64 + row] + rbias[c];
    s += v[i];
  }
  s = wred_sum(s);
  float mu = s * (1.f/512.f);
  float qq = 0.f;
#pragma unroll
  for (int i = 0; i < 8; ++i){ float d = v[i]-mu; qq += d*d; }
  qq = wred_sum(qq);
  float rstd = 1.f / sqrtf(qq*(1.f/512.f) + EPS_);
#pragma unroll
  for (int i = 0; i < 8; ++i){
    int c = lane + i*64;
    float ov = (v[i]-mu)*rstd*w[c] + b[c];
    yr[c] = ov;
    yt[(size_t)c*64 + row] = ov;
  }
}

extern "C" void kernel_launch(void* const* d_in, const int* in_sizes, int n_in,
                              void* d_out, int out_size, void* d_ws, size_t ws_size,
                              hipStream_t stream){
  const float* x       = (const float*)d_in[0];
  const int*   ei      = (const int*)d_in[1];
  const float* eattr   = (const float*)d_in[2];
  const float* proj_w  = (const float*)d_in[4];
  const float* proj_b  = (const float*)d_in[5];
  const float* gat_wl  = (const float*)d_in[6];
  const float* gat_wr  = (const float*)d_in[7];
  const float* gat_we  = (const float*)d_in[8];
  const float* gat_att = (const float*)d_in[9];
  const float* gat_b   = (const float*)d_in[10];
  const float* ln_w    = (const float*)d_in[11];
  const float* ln_b    = (const float*)d_in[12];
  const float* n2t_w   = (const float*)d_in[13];
  const float* n2t_b   = (const float*)d_in[14];
  const float* wqkv    = (const float*)d_in[15];
  const float* bqkv    = (const float*)d_in[16];
  const float* wo      = (const float*)d_in[17];
  const float* bo      = (const float*)d_in[18];
  const float* w1      = (const float*)d_in[19];
  const float* b1      = (const float*)d_in[20];
  const float* w2      = (const float*)d_in[21];
  const float* b2      = (const float*)d_in[22];
  const float* ln1w    = (const float*)d_in[23];
  const float* ln1b    = (const float*)d_in[24];
  const float* ln2w    = (const float*)d_in[25];
  const float* ln2b    = (const float*)d_in[26];

  const int* src0 = ei;
  const int* dst0 = ei + E_;

  char* p = (char*)d_ws;
  auto alloc = [&](size_t bytes){ void* r = (void*)p; p += (bytes + 255) & ~(size_t)255; return r; };
  int* cnt   = (int*)alloc((size_t)N_*4);
  int* off   = (int*)alloc((size_t)(N_+1)*4);
  int* pos   = (int*)alloc((size_t)N_*4);
  int* eid   = (int*)alloc((size_t)E_*4);
  float* sl  = (float*)alloc((size_t)T_*N_*2*4);
  float* hA  = (float*)alloc((size_t)T_*N_*G_*4);
  float* hB  = (float*)alloc((size_t)T_*N_*G_*4);
  float* xl  = (float*)alloc((size_t)T_*N_*HC_*4);
  float* xr  = (float*)alloc((size_t)T_*N_*HC_*4);
  float* pooled_t = (float*)alloc(128*64*4);
  float* yt       = (float*)alloc(512*64*4);
  float* attno_t  = (float*)alloc(512*64*4);
  // ---- atomic-accumulated buffers (contiguous; zeroed once) ----
  float* tok_t  = (float*)alloc(512*64*4);
  float* qkv0_t = (float*)alloc(1536*64*4);
  float* qkv1_t = (float*)alloc(1536*64*4);
  float* moA0_t = (float*)alloc(512*64*4);
  float* moB0_t = (float*)alloc(512*64*4);
  float* moA1_t = (float*)alloc(512*64*4);
  float* moB1_t = (float*)alloc(512*64*4);
  float* f10_t  = (float*)alloc(2048*64*4);
  float* f11_t  = (float*)alloc(2048*64*4);
  const int ZT4 = (512 + 1536*2 + 512*4 + 2048*2)*64/4;   // float4 count = 155648

  float* y    = (float*)d_out;          // [B,T,D] transformer state, final output 1
  float* mout = y + B_*T_*D_;           // motion, final output 2

  // zero atomic outputs (once) + CSR + self-loop attrs
  k_zero_f4 <<<dim3((ZT4+255)/256), dim3(256), 0, stream>>>((float4*)tok_t, ZT4);
  k_zero_i  <<<dim3((N_+255)/256), dim3(256), 0, stream>>>(cnt, N_);
  k_count   <<<dim3((E_+255)/256), dim3(256), 0, stream>>>(dst0, cnt);
  k_scan    <<<dim3(1), dim3(256), 0, stream>>>(cnt, off, pos);
  k_scatter <<<dim3((E_+255)/256), dim3(256), 0, stream>>>(dst0, pos, eid);
  k_sl      <<<dim3((T_*N_+255)/256), dim3(256), 0, stream>>>(eattr, off, eid, sl);

  // input projection
  k_gemm<0><<<dim3(1, (T_*N_)/64), dim3(256), 0, stream>>>(x, proj_w, proj_b, hA, T_*N_, G_, IND_);

  float* hcur = hA; float* hnext = hB;
  for (int i = 0; i < 3; ++i){
    k_gemm_lr<<<dim3(2*HC_/64, (T_*N_)/64), dim3(256), 0, stream>>>(hcur,
        gat_wl + (size_t)i*HC_*G_, gat_wr + (size_t)i*HC_*G_, xl, xr);
    k_gat<<<dim3(T_*N_/4), dim3(256), 0, stream>>>(xl, xr, eattr, sl, off, eid, src0,
        gat_we + (size_t)i*HC_*2, gat_att + (size_t)i*HC_, hcur,
        gat_b + i*G_, ln_w + i*G_, ln_b + i*G_, hnext);
    float* tmp = hcur; hcur = hnext; hnext = tmp;
  }

  // pool + node2token (split-K GEMM, bias applied in k_tokout)
  k_pool<<<dim3(T_*B_), dim3(256), 0, stream>>>(hcur, pooled_t);
  k_tgemm_sk<128,8><<<dim3(D_/8, 1), dim3(256), 0, stream>>>(pooled_t, n2t_w, tok_t, 128);
  k_tokout<<<dim3((D_*64+255)/256), dim3(256), 0, stream>>>(tok_t, n2t_b, y, yt, mout);

  // transformer encoder, 2 layers (feature-major activations, split-K GEMMs)
  float* qkvL[2] = {qkv0_t, qkv1_t};
  float* moAL[2] = {moA0_t, moA1_t};
  float* moBL[2] = {moB0_t, moB1_t};
  float* f1L[2]  = {f10_t, f11_t};
  for (int l = 0; l < 2; ++l){
    k_tgemm_sk<128,8><<<dim3(1536/8, 512/128), dim3(256), 0, stream>>>(yt, wqkv + (size_t)l*1536*512, qkvL[l], 512);
    k_mha<<<dim3(64), dim3(64), 0, stream>>>(qkvL[l], bqkv + l*1536, attno_t);
    k_tgemm_sk<128,8><<<dim3(512/8, 512/128), dim3(256), 0, stream>>>(attno_t, wo + (size_t)l*512*512, moAL[l], 512);
    k_lnadd<<<dim3(16), dim3(256), 0, stream>>>(y, yt, moAL[l], bo + l*512, ln1w + l*512, ln1b + l*512);
    k_tgemm_sk<128,8><<<dim3(2048/8, 512/128), dim3(256), 0, stream>>>(yt, w1 + (size_t)l*2048*512, f1L[l], 512);
    k_relub<<<dim3((2048*64+255)/256), dim3(256), 0, stream>>>(f1L[l], b1 + l*2048, 2048*64);
    k_tgemm_sk<128,8><<<dim3(512/8, 2048/128), dim3(256), 0, stream>>>(f1L[l], w2 + (size_t)l*512*2048, moBL[l], 2048);
    k_lnadd<<<dim3(16), dim3(256), 0, stream>>>(y, yt, moBL[l], b2 + l*512, ln2w + l*512, ln2b + l*512);
  }
}

// Round 15
// 459.289 us; speedup vs baseline: 2.1705x; 1.0047x over previous
//
#include <hip/hip_runtime.h>
#include <math.h>

#define T_ 8
#define N_ 3200
#define E_ 25600
#define B_ 8
#define NP_ 400
#define IND_ 128
#define G_ 64
#define HC_ 256
#define D_ 512
#define NEG_ 0.2f
#define EPS_ 1e-5f

__device__ __forceinline__ float wred_sum(float v){
#pragma unroll
  for (int o = 32; o; o >>= 1) v += __shfl_xor(v, o, 64);
  return v;
}

// ---------------- CSR build ----------------
__global__ void k_zero_i(int* p, int n){
  int i = blockIdx.x*256 + threadIdx.x;
  if (i < n) p[i] = 0;
}

__global__ void k_zero_f4(float4* p, int n4){
  int i = blockIdx.x*256 + threadIdx.x;
  if (i < n4) p[i] = make_float4(0.f,0.f,0.f,0.f);
}

__global__ void k_count(const int* __restrict__ dst, int* __restrict__ cnt){
  int e = blockIdx.x*256 + threadIdx.x;
  if (e < E_) atomicAdd(&cnt[dst[e]], 1);
}

__global__ void k_scan(const int* __restrict__ cnt, int* __restrict__ off, int* __restrict__ pos){
  __shared__ int part[256];
  int tid = threadIdx.x;
  const int CH = 13;               // 256*13 = 3328 >= 3200
  int base = tid*CH;
  int s = 0;
  for (int i = 0; i < CH; ++i){ int idx = base+i; s += (idx < N_) ? cnt[idx] : 0; }
  part[tid] = s; __syncthreads();
  for (int d = 1; d < 256; d <<= 1){
    int v = (tid >= d) ? part[tid-d] : 0;
    __syncthreads();
    part[tid] += v;
    __syncthreads();
  }
  int run = tid ? part[tid-1] : 0;
  for (int i = 0; i < CH; ++i){
    int idx = base+i;
    if (idx < N_){ off[idx] = run; pos[idx] = run; run += cnt[idx]; }
  }
  if (tid == 255) off[N_] = part[255];
}

__global__ void k_scatter(const int* __restrict__ dst, int* __restrict__ pos, int* __restrict__ eid){
  int e = blockIdx.x*256 + threadIdx.x;
  if (e < E_){ int p = atomicAdd(&pos[dst[e]], 1); eid[p] = e; }
}

// self-loop attr: per-target mean of incoming edge_attr
__global__ void k_sl(const float* __restrict__ ea, const int* __restrict__ off,
                     const int* __restrict__ eid, float* __restrict__ sl){
  int idx = blockIdx.x*256 + threadIdx.x;
  if (idx >= T_*N_) return;
  int t = idx / N_, n = idx % N_;
  int o = off[n], d = off[n+1] - o;
  float s0 = 0.f, s1 = 0.f;
  for (int j = 0; j < d; ++j){
    int e = eid[o+j];
    const float* p = ea + ((size_t)t*E_ + e)*2;
    s0 += p[0]; s1 += p[1];
  }
  float c = fmaxf((float)d, 1.f);
  sl[(size_t)idx*2]   = s0 / c;
  sl[(size_t)idx*2+1] = s1 / c;
}

// ---------------- generic GEMM tile body: C[M,N] = A[M,K] @ W[N,K]^T (+bias) ----
template<int ACT>
__device__ __forceinline__ void gemm_tile(const float* __restrict__ A, const float* __restrict__ W,
                                          const float* __restrict__ bias, float* __restrict__ C,
                                          int N, int K, int row0, int col0){
  __shared__ float As[32][68];
  __shared__ float Ws[32][68];
  const int tid = threadIdx.x;
  const int tr = tid >> 4, tc = tid & 15;
  const int lm = tid >> 2;          // 0..63
  const int lk = (tid & 3)*8;       // 0,8,16,24
  float acc[4][4] = {};
  for (int k0 = 0; k0 < K; k0 += 32){
    const float* Ap = A + (size_t)(row0+lm)*K + k0 + lk;
    const float* Wp = W + (size_t)(col0+lm)*K + k0 + lk;
#pragma unroll
    for (int j = 0; j < 8; ++j) As[lk+j][lm] = Ap[j];
#pragma unroll
    for (int j = 0; j < 8; ++j) Ws[lk+j][lm] = Wp[j];
    __syncthreads();
#pragma unroll
    for (int kk = 0; kk < 32; ++kk){
      float av[4], wv[4];
      *(float4*)av = *(const float4*)&As[kk][tr*4];
      *(float4*)wv = *(const float4*)&Ws[kk][tc*4];
#pragma unroll
      for (int i = 0; i < 4; ++i)
#pragma unroll
        for (int j = 0; j < 4; ++j)
          acc[i][j] = fmaf(av[i], wv[j], acc[i][j]);
    }
    __syncthreads();
  }
#pragma unroll
  for (int i = 0; i < 4; ++i){
    int r = row0 + tr*4 + i;
    float* Cr = C + (size_t)r*N + col0 + tc*4;
#pragma unroll
    for (int j = 0; j < 4; ++j){
      float v = acc[i][j];
      if (bias) v += bias[col0 + tc*4 + j];
      if (ACT == 1) v = fmaxf(v, 0.f);
      Cr[j] = v;
    }
  }
}

template<int ACT>
__global__ __launch_bounds__(256) void k_gemm(const float* __restrict__ A, const float* __restrict__ W,
                                              const float* __restrict__ bias, float* __restrict__ C,
                                              int M, int N, int K){
  gemm_tile<ACT>(A, W, bias, C, N, K, blockIdx.y*64, blockIdx.x*64);
}

// fused xl/xr
__global__ __launch_bounds__(256) void k_gemm_lr(const float* __restrict__ A,
                                                 const float* __restrict__ Wl, const float* __restrict__ Wr,
                                                 float* __restrict__ xl, float* __restrict__ xr){
  int bx = blockIdx.x;
  if (bx < HC_/64)
    gemm_tile<0>(A, Wl, nullptr, xl, HC_, G_, blockIdx.y*64, bx*64);
  else
    gemm_tile<0>(A, Wr, nullptr, xr, HC_, G_, blockIdx.y*64, (bx - HC_/64)*64);
}

// ---------------- thin GEMM v5: split-K, atomic accumulate ----------------
template<int KC, int FB>
__global__ __launch_bounds__(256) void k_tgemm_sk(const float* __restrict__ At, const float* __restrict__ W,
                                                  float* __restrict__ Ct, int K){
  constexpr int FPG = FB/4;
  constexpr int APT = KC*64/(4*256);      // float4s of At per thread (8 @ KC=128)
  __shared__ float AtS[KC*64];
  __shared__ float WsS[FB*KC];
  const int tid = threadIdx.x;
  const int c0 = blockIdx.x*FB;
  const int k0 = blockIdx.y*KC;
  const int lane = tid & 63;
  const int fg = tid >> 6;                // wave-uniform
  {
    const float4* ap = (const float4*)(At + (size_t)k0*64);
    float4* as = (float4*)AtS;
#pragma unroll
    for (int i = 0; i < APT; ++i) as[tid + i*256] = ap[tid + i*256];
    const int wr = tid / (KC/4), wc = tid % (KC/4);
    *(float4*)&WsS[wr*KC + wc*4] = *(const float4*)(W + (size_t)(c0+wr)*K + k0 + wc*4);
  }
  __syncthreads();
  float acc[FPG] = {};
#pragma unroll 8
  for (int k = 0; k < KC; ++k){
    float a = AtS[k*64 + lane];
#pragma unroll
    for (int i = 0; i < FPG; ++i)
      acc[i] = fmaf(a, WsS[(fg*FPG + i)*KC + k], acc[i]);
  }
#pragma unroll
  for (int i = 0; i < FPG; ++i)
    atomicAdd(&Ct[(size_t)(c0 + fg*FPG + i)*64 + lane], acc[i]);
}

// bias + relu epilogue for f1 (feature-major [nfeat][64])
__global__ void k_relub(float* __restrict__ f, const float* __restrict__ b, int total){
  int i = blockIdx.x*256 + threadIdx.x;
  if (i >= total) return;
  int c = i >> 6;
  f[i] = fmaxf(f[i] + b[c], 0.f);
}

// ---------------- fused GAT layer v3: head-sliced lanes + 2-edge ILP ----------------
// Wave per (t,node). lane = h*16+l16 owns channels c0 = h*64+l16*4..+3 of head h.
// Edge loop processes 2 edges/iter: 2 gathers in flight, interleaved shfl chains,
// merged online-softmax update (1 rescale, 3 exp per 2 edges).
__global__ __launch_bounds__(256) void k_gat(const float* __restrict__ xl, const float* __restrict__ xr,
                                             const float* __restrict__ ea, const float* __restrict__ sl,
                                             const int* __restrict__ off, const int* __restrict__ eid,
                                             const int* __restrict__ srcv,
                                             const float* __restrict__ we, const float* __restrict__ att,
                                             const float* __restrict__ hin, const float* __restrict__ gb,
                                             const float* __restrict__ lw, const float* __restrict__ lb,
                                             float* __restrict__ hout){
  const int b = blockIdx.x;
  const int t = b & 7;
  const int n = (b >> 3)*4 + (threadIdx.x >> 6);
  const int lane = threadIdx.x & 63;
  const int h   = lane >> 4;
  const int l16 = lane & 15;
  const int c0  = h*64 + l16*4;

  const float4 attc = *(const float4*)(att + c0);
  const float4 wea  = *(const float4*)(we + 2*c0);
  const float4 web  = *(const float4*)(we + 2*c0 + 4);
  const float4 xrn  = *(const float4*)(xr + ((size_t)t*N_ + n)*HC_ + c0);
  const float* xlt = xl + (size_t)t*N_*HC_ + c0;
  const float* eat = ea + (size_t)t*E_*2;

  const int o = off[n], deg = off[n+1] - o;

  float m, s; float4 acc;
  // self-loop edge (src = n, attrs = sl)
  {
    float2 a2 = *(const float2*)(sl + ((size_t)t*N_ + n)*2);
    float4 xv = *(const float4*)(xlt + (size_t)n*HC_);
    float v0 = xv.x + xrn.x + a2.x*wea.x + a2.y*wea.y;
    float v1 = xv.y + xrn.y + a2.x*wea.z + a2.y*wea.w;
    float v2 = xv.z + xrn.z + a2.x*web.x + a2.y*web.y;
    float v3 = xv.w + xrn.w + a2.x*web.z + a2.y*web.w;
    v0 = (v0 >= 0.f)? v0 : NEG_*v0;
    v1 = (v1 >= 0.f)? v1 : NEG_*v1;
    v2 = (v2 >= 0.f)? v2 : NEG_*v2;
    v3 = (v3 >= 0.f)? v3 : NEG_*v3;
    float p = v0*attc.x + v1*attc.y + v2*attc.z + v3*attc.w;
    p += __shfl_xor(p, 1, 64); p += __shfl_xor(p, 2, 64);
    p += __shfl_xor(p, 4, 64); p += __shfl_xor(p, 8, 64);
    m = p; s = 1.f; acc = xv;
  }

  if (deg > 0){
    float4 xv0, xv1; float2 a0v, a1v;
    {
      int e = eid[o];
      a0v = *(const float2*)(eat + (size_t)e*2);
      xv0 = *(const float4*)(xlt + (size_t)srcv[e]*HC_);
    }
    if (deg > 1){
      int e = eid[o+1];
      a1v = *(const float2*)(eat + (size_t)e*2);
      xv1 = *(const float4*)(xlt + (size_t)srcv[e]*HC_);
    }
    int j = 0;
    for (; j + 2 <= deg; j += 2){
      float4 cx0 = xv0, cx1 = xv1;
      float2 ca0 = a0v, ca1 = a1v;
      if (j+2 < deg){
        int e = eid[o+j+2];
        a0v = *(const float2*)(eat + (size_t)e*2);
        xv0 = *(const float4*)(xlt + (size_t)srcv[e]*HC_);
      }
      if (j+3 < deg){
        int e = eid[o+j+3];
        a1v = *(const float2*)(eat + (size_t)e*2);
        xv1 = *(const float4*)(xlt + (size_t)srcv[e]*HC_);
      }
      // logits for both edges
      float u0 = cx0.x + xrn.x + ca0.x*wea.x + ca0.y*wea.y;
      float u1 = cx0.y + xrn.y + ca0.x*wea.z + ca0.y*wea.w;
      float u2 = cx0.z + xrn.z + ca0.x*web.x + ca0.y*web.y;
      float u3 = cx0.w + xrn.w + ca0.x*web.z + ca0.y*web.w;
      float r0 = cx1.x + xrn.x + ca1.x*wea.x + ca1.y*wea.y;
      float r1 = cx1.y + xrn.y + ca1.x*wea.z + ca1.y*wea.w;
      float r2 = cx1.z + xrn.z + ca1.x*web.x + ca1.y*web.y;
      float r3 = cx1.w + xrn.w + ca1.x*web.z + ca1.y*web.w;
      u0 = (u0 >= 0.f)? u0 : NEG_*u0;  r0 = (r0 >= 0.f)? r0 : NEG_*r0;
      u1 = (u1 >= 0.f)? u1 : NEG_*u1;  r1 = (r1 >= 0.f)? r1 : NEG_*r1;
      u2 = (u2 >= 0.f)? u2 : NEG_*u2;  r2 = (r2 >= 0.f)? r2 : NEG_*r2;
      u3 = (u3 >= 0.f)? u3 : NEG_*u3;  r3 = (r3 >= 0.f)? r3 : NEG_*r3;
      float p0 = u0*attc.x + u1*attc.y + u2*attc.z + u3*attc.w;
      float p1 = r0*attc.x + r1*attc.y + r2*attc.z + r3*attc.w;
      // interleaved butterflies (two independent chains)
      p0 += __shfl_xor(p0, 1, 64); p1 += __shfl_xor(p1, 1, 64);
      p0 += __shfl_xor(p0, 2, 64); p1 += __shfl_xor(p1, 2, 64);
      p0 += __shfl_xor(p0, 4, 64); p1 += __shfl_xor(p1, 4, 64);
      p0 += __shfl_xor(p0, 8, 64); p1 += __shfl_xor(p1, 8, 64);
      // merged online update
      float nm = fmaxf(m, fmaxf(p0, p1));
      float e1 = __expf(m - nm);
      float g0 = __expf(p0 - nm);
      float g1 = __expf(p1 - nm);
      s = fmaf(s, e1, g0 + g1);
      acc.x = fmaf(acc.x, e1, fmaf(g0, cx0.x, g1*cx1.x));
      acc.y = fmaf(acc.y, e1, fmaf(g0, cx0.y, g1*cx1.y));
      acc.z = fmaf(acc.z, e1, fmaf(g0, cx0.z, g1*cx1.z));
      acc.w = fmaf(acc.w, e1, fmaf(g0, cx0.w, g1*cx1.w));
      m = nm;
    }
    if (j < deg){   // odd tail: operands already in slot 0
      float4 cx0 = xv0; float2 ca0 = a0v;
      float u0 = cx0.x + xrn.x + ca0.x*wea.x + ca0.y*wea.y;
      float u1 = cx0.y + xrn.y + ca0.x*wea.z + ca0.y*wea.w;
      float u2 = cx0.z + xrn.z + ca0.x*web.x + ca0.y*web.y;
      float u3 = cx0.w + xrn.w + ca0.x*web.z + ca0.y*web.w;
      u0 = (u0 >= 0.f)? u0 : NEG_*u0;
      u1 = (u1 >= 0.f)? u1 : NEG_*u1;
      u2 = (u2 >= 0.f)? u2 : NEG_*u2;
      u3 = (u3 >= 0.f)? u3 : NEG_*u3;
      float p0 = u0*attc.x + u1*attc.y + u2*attc.z + u3*attc.w;
      p0 += __shfl_xor(p0, 1, 64); p0 += __shfl_xor(p0, 2, 64);
      p0 += __shfl_xor(p0, 4, 64); p0 += __shfl_xor(p0, 8, 64);
      float nm = fmaxf(m, p0);
      float e1 = __expf(m - nm);
      float g0 = __expf(p0 - nm);
      s = fmaf(s, e1, g0);
      acc.x = fmaf(acc.x, e1, g0*cx0.x);
      acc.y = fmaf(acc.y, e1, g0*cx0.y);
      acc.z = fmaf(acc.z, e1, g0*cx0.z);
      acc.w = fmaf(acc.w, e1, g0*cx0.w);
      m = nm;
    }
  }

  float inv = 1.f / s;
  float o0 = acc.x*inv, o1 = acc.y*inv, o2 = acc.z*inv, o3 = acc.w*inv;
  o0 += __shfl_xor(o0, 16, 64); o1 += __shfl_xor(o1, 16, 64);
  o2 += __shfl_xor(o2, 16, 64); o3 += __shfl_xor(o3, 16, 64);
  o0 += __shfl_xor(o0, 32, 64); o1 += __shfl_xor(o1, 32, 64);
  o2 += __shfl_xor(o2, 32, 64); o3 += __shfl_xor(o3, 32, 64);

  const int g0i = l16*4;
  float4 gbv = *(const float4*)(gb + g0i);
  float4 hv  = *(const float4*)(hin + ((size_t)t*N_ + n)*G_ + g0i);
  float w0 = fmaxf(0.25f*o0 + gbv.x, 0.f) + hv.x;
  float w1 = fmaxf(0.25f*o1 + gbv.y, 0.f) + hv.y;
  float w2 = fmaxf(0.25f*o2 + gbv.z, 0.f) + hv.z;
  float w3 = fmaxf(0.25f*o3 + gbv.w, 0.f) + hv.w;

  float ssum = w0 + w1 + w2 + w3;
  ssum += __shfl_xor(ssum, 1, 64); ssum += __shfl_xor(ssum, 2, 64);
  ssum += __shfl_xor(ssum, 4, 64); ssum += __shfl_xor(ssum, 8, 64);
  float mu = ssum * (1.f/64.f);
  float d0 = w0-mu, d1 = w1-mu, d2 = w2-mu, d3 = w3-mu;
  float q = d0*d0 + d1*d1 + d2*d2 + d3*d3;
  q += __shfl_xor(q, 1, 64); q += __shfl_xor(q, 2, 64);
  q += __shfl_xor(q, 4, 64); q += __shfl_xor(q, 8, 64);
  float rstd = 1.f / sqrtf(q*(1.f/64.f) + EPS_);

  if (h == 0){
    float4 lwv = *(const float4*)(lw + g0i);
    float4 lbv = *(const float4*)(lb + g0i);
    float4 r;
    r.x = d0*rstd*lwv.x + lbv.x;
    r.y = d1*rstd*lwv.y + lbv.y;
    r.z = d2*rstd*lwv.z + lbv.z;
    r.w = d3*rstd*lwv.w + lbv.w;
    *(float4*)(hout + ((size_t)t*N_ + n)*G_ + g0i) = r;
  }
}

// ---------------- pooling -> pooled_t[128][64] (feature-major) ----------------
__global__ __launch_bounds__(256) void k_pool(const float* __restrict__ h, float* __restrict__ pooled_t){
  int tb = blockIdx.x;                 // token = t*8+b
  int t = tb >> 3, b = tb & 7;
  int lane = threadIdx.x & 63, w = threadIdx.x >> 6;
  const float* hp = h + ((size_t)t*N_ + b*NP_)*G_;
  float s = 0.f, m = -1e30f;
  for (int n = w*100; n < (w+1)*100; ++n){
    float v = hp[(size_t)n*G_ + lane];
    s += v; m = fmaxf(m, v);
  }
  __shared__ float ss[4][64], mm[4][64];
  ss[w][lane] = s; mm[w][lane] = m;
  __syncthreads();
  if (w == 0){
    s = ss[0][lane] + ss[1][lane] + ss[2][lane] + ss[3][lane];
    m = fmaxf(fmaxf(mm[0][lane], mm[1][lane]), fmaxf(mm[2][lane], mm[3][lane]));
    pooled_t[(size_t)lane*64 + tb]      = s * (1.f/400.f);
    pooled_t[(size_t)(64+lane)*64 + tb] = m;
  }
}

// ---------------- tok_t (raw sums) + n2t bias -> y, y_t, motion ----------------
__global__ void k_tokout(const float* __restrict__ tok_t, const float* __restrict__ n2tb,
                         float* __restrict__ y, float* __restrict__ yt, float* __restrict__ mo){
  int i = blockIdx.x*256 + threadIdx.x;
  if (i >= D_*64) return;
  int tk = i & 63;              // t*8+b
  int c = i >> 6;
  int t = tk >> 3, b = tk & 7;
  float bb = n2tb[c];
  float v = tok_t[(size_t)c*64 + tk] + bb;
  int yrow = b*8 + t;
  y[(size_t)yrow*D_ + c] = v;
  yt[(size_t)c*64 + yrow] = v;
  if (c < 256 && t < 7)
    mo[((size_t)b*7 + t)*256 + c] = (tok_t[(size_t)c*64 + (tk+8)] + bb) - v;  // (t+1)*8+b
}

// ---------------- MHA: reads raw qkv_t + bias, writes attno_t[512][64] ----------------
__global__ __launch_bounds__(64) void k_mha(const float* __restrict__ qkv_t, const float* __restrict__ bqkv,
                                            float* __restrict__ o_t){
  int bh = blockIdx.x;
  int b = bh >> 3, hd = bh & 7;
  __shared__ float q[8][64], k[8][64], v[8][64], p[8][8];
  int tid = threadIdx.x;
  int tt = tid >> 3, d0 = (tid & 7)*8;
  int row = b*8 + tt;           // y-row token
#pragma unroll
  for (int j = 0; j < 8; ++j){
    int f = hd*64 + d0 + j;
    q[tt][d0+j] = qkv_t[(size_t)f*64 + row] + bqkv[f];
    k[tt][d0+j] = qkv_t[(size_t)(512+f)*64 + row] + bqkv[512+f];
    v[tt][d0+j] = qkv_t[(size_t)(1024+f)*64 + row] + bqkv[1024+f];
  }
  __syncthreads();
  int tq = tid >> 3, tk = tid & 7;
  float s = 0.f;
#pragma unroll
  for (int d = 0; d < 64; ++d) s += q[tq][d]*k[tk][d];
  p[tq][tk] = s * 0.125f;
  __syncthreads();
  if (tid < 8){
    float mx = -1e30f;
#pragma unroll
    for (int j = 0; j < 8; ++j) mx = fmaxf(mx, p[tid][j]);
    float smv = 0.f;
#pragma unroll
    for (int j = 0; j < 8; ++j){ float e = expf(p[tid][j]-mx); p[tid][j] = e; smv += e; }
    float r = 1.f/smv;
#pragma unroll
    for (int j = 0; j < 8; ++j) p[tid][j] *= r;
  }
  __syncthreads();
  float out[8];
#pragma unroll
  for (int j = 0; j < 8; ++j) out[j] = 0.f;
#pragma unroll
  for (int t2 = 0; t2 < 8; ++t2){
    float wv = p[tq][t2];
#pragma unroll
    for (int j = 0; j < 8; ++j) out[j] = fmaf(wv, v[t2][d0+j], out[j]);
  }
  int orow = b*8 + tq;
#pragma unroll
  for (int j = 0; j < 8; ++j) o_t[(size_t)(hd*64 + d0 + j)*64 + orow] = out[j];
}

// ---------------- residual(+transposed raw res + bias) + LayerNorm; writes y and y_t ---
__global__ __launch_bounds__(256) void k_lnadd(float* __restrict__ y, float* __restrict__ yt,
                                               const float* __restrict__ res_t, const float* __restrict__ rbias,
                                               const float* __restrict__ w, const float* __restrict__ b){
  int row = blockIdx.x*4 + (threadIdx.x >> 6);
  int lane = threadIdx.x & 63;
  float* yr = y + (size_t)row*D_;
  float v[8]; float s = 0.f;
#pragma unroll
  for (int i = 0; i < 8; ++i){
    int c = lane + i*64;
    v[i] = yr[c] + res_t[(size_t)c*64 + row] + rbias[c];
    s += v[i];
  }
  s = wred_sum(s);
  float mu = s * (1.f/512.f);
  float qq = 0.f;
#pragma unroll
  for (int i = 0; i < 8; ++i){ float d = v[i]-mu; qq += d*d; }
  qq = wred_sum(qq);
  float rstd = 1.f / sqrtf(qq*(1.f/512.f) + EPS_);
#pragma unroll
  for (int i = 0; i < 8; ++i){
    int c = lane + i*64;
    float ov = (v[i]-mu)*rstd*w[c] + b[c];
    yr[c] = ov;
    yt[(size_t)c*64 + row] = ov;
  }
}

extern "C" void kernel_launch(void* const* d_in, const int* in_sizes, int n_in,
                              void* d_out, int out_size, void* d_ws, size_t ws_size,
                              hipStream_t stream){
  const float* x       = (const float*)d_in[0];
  const int*   ei      = (const int*)d_in[1];
  const float* eattr   = (const float*)d_in[2];
  const float* proj_w  = (const float*)d_in[4];
  const float* proj_b  = (const float*)d_in[5];
  const float* gat_wl  = (const float*)d_in[6];
  const float* gat_wr  = (const float*)d_in[7];
  const float* gat_we  = (const float*)d_in[8];
  const float* gat_att = (const float*)d_in[9];
  const float* gat_b   = (const float*)d_in[10];
  const float* ln_w    = (const float*)d_in[11];
  const float* ln_b    = (const float*)d_in[12];
  const float* n2t_w   = (const float*)d_in[13];
  const float* n2t_b   = (const float*)d_in[14];
  const float* wqkv    = (const float*)d_in[15];
  const float* bqkv    = (const float*)d_in[16];
  const float* wo      = (const float*)d_in[17];
  const float* bo      = (const float*)d_in[18];
  const float* w1      = (const float*)d_in[19];
  const float* b1      = (const float*)d_in[20];
  const float* w2      = (const float*)d_in[21];
  const float* b2      = (const float*)d_in[22];
  const float* ln1w    = (const float*)d_in[23];
  const float* ln1b    = (const float*)d_in[24];
  const float* ln2w    = (const float*)d_in[25];
  const float* ln2b    = (const float*)d_in[26];

  const int* src0 = ei;
  const int* dst0 = ei + E_;

  char* p = (char*)d_ws;
  auto alloc = [&](size_t bytes){ void* r = (void*)p; p += (bytes + 255) & ~(size_t)255; return r; };
  int* cnt   = (int*)alloc((size_t)N_*4);
  int* off   = (int*)alloc((size_t)(N_+1)*4);
  int* pos   = (int*)alloc((size_t)N_*4);
  int* eid   = (int*)alloc((size_t)E_*4);
  float* sl  = (float*)alloc((size_t)T_*N_*2*4);
  float* hA  = (float*)alloc((size_t)T_*N_*G_*4);
  float* hB  = (float*)alloc((size_t)T_*N_*G_*4);
  float* xl  = (float*)alloc((size_t)T_*N_*HC_*4);
  float* xr  = (float*)alloc((size_t)T_*N_*HC_*4);
  float* pooled_t = (float*)alloc(128*64*4);
  float* yt       = (float*)alloc(512*64*4);
  float* attno_t  = (float*)alloc(512*64*4);
  // ---- atomic-accumulated buffers (contiguous; zeroed once) ----
  float* tok_t  = (float*)alloc(512*64*4);
  float* qkv0_t = (float*)alloc(1536*64*4);
  float* qkv1_t = (float*)alloc(1536*64*4);
  float* moA0_t = (float*)alloc(512*64*4);
  float* moB0_t = (float*)alloc(512*64*4);
  float* moA1_t = (float*)alloc(512*64*4);
  float* moB1_t = (float*)alloc(512*64*4);
  float* f10_t  = (float*)alloc(2048*64*4);
  float* f11_t  = (float*)alloc(2048*64*4);
  const int ZT4 = (512 + 1536*2 + 512*4 + 2048*2)*64/4;   // float4 count = 155648

  float* y    = (float*)d_out;          // [B,T,D] transformer state, final output 1
  float* mout = y + B_*T_*D_;           // motion, final output 2

  // zero atomic outputs (once) + CSR + self-loop attrs
  k_zero_f4 <<<dim3((ZT4+255)/256), dim3(256), 0, stream>>>((float4*)tok_t, ZT4);
  k_zero_i  <<<dim3((N_+255)/256), dim3(256), 0, stream>>>(cnt, N_);
  k_count   <<<dim3((E_+255)/256), dim3(256), 0, stream>>>(dst0, cnt);
  k_scan    <<<dim3(1), dim3(256), 0, stream>>>(cnt, off, pos);
  k_scatter <<<dim3((E_+255)/256), dim3(256), 0, stream>>>(dst0, pos, eid);
  k_sl      <<<dim3((T_*N_+255)/256), dim3(256), 0, stream>>>(eattr, off, eid, sl);

  // input projection
  k_gemm<0><<<dim3(1, (T_*N_)/64), dim3(256), 0, stream>>>(x, proj_w, proj_b, hA, T_*N_, G_, IND_);

  float* hcur = hA; float* hnext = hB;
  for (int i = 0; i < 3; ++i){
    k_gemm_lr<<<dim3(2*HC_/64, (T_*N_)/64), dim3(256), 0, stream>>>(hcur,
        gat_wl + (size_t)i*HC_*G_, gat_wr + (size_t)i*HC_*G_, xl, xr);
    k_gat<<<dim3(T_*N_/4), dim3(256), 0, stream>>>(xl, xr, eattr, sl, off, eid, src0,
        gat_we + (size_t)i*HC_*2, gat_att + (size_t)i*HC_, hcur,
        gat_b + i*G_, ln_w + i*G_, ln_b + i*G_, hnext);
    float* tmp = hcur; hcur = hnext; hnext = tmp;
  }

  // pool + node2token (split-K GEMM, bias applied in k_tokout)
  k_pool<<<dim3(T_*B_), dim3(256), 0, stream>>>(hcur, pooled_t);
  k_tgemm_sk<128,8><<<dim3(D_/8, 1), dim3(256), 0, stream>>>(pooled_t, n2t_w, tok_t, 128);
  k_tokout<<<dim3((D_*64+255)/256), dim3(256), 0, stream>>>(tok_t, n2t_b, y, yt, mout);

  // transformer encoder, 2 layers (feature-major activations, split-K GEMMs)
  float* qkvL[2] = {qkv0_t, qkv1_t};
  float* moAL[2] = {moA0_t, moA1_t};
  float* moBL[2] = {moB0_t, moB1_t};
  float* f1L[2]  = {f10_t, f11_t};
  for (int l = 0; l < 2; ++l){
    k_tgemm_sk<128,8><<<dim3(1536/8, 512/128), dim3(256), 0, stream>>>(yt, wqkv + (size_t)l*1536*512, qkvL[l], 512);
    k_mha<<<dim3(64), dim3(64), 0, stream>>>(qkvL[l], bqkv + l*1536, attno_t);
    k_tgemm_sk<128,8><<<dim3(512/8, 512/128), dim3(256), 0, stream>>>(attno_t, wo + (size_t)l*512*512, moAL[l], 512);
    k_lnadd<<<dim3(16), dim3(256), 0, stream>>>(y, yt, moAL[l], bo + l*512, ln1w + l*512, ln1b + l*512);
    k_tgemm_sk<128,8><<<dim3(2048/8, 512/128), dim3(256), 0, stream>>>(yt, w1 + (size_t)l*2048*512, f1L[l], 512);
    k_relub<<<dim3((2048*64+255)/256), dim3(256), 0, stream>>>(f1L[l], b1 + l*2048, 2048*64);
    k_tgemm_sk<128,8><<<dim3(512/8, 2048/128), dim3(256), 0, stream>>>(f1L[l], w2 + (size_t)l*512*2048, moBL[l], 2048);
    k_lnadd<<<dim3(16), dim3(256), 0, stream>>>(y, yt, moBL[l], b2 + l*512, ln2w + l*512, ln2b + l*512);
  }
}